// Round 1
// baseline (747.493 us; speedup 1.0000x reference)
//
#include <hip/hip_runtime.h>
#include <hip/hip_bf16.h>
#include <math.h>

// Problem constants
#define NN 768
#define CS 256
#define CZ 128
#define CH 128
#define HH 8
#define PQK 8
#define PV 12
#define CONCAT 2432   // 1024 + 288 + 96 + 1024
#define ATT_HSTRIDE (768*768)

// ---------------------------------------------------------------------------
// Generic tiled fp32 GEMM: C[M,D] = A[M,K] @ W[D,K]^T + bias, optional relu
// ---------------------------------------------------------------------------
__global__ __launch_bounds__(256) void gemm_nt(
    const float* __restrict__ A, int lda,
    const float* __restrict__ W,
    const float* __restrict__ bias,
    float* __restrict__ C, int ldc,
    int M, int D, int K, int relu)
{
    __shared__ float As[32][33];
    __shared__ float Ws[32][33];   // Ws[kk][d_local]
    int tx = threadIdx.x, ty = threadIdx.y;
    int bi = blockIdx.y * 32;
    int bd = blockIdx.x * 32;
    float acc[2][2] = {{0.f,0.f},{0.f,0.f}};
    for (int k0 = 0; k0 < K; k0 += 32) {
        #pragma unroll
        for (int a = 0; a < 2; a++) {
            #pragma unroll
            for (int b = 0; b < 2; b++) {
                int r = ty + a*16, c = tx + b*16;
                int gr = bi + r, gc = k0 + c;
                As[r][c] = (gr < M && gc < K) ? A[gr*lda + gc] : 0.f;
                int dr = bd + r;
                Ws[c][r] = (dr < D && gc < K) ? W[dr*K + gc] : 0.f;
            }
        }
        __syncthreads();
        #pragma unroll 8
        for (int kk = 0; kk < 32; kk++) {
            float a0 = As[ty][kk],    a1 = As[ty+16][kk];
            float b0 = Ws[kk][tx],    b1 = Ws[kk][tx+16];
            acc[0][0] += a0*b0; acc[0][1] += a0*b1;
            acc[1][0] += a1*b0; acc[1][1] += a1*b1;
        }
        __syncthreads();
    }
    #pragma unroll
    for (int a = 0; a < 2; a++) {
        #pragma unroll
        for (int b = 0; b < 2; b++) {
            int gr = bi + ty + a*16, gd = bd + tx + b*16;
            if (gr < M && gd < D) {
                float v = acc[a][b] + bias[gd];
                if (relu) v = fmaxf(v, 0.f);
                C[gr*ldc + gd] = v;
            }
        }
    }
}

// ---------------------------------------------------------------------------
// hw[h] = softplus(head_w[h]) * sqrt(1/108)
// ---------------------------------------------------------------------------
__global__ void prep_kernel(const float* __restrict__ head_w, float* __restrict__ hw8)
{
    int t = threadIdx.x;
    if (t < HH) {
        float x = head_w[t];
        float sp = (x > 20.f) ? x : log1pf(expf(x));
        hw8[t] = sp * 0.09622504486493764f;
    }
}

// ---------------------------------------------------------------------------
// Rotate q/k/v points into global frame: out[i][h][p][3] = rot[i] @ raw + trans
// qpraw: [i][x*64 + h*8 + p], kvpraw: [i][x*160 + h*20 + pp]
// ---------------------------------------------------------------------------
__global__ void rotate_kernel(
    const float* __restrict__ qpraw, const float* __restrict__ kvpraw,
    const float* __restrict__ rot, const float* __restrict__ trans,
    float* __restrict__ qpb, float* __restrict__ kpb, float* __restrict__ vpb)
{
    int id = blockIdx.x*256 + threadIdx.x;
    if (id >= NN*HH*28) return;
    int i = id / (HH*28);
    int rem = id % (HH*28);
    int h = rem / 28;
    int idx = rem % 28;
    const float* R = rot + i*9;
    const float* T = trans + i*3;
    float s0, s1, s2;
    if (idx < 8) {
        int pp = idx;
        s0 = qpraw[i*192 +   0 + h*8 + pp];
        s1 = qpraw[i*192 +  64 + h*8 + pp];
        s2 = qpraw[i*192 + 128 + h*8 + pp];
    } else {
        int pp = (idx < 16) ? (idx - 8) : (idx - 8);  // 0..7 for kp, 8..19 for vp
        s0 = kvpraw[i*480 +   0 + h*20 + pp];
        s1 = kvpraw[i*480 + 160 + h*20 + pp];
        s2 = kvpraw[i*480 + 320 + h*20 + pp];
    }
    float o0 = R[0]*s0 + R[1]*s1 + R[2]*s2 + T[0];
    float o1 = R[3]*s0 + R[4]*s1 + R[5]*s2 + T[1];
    float o2 = R[6]*s0 + R[7]*s1 + R[8]*s2 + T[2];
    float* dst;
    if (idx < 8)       dst = qpb + i*192 + h*24 + idx*3;
    else if (idx < 16) dst = kpb + i*192 + h*24 + (idx-8)*3;
    else               dst = vpb + i*288 + h*36 + (idx-16)*3;
    dst[0] = o0; dst[1] = o1; dst[2] = o2;
}

// Qsq[i*8+h] = sum over 24 coords of qp^2 ; same for Ksq over kp
__global__ void sq_kernel(const float* __restrict__ qpb, const float* __restrict__ kpb,
                          float* __restrict__ Qsq, float* __restrict__ Ksq)
{
    int id = blockIdx.x*256 + threadIdx.x;
    if (id >= NN*HH) return;
    const float* qq = qpb + id*24;
    const float* kk = kpb + id*24;
    float a = 0.f, b = 0.f;
    #pragma unroll
    for (int m = 0; m < 24; m++) { a += qq[m]*qq[m]; b += kk[m]*kk[m]; }
    Qsq[id] = a; Ksq[id] = b;
}

// ---------------------------------------------------------------------------
// bias_p folded into att: att[h][pair] = sqrt(1/3) * (p[pair,:] . Wpb[h,:] + bpb[h])
// 16 lanes per pair, 8 floats each, shuffle-reduce.
// ---------------------------------------------------------------------------
__global__ __launch_bounds__(256) void biasp_kernel(
    const float* __restrict__ p, const float* __restrict__ Wpb,
    const float* __restrict__ bpb, float* __restrict__ att)
{
    __shared__ float wpb_s[8][128];
    __shared__ float bpb_s[8];
    int tid = threadIdx.x;
    for (int idx = tid; idx < 1024; idx += 256) wpb_s[idx >> 7][idx & 127] = Wpb[idx];
    if (tid < 8) bpb_s[tid] = bpb[tid];
    __syncthreads();
    int lane = tid & 63, wv = tid >> 6;
    int pl = lane >> 4, zg = lane & 15;
    size_t pair = (size_t)blockIdx.x*16 + wv*4 + pl;
    const float* prow = p + pair*128 + zg*8;
    float4 a0 = *(const float4*)prow;
    float4 a1 = *(const float4*)(prow + 4);
    float acc[8];
    #pragma unroll
    for (int h = 0; h < 8; h++) {
        const float* wr = &wpb_s[h][zg*8];
        acc[h] = a0.x*wr[0] + a0.y*wr[1] + a0.z*wr[2] + a0.w*wr[3]
               + a1.x*wr[4] + a1.y*wr[5] + a1.z*wr[6] + a1.w*wr[7];
    }
    #pragma unroll
    for (int m = 1; m < 16; m <<= 1) {
        #pragma unroll
        for (int h = 0; h < 8; h++) acc[h] += __shfl_xor(acc[h], m);
    }
    if (zg == 0) {
        #pragma unroll
        for (int h = 0; h < 8; h++)
            att[(size_t)h*ATT_HSTRIDE + pair] = 0.57735026918962576f*(acc[h] + bpb_s[h]);
    }
}

// ---------------------------------------------------------------------------
// Logits: att[h][i][j] += scale*q.k + hw*(qp.kp) - 0.5*hw*(|qp|^2+|kp|^2) + mask
// ---------------------------------------------------------------------------
__global__ __launch_bounds__(256) void logits_kernel(
    const float* __restrict__ qb, const float* __restrict__ kvb,
    const float* __restrict__ qpb, const float* __restrict__ kpb,
    const float* __restrict__ Qsq, const float* __restrict__ Ksq,
    const float* __restrict__ mask, const float* __restrict__ hw8,
    float* __restrict__ att)
{
    __shared__ float qs[32][129];
    __shared__ float ks[32][129];
    __shared__ float qps[32][25];
    __shared__ float kps[32][25];
    __shared__ float Qs[32], Ks[32], Mi[32], Mj[32];
    int h = blockIdx.z;
    int i0 = blockIdx.y*32, j0 = blockIdx.x*32;
    int tx = threadIdx.x, ty = threadIdx.y;
    int tid = ty*16 + tx;
    for (int idx = tid; idx < 32*128; idx += 256) {
        int r = idx >> 7, c = idx & 127;
        qs[r][c] = qb[(i0+r)*1024 + h*128 + c];
        ks[r][c] = kvb[(j0+r)*2048 + h*256 + c];
    }
    for (int idx = tid; idx < 32*24; idx += 256) {
        int r = idx / 24, m = idx % 24;
        qps[r][m] = qpb[(i0+r)*192 + h*24 + m];
        kps[r][m] = kpb[(j0+r)*192 + h*24 + m];
    }
    if (tid < 32) {
        Qs[tid] = Qsq[(i0+tid)*8 + h];
        Ks[tid] = Ksq[(j0+tid)*8 + h];
        Mi[tid] = mask[i0+tid];
        Mj[tid] = mask[j0+tid];
    }
    __syncthreads();
    float hw = hw8[h];
    float acc[2][2] = {{0.f,0.f},{0.f,0.f}};
    float accp[2][2] = {{0.f,0.f},{0.f,0.f}};
    #pragma unroll 4
    for (int kk = 0; kk < 128; kk++) {
        float a0 = qs[ty][kk], a1 = qs[ty+16][kk];
        float b0 = ks[tx][kk], b1 = ks[tx+16][kk];
        acc[0][0] += a0*b0; acc[0][1] += a0*b1;
        acc[1][0] += a1*b0; acc[1][1] += a1*b1;
    }
    #pragma unroll
    for (int m = 0; m < 24; m++) {
        float a0 = qps[ty][m], a1 = qps[ty+16][m];
        float b0 = kps[tx][m], b1 = kps[tx+16][m];
        accp[0][0] += a0*b0; accp[0][1] += a0*b1;
        accp[1][0] += a1*b0; accp[1][1] += a1*b1;
    }
    const float scale_qk = 0.05103103630798288f;  // sqrt(1/384)
    #pragma unroll
    for (int a = 0; a < 2; a++) {
        #pragma unroll
        for (int b = 0; b < 2; b++) {
            int r = ty + a*16, c = tx + b*16;
            size_t aidx = (size_t)h*ATT_HSTRIDE + (size_t)(i0+r)*768 + (j0+c);
            float v = att[aidx];
            v += acc[a][b]*scale_qk + hw*accp[a][b]
               - 0.5f*hw*(Qs[r] + Ks[c])
               + 100000.0f*(Mi[r]*Mj[c] - 1.0f);
            att[aidx] = v;
        }
    }
}

// ---------------------------------------------------------------------------
// Softmax over j: one wave per (h,i) row of 768
// ---------------------------------------------------------------------------
__global__ __launch_bounds__(64) void softmax_kernel(float* __restrict__ att)
{
    int i = blockIdx.x, h = blockIdx.y, lane = threadIdx.x;
    float* row = att + ((size_t)h*768 + i)*768;
    float v[12];
    float m = -3.0e38f;
    #pragma unroll
    for (int e = 0; e < 12; e++) { v[e] = row[lane + e*64]; m = fmaxf(m, v[e]); }
    #pragma unroll
    for (int d = 1; d < 64; d <<= 1) m = fmaxf(m, __shfl_xor(m, d));
    float ssum = 0.f;
    #pragma unroll
    for (int e = 0; e < 12; e++) { v[e] = expf(v[e] - m); ssum += v[e]; }
    #pragma unroll
    for (int d = 1; d < 64; d <<= 1) ssum += __shfl_xor(ssum, d);
    float inv = 1.0f/ssum;
    #pragma unroll
    for (int e = 0; e < 12; e++) row[lane + e*64] = v[e]*inv;
}

// ---------------------------------------------------------------------------
// o = att @ v  -> concat[i][h*128+c]  (batched per-h tiled GEMM)
// ---------------------------------------------------------------------------
__global__ __launch_bounds__(256) void attv_kernel(
    const float* __restrict__ att, const float* __restrict__ kvb,
    float* __restrict__ concat)
{
    __shared__ float as_[32][33];
    __shared__ float vs[32][33];
    int h = blockIdx.z;
    int i0 = blockIdx.y*32, c0 = blockIdx.x*32;
    int tx = threadIdx.x, ty = threadIdx.y;
    float acc[2][2] = {{0.f,0.f},{0.f,0.f}};
    for (int k0 = 0; k0 < 768; k0 += 32) {
        #pragma unroll
        for (int a = 0; a < 2; a++) {
            #pragma unroll
            for (int b = 0; b < 2; b++) {
                int r = ty + a*16, c = tx + b*16;
                as_[r][c] = att[(size_t)h*ATT_HSTRIDE + (size_t)(i0+r)*768 + k0 + c];
                vs[r][c]  = kvb[(k0+r)*2048 + h*256 + 128 + c0 + c];
            }
        }
        __syncthreads();
        #pragma unroll 8
        for (int kk = 0; kk < 32; kk++) {
            float a0 = as_[ty][kk],   a1 = as_[ty+16][kk];
            float b0 = vs[kk][tx],    b1 = vs[kk][tx+16];
            acc[0][0] += a0*b0; acc[0][1] += a0*b1;
            acc[1][0] += a1*b0; acc[1][1] += a1*b1;
        }
        __syncthreads();
    }
    #pragma unroll
    for (int a = 0; a < 2; a++) {
        #pragma unroll
        for (int b = 0; b < 2; b++) {
            int gi = i0 + ty + a*16, gc = c0 + tx + b*16;
            concat[gi*CONCAT + h*128 + gc] = acc[a][b];
        }
    }
}

// ---------------------------------------------------------------------------
// opt[i][h][p][x] = sum_j att[h,i,j]*vp[j,h,p,x]   (36 cols per h)
// ---------------------------------------------------------------------------
__global__ __launch_bounds__(64) void optv_kernel(
    const float* __restrict__ att, const float* __restrict__ vpb,
    float* __restrict__ optb)
{
    int i = blockIdx.x, h = blockIdx.y, t = threadIdx.x;
    __shared__ float arow[768];
    const float* arp = att + ((size_t)h*768 + i)*768;
    for (int idx = t; idx < 768; idx += 64) arow[idx] = arp[idx];
    __syncthreads();
    if (t < 36) {
        float acc = 0.f;
        #pragma unroll 4
        for (int j = 0; j < 768; j++) acc += arow[j]*vpb[j*288 + h*36 + t];
        optb[i*288 + h*36 + t] = acc;
    }
}

// ---------------------------------------------------------------------------
// opt2 = rot^T (opt - trans); write opt_flat + opt_norm into concat
// ---------------------------------------------------------------------------
__global__ void optfinal_kernel(
    const float* __restrict__ optb, const float* __restrict__ rot,
    const float* __restrict__ trans, float* __restrict__ concat)
{
    int id = blockIdx.x*256 + threadIdx.x;
    if (id >= NN*96) return;
    int i = id / 96;
    int hp = id % 96;                 // h*12 + p
    const float* ob = optb + i*288 + hp*3;
    float y0 = ob[0] - trans[i*3+0];
    float y1 = ob[1] - trans[i*3+1];
    float y2 = ob[2] - trans[i*3+2];
    const float* R = rot + i*9;
    float o0 = R[0]*y0 + R[3]*y1 + R[6]*y2;
    float o1 = R[1]*y0 + R[4]*y1 + R[7]*y2;
    float o2 = R[2]*y0 + R[5]*y1 + R[8]*y2;
    float nrm = sqrtf(o0*o0 + o1*o1 + o2*o2 + 1e-8f);
    float* cb = concat + i*CONCAT;
    cb[1024 +   0 + hp] = o0;
    cb[1024 +  96 + hp] = o1;
    cb[1024 + 192 + hp] = o2;
    cb[1312 + hp] = nrm;
}

// ---------------------------------------------------------------------------
// opair[i][h][z] = sum_j att[h,i,j]*p[i,j,z]  -> concat[i][1408 + h*128 + z]
// ---------------------------------------------------------------------------
__global__ __launch_bounds__(256) void opair_kernel(
    const float* __restrict__ att, const float* __restrict__ p,
    float* __restrict__ concat)
{
    int i = blockIdx.x;
    int t = threadIdx.x;
    int z = t & 127, jj = t >> 7;
    __shared__ float att_s[8][768];
    __shared__ float red[2][128][8];
    for (int idx = t; idx < 8*768; idx += 256) {
        int h = idx / 768, j = idx % 768;
        att_s[h][j] = att[((size_t)h*768 + i)*768 + j];
    }
    __syncthreads();
    float acc[8] = {0.f,0.f,0.f,0.f,0.f,0.f,0.f,0.f};
    const float* prow = p + (size_t)i*(768*128) + z;
    #pragma unroll 4
    for (int j = jj; j < 768; j += 2) {
        float pv = prow[(size_t)j*128];
        #pragma unroll
        for (int h = 0; h < 8; h++) acc[h] += att_s[h][j]*pv;
    }
    #pragma unroll
    for (int h = 0; h < 8; h++) red[jj][z][h] = acc[h];
    __syncthreads();
    if (jj == 0) {
        #pragma unroll
        for (int h = 0; h < 8; h++)
            concat[i*CONCAT + 1408 + h*128 + z] = red[0][z][h] + red[1][z][h];
    }
}

// ---------------------------------------------------------------------------
// s_out = LN(A + B) * g + be  (rows of 256)
// ---------------------------------------------------------------------------
__global__ __launch_bounds__(256) void add_ln_kernel(
    const float* __restrict__ A, const float* __restrict__ Bv,
    const float* __restrict__ g, const float* __restrict__ be,
    float* __restrict__ out)
{
    int i = blockIdx.x, t = threadIdx.x;
    float x = A[i*256 + t] + Bv[i*256 + t];
    __shared__ float red[4];
    float v = x;
    #pragma unroll
    for (int m = 1; m < 64; m <<= 1) v += __shfl_xor(v, m);
    if ((t & 63) == 0) red[t >> 6] = v;
    __syncthreads();
    float mu = (red[0] + red[1] + red[2] + red[3]) * (1.0f/256.0f);
    __syncthreads();
    float d = x - mu;
    float v2 = d*d;
    #pragma unroll
    for (int m = 1; m < 64; m <<= 1) v2 += __shfl_xor(v2, m);
    if ((t & 63) == 0) red[t >> 6] = v2;
    __syncthreads();
    float var = (red[0] + red[1] + red[2] + red[3]) * (1.0f/256.0f);
    out[i*256 + t] = d * (1.0f/sqrtf(var + 1e-5f)) * g[t] + be[t];
}

// ---------------------------------------------------------------------------
// upd[i][d] = (s2[i,:] . Wbb[d,:] + bbb[d]) * mask[i],  d<6
// ---------------------------------------------------------------------------
__global__ __launch_bounds__(256) void upd_kernel(
    const float* __restrict__ s2, const float* __restrict__ Wbb,
    const float* __restrict__ bbb, const float* __restrict__ mask,
    float* __restrict__ upd)
{
    int i = blockIdx.x, t = threadIdx.x;
    __shared__ float row[256];
    row[t] = s2[i*256 + t];
    __syncthreads();
    if (t < 6) {
        float acc = bbb[t];
        #pragma unroll 8
        for (int c = 0; c < 256; c++) acc += row[c]*Wbb[t*256 + c];
        upd[i*6 + t] = acc * mask[i];
    }
}

// ---------------------------------------------------------------------------
// quaternion -> rotation, compose with rot, update trans
// ---------------------------------------------------------------------------
__global__ void frame_kernel(
    const float* __restrict__ upd, const float* __restrict__ rot,
    const float* __restrict__ trans, float* __restrict__ rot_out,
    float* __restrict__ trans_out)
{
    int i = blockIdx.x*64 + threadIdx.x;
    if (i >= NN) return;
    float u0 = upd[i*6+0], u1 = upd[i*6+1], u2 = upd[i*6+2];
    float t0 = upd[i*6+3], t1 = upd[i*6+4], t2 = upd[i*6+5];
    float n = sqrtf(1.f + u0*u0 + u1*u1 + u2*u2);
    float w = 1.f/n, x = u0/n, y = u1/n, z = u2/n;
    float R[3][3];
    R[0][0] = 1.f - 2.f*(y*y + z*z); R[0][1] = 2.f*(x*y - w*z);       R[0][2] = 2.f*(x*z + w*y);
    R[1][0] = 2.f*(x*y + w*z);       R[1][1] = 1.f - 2.f*(x*x + z*z); R[1][2] = 2.f*(y*z - w*x);
    R[2][0] = 2.f*(x*z - w*y);       R[2][1] = 2.f*(y*z + w*x);       R[2][2] = 1.f - 2.f*(x*x + y*y);
    const float* Ri = rot + i*9;
    #pragma unroll
    for (int a = 0; a < 3; a++) {
        #pragma unroll
        for (int b = 0; b < 3; b++) {
            float acc = 0.f;
            #pragma unroll
            for (int j = 0; j < 3; j++) acc += Ri[a*3+j]*R[j][b];
            rot_out[i*9 + a*3 + b] = acc;
        }
        trans_out[i*3 + a] = trans[i*3 + a] + Ri[a*3+0]*t0 + Ri[a*3+1]*t1 + Ri[a*3+2]*t2;
    }
}

// ---------------------------------------------------------------------------
extern "C" void kernel_launch(void* const* d_in, const int* in_sizes, int n_in,
                              void* d_out, int out_size, void* d_ws, size_t ws_size,
                              hipStream_t stream)
{
    const float* s      = (const float*)d_in[0];
    const float* p      = (const float*)d_in[1];
    const float* rot    = (const float*)d_in[2];
    const float* trans  = (const float*)d_in[3];
    const float* mask   = (const float*)d_in[4];
    const float* Wq     = (const float*)d_in[5];
    const float* bq     = (const float*)d_in[6];
    const float* Wkv    = (const float*)d_in[7];
    const float* bkv    = (const float*)d_in[8];
    const float* Wqp    = (const float*)d_in[9];
    const float* bqp    = (const float*)d_in[10];
    const float* Wkvp   = (const float*)d_in[11];
    const float* bkvp   = (const float*)d_in[12];
    const float* Wpb    = (const float*)d_in[13];
    const float* bpb    = (const float*)d_in[14];
    const float* Wo     = (const float*)d_in[15];
    const float* bo     = (const float*)d_in[16];
    const float* Wt1    = (const float*)d_in[17];
    const float* bt1    = (const float*)d_in[18];
    const float* Wt2    = (const float*)d_in[19];
    const float* bt2    = (const float*)d_in[20];
    const float* Wt3    = (const float*)d_in[21];
    const float* bt3    = (const float*)d_in[22];
    const float* Wbb    = (const float*)d_in[23];
    const float* bbb    = (const float*)d_in[24];
    const float* head_w = (const float*)d_in[25];
    const float* g1     = (const float*)d_in[26];
    const float* be1    = (const float*)d_in[27];
    const float* g2     = (const float*)d_in[28];
    const float* be2    = (const float*)d_in[29];

    float* out = (float*)d_out;
    float* ws  = (float*)d_ws;

    // Workspace layout (floats)
    size_t off = 0;
    float* qb      = ws + off; off += (size_t)NN*1024;
    float* kvb     = ws + off; off += (size_t)NN*2048;
    float* qpraw   = ws + off; off += (size_t)NN*192;
    float* kvpraw  = ws + off; off += (size_t)NN*480;
    float* qpb     = ws + off; off += (size_t)NN*192;
    float* kpb     = ws + off; off += (size_t)NN*192;
    float* vpb     = ws + off; off += (size_t)NN*288;
    float* Qsq     = ws + off; off += (size_t)NN*8;
    float* Ksq     = ws + off; off += (size_t)NN*8;
    float* hw8     = ws + off; off += 8;
    float* att     = ws + off; off += (size_t)8*768*768;
    float* optb    = ws + off; off += (size_t)NN*288;
    float* concat  = ws + off; off += (size_t)NN*CONCAT;
    float* ipa     = ws + off; off += (size_t)NN*256;
    float* s1      = ws + off; off += (size_t)NN*256;
    float* x1      = ws + off; off += (size_t)NN*256;
    float* x2      = ws + off; off += (size_t)NN*256;
    float* y3      = ws + off; off += (size_t)NN*256;
    float* updb    = ws + off; off += (size_t)NN*6;

    dim3 t16(16, 16);

    // 1) Projections from s
    gemm_nt<<<dim3(1024/32, 768/32), t16, 0, stream>>>(s, 256, Wq,   bq,   qb,     1024, 768, 1024, 256, 0);
    gemm_nt<<<dim3(2048/32, 768/32), t16, 0, stream>>>(s, 256, Wkv,  bkv,  kvb,    2048, 768, 2048, 256, 0);
    gemm_nt<<<dim3(192/32,  768/32), t16, 0, stream>>>(s, 256, Wqp,  bqp,  qpraw,  192,  768, 192,  256, 0);
    gemm_nt<<<dim3(480/32,  768/32), t16, 0, stream>>>(s, 256, Wkvp, bkvp, kvpraw, 480,  768, 480,  256, 0);

    // 2) Small prep
    prep_kernel<<<1, 64, 0, stream>>>(head_w, hw8);
    rotate_kernel<<<(NN*HH*28 + 255)/256, 256, 0, stream>>>(qpraw, kvpraw, rot, trans, qpb, kpb, vpb);
    sq_kernel<<<(NN*HH + 255)/256, 256, 0, stream>>>(qpb, kpb, Qsq, Ksq);

    // 3) bias_p streamed into att, then logits RMW, softmax
    biasp_kernel<<<(768*768)/16, 256, 0, stream>>>(p, Wpb, bpb, att);
    logits_kernel<<<dim3(24, 24, 8), t16, 0, stream>>>(qb, kvb, qpb, kpb, Qsq, Ksq, mask, hw8, att);
    softmax_kernel<<<dim3(768, 8), 64, 0, stream>>>(att);

    // 4) Attention outputs -> concat buffer
    attv_kernel<<<dim3(128/32, 768/32, 8), t16, 0, stream>>>(att, kvb, concat);
    optv_kernel<<<dim3(768, 8), 64, 0, stream>>>(att, vpb, optb);
    optfinal_kernel<<<(NN*96 + 255)/256, 256, 0, stream>>>(optb, rot, trans, concat);
    opair_kernel<<<768, 256, 0, stream>>>(att, p, concat);

    // 5) Output projection + residual LN
    gemm_nt<<<dim3(256/32, 768/32), t16, 0, stream>>>(concat, CONCAT, Wo, bo, ipa, 256, 768, 256, 2432, 0);
    add_ln_kernel<<<768, 256, 0, stream>>>(s, ipa, g1, be1, s1);

    // 6) Transition MLP + residual LN  (s2 written straight to output)
    gemm_nt<<<dim3(256/32, 768/32), t16, 0, stream>>>(s1, 256, Wt1, bt1, x1, 256, 768, 256, 256, 1);
    gemm_nt<<<dim3(256/32, 768/32), t16, 0, stream>>>(x1, 256, Wt2, bt2, x2, 256, 768, 256, 256, 1);
    gemm_nt<<<dim3(256/32, 768/32), t16, 0, stream>>>(x2, 256, Wt3, bt3, y3, 256, 768, 256, 256, 0);
    add_ln_kernel<<<768, 256, 0, stream>>>(s1, y3, g2, be2, out);

    // 7) Backbone update + frame composition
    upd_kernel<<<768, 256, 0, stream>>>(out, Wbb, bbb, mask, updb);
    frame_kernel<<<12, 64, 0, stream>>>(updb, rot, trans, out + (size_t)NN*256, out + (size_t)NN*256 + (size_t)NN*9);
}

// Round 2
// 463.376 us; speedup vs baseline: 1.6131x; 1.6131x over previous
//
#include <hip/hip_runtime.h>
#include <hip/hip_bf16.h>
#include <math.h>

// Problem constants
#define NN 768
#define CS 256
#define CZ 128
#define CH 128
#define HH 8
#define PQK 8
#define PV 12
#define CONCAT 2432   // 1024 + 288 + 96 + 1024
#define ATT_HSTRIDE (768*768)

typedef __bf16 v8bf __attribute__((ext_vector_type(8)));
typedef float  v4f  __attribute__((ext_vector_type(4)));

__device__ inline unsigned short f2bf(float f) {
    union { float f; unsigned u; } v; v.f = f;
    unsigned r = v.u + 0x7FFFu + ((v.u >> 16) & 1u);
    return (unsigned short)(r >> 16);
}

// ---------------------------------------------------------------------------
// Batched f32 -> bf16 conversion for s + all weight matrices (one launch)
// ---------------------------------------------------------------------------
#define NCVT 9
struct CvtDesc {
    const float* src[NCVT];
    unsigned short* dst[NCVT];
    int nelem[NCVT];
    int blk_start[NCVT + 1];
};

__global__ __launch_bounds__(256) void cvt_many(CvtDesc d)
{
    int b = blockIdx.x;
    int seg = 0;
    #pragma unroll
    for (int i = 0; i < NCVT - 1; i++) if (b >= d.blk_start[i + 1]) seg = i + 1;
    int local = b - d.blk_start[seg];
    int base = local * 2048 + threadIdx.x;
    const float* s = d.src[seg];
    unsigned short* o = d.dst[seg];
    int n = d.nelem[seg];
    #pragma unroll
    for (int r = 0; r < 8; r++) {
        int idx = base + r * 256;
        if (idx < n) o[idx] = f2bf(s[idx]);
    }
}

// ---------------------------------------------------------------------------
// MFMA bf16 GEMM: C[M,D] = A[M,K](bf16) @ W[D,K](bf16)^T + bias
// 64x64 tile, 4 waves, 16x16x32 MFMA. M must be multiple of 64, K of 32.
// SPLITK>1: C pre-initialized with bias, atomicAdd partials (MODE/RELU unused)
// MODE: 0 = f32 out, 1 = f32 + bf16 out, 2 = bf16 out only
// ---------------------------------------------------------------------------
template<int SPLITK, int MODE, int RELU>
__global__ __launch_bounds__(256) void mfma_gemm(
    const unsigned short* __restrict__ A,
    const unsigned short* __restrict__ W,
    const float* __restrict__ bias,
    float* __restrict__ C,
    unsigned short* __restrict__ Cb,
    int D, int K, int ldc)
{
    __shared__ unsigned short As[64][40];   // +8 pad: conflict-free b128 frags
    __shared__ unsigned short Ws[64][40];
    int tid = threadIdx.x;
    int bi = blockIdx.y * 64;
    int bd = blockIdx.x * 64;
    int kpb = K / SPLITK;
    int k0b = blockIdx.z * kpb;
    int lane = tid & 63;
    int wid = tid >> 6;
    int wr = (wid >> 1) * 32, wc = (wid & 1) * 32;
    v4f acc[2][2] = {};
    int lrow = tid >> 2;
    int lcol = (tid & 3) * 8;
    const unsigned short* Ap = A + (size_t)(bi + lrow) * K + lcol;
    const unsigned short* Wp = W + (size_t)(bd + lrow) * K + lcol;
    bool wv = (bd + lrow) < D;
    int fr = lane & 15, fc = (lane >> 4) * 8;

    for (int k0 = k0b; k0 < k0b + kpb; k0 += 32) {
        *(int4*)&As[lrow][lcol] = *(const int4*)(Ap + k0);
        int4 wz = {0, 0, 0, 0};
        *(int4*)&Ws[lrow][lcol] = wv ? *(const int4*)(Wp + k0) : wz;
        __syncthreads();
        v8bf a0 = *(const v8bf*)&As[wr + fr][fc];
        v8bf a1 = *(const v8bf*)&As[wr + 16 + fr][fc];
        v8bf b0 = *(const v8bf*)&Ws[wc + fr][fc];
        v8bf b1 = *(const v8bf*)&Ws[wc + 16 + fr][fc];
        acc[0][0] = __builtin_amdgcn_mfma_f32_16x16x32_bf16(a0, b0, acc[0][0], 0, 0, 0);
        acc[0][1] = __builtin_amdgcn_mfma_f32_16x16x32_bf16(a0, b1, acc[0][1], 0, 0, 0);
        acc[1][0] = __builtin_amdgcn_mfma_f32_16x16x32_bf16(a1, b0, acc[1][0], 0, 0, 0);
        acc[1][1] = __builtin_amdgcn_mfma_f32_16x16x32_bf16(a1, b1, acc[1][1], 0, 0, 0);
        __syncthreads();
    }
    int mrow = (lane >> 4) * 4;
    #pragma unroll
    for (int mi = 0; mi < 2; mi++) {
        #pragma unroll
        for (int ni = 0; ni < 2; ni++) {
            int d = bd + wc + ni * 16 + fr;
            if (d < D) {
                #pragma unroll
                for (int r = 0; r < 4; r++) {
                    int m = bi + wr + mi * 16 + mrow + r;
                    float v = acc[mi][ni][r];
                    if (SPLITK > 1) {
                        atomicAdd(&C[(size_t)m * ldc + d], v);
                    } else {
                        v += bias[d];
                        if (RELU) v = fmaxf(v, 0.f);
                        if (MODE != 2) C[(size_t)m * ldc + d] = v;
                        if (MODE >= 1) Cb[(size_t)m * ldc + d] = f2bf(v);
                    }
                }
            }
        }
    }
}

// ipa[i][d] = bo[d]   (pre-bias for split-K atomic GEMM)
__global__ __launch_bounds__(256) void ipa_init_kernel(
    const float* __restrict__ bo, float* __restrict__ ipa)
{
    ipa[blockIdx.x * 256 + threadIdx.x] = bo[threadIdx.x];
}

// ---------------------------------------------------------------------------
// hw[h] = softplus(head_w[h]) * sqrt(1/108)
// ---------------------------------------------------------------------------
__global__ void prep_kernel(const float* __restrict__ head_w, float* __restrict__ hw8)
{
    int t = threadIdx.x;
    if (t < HH) {
        float x = head_w[t];
        float sp = (x > 20.f) ? x : log1pf(expf(x));
        hw8[t] = sp * 0.09622504486493764f;
    }
}

// ---------------------------------------------------------------------------
// Rotate q/k/v points into global frame
// ---------------------------------------------------------------------------
__global__ void rotate_kernel(
    const float* __restrict__ qpraw, const float* __restrict__ kvpraw,
    const float* __restrict__ rot, const float* __restrict__ trans,
    float* __restrict__ qpb, float* __restrict__ kpb, float* __restrict__ vpb)
{
    int id = blockIdx.x*256 + threadIdx.x;
    if (id >= NN*HH*28) return;
    int i = id / (HH*28);
    int rem = id % (HH*28);
    int h = rem / 28;
    int idx = rem % 28;
    const float* R = rot + i*9;
    const float* T = trans + i*3;
    float s0, s1, s2;
    if (idx < 8) {
        int pp = idx;
        s0 = qpraw[i*192 +   0 + h*8 + pp];
        s1 = qpraw[i*192 +  64 + h*8 + pp];
        s2 = qpraw[i*192 + 128 + h*8 + pp];
    } else {
        int pp = idx - 8;
        s0 = kvpraw[i*480 +   0 + h*20 + pp];
        s1 = kvpraw[i*480 + 160 + h*20 + pp];
        s2 = kvpraw[i*480 + 320 + h*20 + pp];
    }
    float o0 = R[0]*s0 + R[1]*s1 + R[2]*s2 + T[0];
    float o1 = R[3]*s0 + R[4]*s1 + R[5]*s2 + T[1];
    float o2 = R[6]*s0 + R[7]*s1 + R[8]*s2 + T[2];
    float* dst;
    if (idx < 8)       dst = qpb + i*192 + h*24 + idx*3;
    else if (idx < 16) dst = kpb + i*192 + h*24 + (idx-8)*3;
    else               dst = vpb + i*288 + h*36 + (idx-16)*3;
    dst[0] = o0; dst[1] = o1; dst[2] = o2;
}

__global__ void sq_kernel(const float* __restrict__ qpb, const float* __restrict__ kpb,
                          float* __restrict__ Qsq, float* __restrict__ Ksq)
{
    int id = blockIdx.x*256 + threadIdx.x;
    if (id >= NN*HH) return;
    const float* qq = qpb + id*24;
    const float* kk = kpb + id*24;
    float a = 0.f, b = 0.f;
    #pragma unroll
    for (int m = 0; m < 24; m++) { a += qq[m]*qq[m]; b += kk[m]*kk[m]; }
    Qsq[id] = a; Ksq[id] = b;
}

// ---------------------------------------------------------------------------
// bias_p folded into att
// ---------------------------------------------------------------------------
__global__ __launch_bounds__(256) void biasp_kernel(
    const float* __restrict__ p, const float* __restrict__ Wpb,
    const float* __restrict__ bpb, float* __restrict__ att)
{
    __shared__ float wpb_s[8][128];
    __shared__ float bpb_s[8];
    int tid = threadIdx.x;
    for (int idx = tid; idx < 1024; idx += 256) wpb_s[idx >> 7][idx & 127] = Wpb[idx];
    if (tid < 8) bpb_s[tid] = bpb[tid];
    __syncthreads();
    int lane = tid & 63, wv = tid >> 6;
    int pl = lane >> 4, zg = lane & 15;
    size_t pair = (size_t)blockIdx.x*16 + wv*4 + pl;
    const float* prow = p + pair*128 + zg*8;
    float4 a0 = *(const float4*)prow;
    float4 a1 = *(const float4*)(prow + 4);
    float acc[8];
    #pragma unroll
    for (int h = 0; h < 8; h++) {
        const float* wr = &wpb_s[h][zg*8];
        acc[h] = a0.x*wr[0] + a0.y*wr[1] + a0.z*wr[2] + a0.w*wr[3]
               + a1.x*wr[4] + a1.y*wr[5] + a1.z*wr[6] + a1.w*wr[7];
    }
    #pragma unroll
    for (int m = 1; m < 16; m <<= 1) {
        #pragma unroll
        for (int h = 0; h < 8; h++) acc[h] += __shfl_xor(acc[h], m);
    }
    if (zg == 0) {
        #pragma unroll
        for (int h = 0; h < 8; h++)
            att[(size_t)h*ATT_HSTRIDE + pair] = 0.57735026918962576f*(acc[h] + bpb_s[h]);
    }
}

// ---------------------------------------------------------------------------
// Logits RMW
// ---------------------------------------------------------------------------
__global__ __launch_bounds__(256) void logits_kernel(
    const float* __restrict__ qb, const float* __restrict__ kvb,
    const float* __restrict__ qpb, const float* __restrict__ kpb,
    const float* __restrict__ Qsq, const float* __restrict__ Ksq,
    const float* __restrict__ mask, const float* __restrict__ hw8,
    float* __restrict__ att)
{
    __shared__ float qs[32][129];
    __shared__ float ks[32][129];
    __shared__ float qps[32][25];
    __shared__ float kps[32][25];
    __shared__ float Qs[32], Ks[32], Mi[32], Mj[32];
    int h = blockIdx.z;
    int i0 = blockIdx.y*32, j0 = blockIdx.x*32;
    int tx = threadIdx.x, ty = threadIdx.y;
    int tid = ty*16 + tx;
    for (int idx = tid; idx < 32*128; idx += 256) {
        int r = idx >> 7, c = idx & 127;
        qs[r][c] = qb[(i0+r)*1024 + h*128 + c];
        ks[r][c] = kvb[(j0+r)*2048 + h*256 + c];
    }
    for (int idx = tid; idx < 32*24; idx += 256) {
        int r = idx / 24, m = idx % 24;
        qps[r][m] = qpb[(i0+r)*192 + h*24 + m];
        kps[r][m] = kpb[(j0+r)*192 + h*24 + m];
    }
    if (tid < 32) {
        Qs[tid] = Qsq[(i0+tid)*8 + h];
        Ks[tid] = Ksq[(j0+tid)*8 + h];
        Mi[tid] = mask[i0+tid];
        Mj[tid] = mask[j0+tid];
    }
    __syncthreads();
    float hw = hw8[h];
    float acc[2][2] = {{0.f,0.f},{0.f,0.f}};
    float accp[2][2] = {{0.f,0.f},{0.f,0.f}};
    #pragma unroll 4
    for (int kk = 0; kk < 128; kk++) {
        float a0 = qs[ty][kk], a1 = qs[ty+16][kk];
        float b0 = ks[tx][kk], b1 = ks[tx+16][kk];
        acc[0][0] += a0*b0; acc[0][1] += a0*b1;
        acc[1][0] += a1*b0; acc[1][1] += a1*b1;
    }
    #pragma unroll
    for (int m = 0; m < 24; m++) {
        float a0 = qps[ty][m], a1 = qps[ty+16][m];
        float b0 = kps[tx][m], b1 = kps[tx+16][m];
        accp[0][0] += a0*b0; accp[0][1] += a0*b1;
        accp[1][0] += a1*b0; accp[1][1] += a1*b1;
    }
    const float scale_qk = 0.05103103630798288f;  // sqrt(1/384)
    #pragma unroll
    for (int a = 0; a < 2; a++) {
        #pragma unroll
        for (int b = 0; b < 2; b++) {
            int r = ty + a*16, c = tx + b*16;
            size_t aidx = (size_t)h*ATT_HSTRIDE + (size_t)(i0+r)*768 + (j0+c);
            float v = att[aidx];
            v += acc[a][b]*scale_qk + hw*accp[a][b]
               - 0.5f*hw*(Qs[r] + Ks[c])
               + 100000.0f*(Mi[r]*Mj[c] - 1.0f);
            att[aidx] = v;
        }
    }
}

// ---------------------------------------------------------------------------
// Softmax over j
// ---------------------------------------------------------------------------
__global__ __launch_bounds__(64) void softmax_kernel(float* __restrict__ att)
{
    int i = blockIdx.x, h = blockIdx.y, lane = threadIdx.x;
    float* row = att + ((size_t)h*768 + i)*768;
    float v[12];
    float m = -3.0e38f;
    #pragma unroll
    for (int e = 0; e < 12; e++) { v[e] = row[lane + e*64]; m = fmaxf(m, v[e]); }
    #pragma unroll
    for (int d = 1; d < 64; d <<= 1) m = fmaxf(m, __shfl_xor(m, d));
    float ssum = 0.f;
    #pragma unroll
    for (int e = 0; e < 12; e++) { v[e] = expf(v[e] - m); ssum += v[e]; }
    #pragma unroll
    for (int d = 1; d < 64; d <<= 1) ssum += __shfl_xor(ssum, d);
    float inv = 1.0f/ssum;
    #pragma unroll
    for (int e = 0; e < 12; e++) row[lane + e*64] = v[e]*inv;
}

// ---------------------------------------------------------------------------
// o = att @ v  -> concat (bf16) [i][h*128+c]
// ---------------------------------------------------------------------------
__global__ __launch_bounds__(256) void attv_kernel(
    const float* __restrict__ att, const float* __restrict__ kvb,
    unsigned short* __restrict__ concat)
{
    __shared__ float as_[32][33];
    __shared__ float vs[32][33];
    int h = blockIdx.z;
    int i0 = blockIdx.y*32, c0 = blockIdx.x*32;
    int tx = threadIdx.x, ty = threadIdx.y;
    float acc[2][2] = {{0.f,0.f},{0.f,0.f}};
    for (int k0 = 0; k0 < 768; k0 += 32) {
        #pragma unroll
        for (int a = 0; a < 2; a++) {
            #pragma unroll
            for (int b = 0; b < 2; b++) {
                int r = ty + a*16, c = tx + b*16;
                as_[r][c] = att[(size_t)h*ATT_HSTRIDE + (size_t)(i0+r)*768 + k0 + c];
                vs[r][c]  = kvb[(k0+r)*2048 + h*256 + 128 + c0 + c];
            }
        }
        __syncthreads();
        #pragma unroll 8
        for (int kk = 0; kk < 32; kk++) {
            float a0 = as_[ty][kk],   a1 = as_[ty+16][kk];
            float b0 = vs[kk][tx],    b1 = vs[kk][tx+16];
            acc[0][0] += a0*b0; acc[0][1] += a0*b1;
            acc[1][0] += a1*b0; acc[1][1] += a1*b1;
        }
        __syncthreads();
    }
    #pragma unroll
    for (int a = 0; a < 2; a++) {
        #pragma unroll
        for (int b = 0; b < 2; b++) {
            int gi = i0 + ty + a*16, gc = c0 + tx + b*16;
            concat[gi*CONCAT + h*128 + gc] = f2bf(acc[a][b]);
        }
    }
}

// ---------------------------------------------------------------------------
// opt[i][h][p][x] = sum_j att[h,i,j]*vp[j,h,p,x]
// ---------------------------------------------------------------------------
__global__ __launch_bounds__(64) void optv_kernel(
    const float* __restrict__ att, const float* __restrict__ vpb,
    float* __restrict__ optb)
{
    int i = blockIdx.x, h = blockIdx.y, t = threadIdx.x;
    __shared__ float arow[768];
    const float* arp = att + ((size_t)h*768 + i)*768;
    for (int idx = t; idx < 768; idx += 64) arow[idx] = arp[idx];
    __syncthreads();
    if (t < 36) {
        float acc = 0.f;
        #pragma unroll 4
        for (int j = 0; j < 768; j++) acc += arow[j]*vpb[j*288 + h*36 + t];
        optb[i*288 + h*36 + t] = acc;
    }
}

// ---------------------------------------------------------------------------
// opt2 = rot^T (opt - trans); write opt_flat + opt_norm into concat (bf16)
// ---------------------------------------------------------------------------
__global__ void optfinal_kernel(
    const float* __restrict__ optb, const float* __restrict__ rot,
    const float* __restrict__ trans, unsigned short* __restrict__ concat)
{
    int id = blockIdx.x*256 + threadIdx.x;
    if (id >= NN*96) return;
    int i = id / 96;
    int hp = id % 96;
    const float* ob = optb + i*288 + hp*3;
    float y0 = ob[0] - trans[i*3+0];
    float y1 = ob[1] - trans[i*3+1];
    float y2 = ob[2] - trans[i*3+2];
    const float* R = rot + i*9;
    float o0 = R[0]*y0 + R[3]*y1 + R[6]*y2;
    float o1 = R[1]*y0 + R[4]*y1 + R[7]*y2;
    float o2 = R[2]*y0 + R[5]*y1 + R[8]*y2;
    float nrm = sqrtf(o0*o0 + o1*o1 + o2*o2 + 1e-8f);
    unsigned short* cb = concat + i*CONCAT;
    cb[1024 +   0 + hp] = f2bf(o0);
    cb[1024 +  96 + hp] = f2bf(o1);
    cb[1024 + 192 + hp] = f2bf(o2);
    cb[1312 + hp] = f2bf(nrm);
}

// ---------------------------------------------------------------------------
// opair -> concat (bf16)
// ---------------------------------------------------------------------------
__global__ __launch_bounds__(256) void opair_kernel(
    const float* __restrict__ att, const float* __restrict__ p,
    unsigned short* __restrict__ concat)
{
    int i = blockIdx.x;
    int t = threadIdx.x;
    int z = t & 127, jj = t >> 7;
    __shared__ float att_s[8][768];
    __shared__ float red[2][128][8];
    for (int idx = t; idx < 8*768; idx += 256) {
        int h = idx / 768, j = idx % 768;
        att_s[h][j] = att[((size_t)h*768 + i)*768 + j];
    }
    __syncthreads();
    float acc[8] = {0.f,0.f,0.f,0.f,0.f,0.f,0.f,0.f};
    const float* prow = p + (size_t)i*(768*128) + z;
    #pragma unroll 4
    for (int j = jj; j < 768; j += 2) {
        float pv = prow[(size_t)j*128];
        #pragma unroll
        for (int h = 0; h < 8; h++) acc[h] += att_s[h][j]*pv;
    }
    #pragma unroll
    for (int h = 0; h < 8; h++) red[jj][z][h] = acc[h];
    __syncthreads();
    if (jj == 0) {
        #pragma unroll
        for (int h = 0; h < 8; h++)
            concat[i*CONCAT + 1408 + h*128 + z] = f2bf(red[0][z][h] + red[1][z][h]);
    }
}

// ---------------------------------------------------------------------------
// s_out = LN(A + B) * g + be ; optional bf16 copy
// ---------------------------------------------------------------------------
template<int BF>
__global__ __launch_bounds__(256) void add_ln_kernel(
    const float* __restrict__ A, const float* __restrict__ Bv,
    const float* __restrict__ g, const float* __restrict__ be,
    float* __restrict__ out, unsigned short* __restrict__ outb)
{
    int i = blockIdx.x, t = threadIdx.x;
    float x = A[i*256 + t] + Bv[i*256 + t];
    __shared__ float red[4];
    float v = x;
    #pragma unroll
    for (int m = 1; m < 64; m <<= 1) v += __shfl_xor(v, m);
    if ((t & 63) == 0) red[t >> 6] = v;
    __syncthreads();
    float mu = (red[0] + red[1] + red[2] + red[3]) * (1.0f/256.0f);
    __syncthreads();
    float d = x - mu;
    float v2 = d*d;
    #pragma unroll
    for (int m = 1; m < 64; m <<= 1) v2 += __shfl_xor(v2, m);
    if ((t & 63) == 0) red[t >> 6] = v2;
    __syncthreads();
    float var = (red[0] + red[1] + red[2] + red[3]) * (1.0f/256.0f);
    float o = d * (1.0f/sqrtf(var + 1e-5f)) * g[t] + be[t];
    out[i*256 + t] = o;
    if (BF) outb[i*256 + t] = f2bf(o);
}

// ---------------------------------------------------------------------------
// upd head
// ---------------------------------------------------------------------------
__global__ __launch_bounds__(256) void upd_kernel(
    const float* __restrict__ s2, const float* __restrict__ Wbb,
    const float* __restrict__ bbb, const float* __restrict__ mask,
    float* __restrict__ upd)
{
    int i = blockIdx.x, t = threadIdx.x;
    __shared__ float row[256];
    row[t] = s2[i*256 + t];
    __syncthreads();
    if (t < 6) {
        float acc = bbb[t];
        #pragma unroll 8
        for (int c = 0; c < 256; c++) acc += row[c]*Wbb[t*256 + c];
        upd[i*6 + t] = acc * mask[i];
    }
}

// ---------------------------------------------------------------------------
// frame composition
// ---------------------------------------------------------------------------
__global__ void frame_kernel(
    const float* __restrict__ upd, const float* __restrict__ rot,
    const float* __restrict__ trans, float* __restrict__ rot_out,
    float* __restrict__ trans_out)
{
    int i = blockIdx.x*64 + threadIdx.x;
    if (i >= NN) return;
    float u0 = upd[i*6+0], u1 = upd[i*6+1], u2 = upd[i*6+2];
    float t0 = upd[i*6+3], t1 = upd[i*6+4], t2 = upd[i*6+5];
    float n = sqrtf(1.f + u0*u0 + u1*u1 + u2*u2);
    float w = 1.f/n, x = u0/n, y = u1/n, z = u2/n;
    float R[3][3];
    R[0][0] = 1.f - 2.f*(y*y + z*z); R[0][1] = 2.f*(x*y - w*z);       R[0][2] = 2.f*(x*z + w*y);
    R[1][0] = 2.f*(x*y + w*z);       R[1][1] = 1.f - 2.f*(x*x + z*z); R[1][2] = 2.f*(y*z - w*x);
    R[2][0] = 2.f*(x*z - w*y);       R[2][1] = 2.f*(y*z + w*x);       R[2][2] = 1.f - 2.f*(x*x + y*y);
    const float* Ri = rot + i*9;
    #pragma unroll
    for (int a = 0; a < 3; a++) {
        #pragma unroll
        for (int b = 0; b < 3; b++) {
            float acc = 0.f;
            #pragma unroll
            for (int j = 0; j < 3; j++) acc += Ri[a*3+j]*R[j][b];
            rot_out[i*9 + a*3 + b] = acc;
        }
        trans_out[i*3 + a] = trans[i*3 + a] + Ri[a*3+0]*t0 + Ri[a*3+1]*t1 + Ri[a*3+2]*t2;
    }
}

// ---------------------------------------------------------------------------
extern "C" void kernel_launch(void* const* d_in, const int* in_sizes, int n_in,
                              void* d_out, int out_size, void* d_ws, size_t ws_size,
                              hipStream_t stream)
{
    const float* s      = (const float*)d_in[0];
    const float* p      = (const float*)d_in[1];
    const float* rot    = (const float*)d_in[2];
    const float* trans  = (const float*)d_in[3];
    const float* mask   = (const float*)d_in[4];
    const float* Wq     = (const float*)d_in[5];
    const float* bq     = (const float*)d_in[6];
    const float* Wkv    = (const float*)d_in[7];
    const float* bkv    = (const float*)d_in[8];
    const float* Wqp    = (const float*)d_in[9];
    const float* bqp    = (const float*)d_in[10];
    const float* Wkvp   = (const float*)d_in[11];
    const float* bkvp   = (const float*)d_in[12];
    const float* Wpb    = (const float*)d_in[13];
    const float* bpb    = (const float*)d_in[14];
    const float* Wo     = (const float*)d_in[15];
    const float* bo     = (const float*)d_in[16];
    const float* Wt1    = (const float*)d_in[17];
    const float* bt1    = (const float*)d_in[18];
    const float* Wt2    = (const float*)d_in[19];
    const float* bt2    = (const float*)d_in[20];
    const float* Wt3    = (const float*)d_in[21];
    const float* bt3    = (const float*)d_in[22];
    const float* Wbb    = (const float*)d_in[23];
    const float* bbb    = (const float*)d_in[24];
    const float* head_w = (const float*)d_in[25];
    const float* g1     = (const float*)d_in[26];
    const float* be1    = (const float*)d_in[27];
    const float* g2     = (const float*)d_in[28];
    const float* be2    = (const float*)d_in[29];

    float* out = (float*)d_out;
    char*  wsb = (char*)d_ws;

    // Byte allocator, 256B aligned
    size_t off = 0;
    auto alloc = [&](size_t bytes) -> char* {
        char* ptr = wsb + off;
        off += (bytes + 255) & ~(size_t)255;
        return ptr;
    };
    float* qb      = (float*)alloc((size_t)NN*1024*4);
    float* kvb     = (float*)alloc((size_t)NN*2048*4);
    float* qpraw   = (float*)alloc((size_t)NN*192*4);
    float* kvpraw  = (float*)alloc((size_t)NN*480*4);
    float* qpb     = (float*)alloc((size_t)NN*192*4);
    float* kpb     = (float*)alloc((size_t)NN*192*4);
    float* vpb     = (float*)alloc((size_t)NN*288*4);
    float* Qsq     = (float*)alloc((size_t)NN*8*4);
    float* Ksq     = (float*)alloc((size_t)NN*8*4);
    float* hw8     = (float*)alloc(64);
    float* att     = (float*)alloc((size_t)8*768*768*4);
    float* optb    = (float*)alloc((size_t)NN*288*4);
    float* ipa     = (float*)alloc((size_t)NN*256*4);
    float* s1      = (float*)alloc((size_t)NN*256*4);
    float* y3      = (float*)alloc((size_t)NN*256*4);
    float* updb    = (float*)alloc((size_t)NN*6*4);
    unsigned short* s_bf    = (unsigned short*)alloc((size_t)NN*256*2);
    unsigned short* Wq_bf   = (unsigned short*)alloc((size_t)1024*256*2);
    unsigned short* Wkv_bf  = (unsigned short*)alloc((size_t)2048*256*2);
    unsigned short* Wqp_bf  = (unsigned short*)alloc((size_t)192*256*2);
    unsigned short* Wkvp_bf = (unsigned short*)alloc((size_t)480*256*2);
    unsigned short* Wo_bf   = (unsigned short*)alloc((size_t)256*2432*2);
    unsigned short* Wt1_bf  = (unsigned short*)alloc((size_t)256*256*2);
    unsigned short* Wt2_bf  = (unsigned short*)alloc((size_t)256*256*2);
    unsigned short* Wt3_bf  = (unsigned short*)alloc((size_t)256*256*2);
    unsigned short* concat  = (unsigned short*)alloc((size_t)NN*CONCAT*2);
    unsigned short* s1b     = (unsigned short*)alloc((size_t)NN*256*2);
    unsigned short* x1b     = (unsigned short*)alloc((size_t)NN*256*2);
    unsigned short* x2b     = (unsigned short*)alloc((size_t)NN*256*2);

    // 0) Convert s + weights to bf16 (one launch)
    CvtDesc cd;
    const float* csrc[NCVT]    = {s, Wq, Wkv, Wqp, Wkvp, Wo, Wt1, Wt2, Wt3};
    unsigned short* cdst[NCVT] = {s_bf, Wq_bf, Wkv_bf, Wqp_bf, Wkvp_bf, Wo_bf, Wt1_bf, Wt2_bf, Wt3_bf};
    int csz[NCVT] = {NN*256, 1024*256, 2048*256, 192*256, 480*256, 256*2432, 256*256, 256*256, 256*256};
    int cum = 0;
    for (int i2 = 0; i2 < NCVT; i2++) {
        cd.src[i2] = csrc[i2]; cd.dst[i2] = cdst[i2]; cd.nelem[i2] = csz[i2];
        cd.blk_start[i2] = cum;
        cum += (csz[i2] + 2047) / 2048;
    }
    cd.blk_start[NCVT] = cum;
    cvt_many<<<cum, 256, 0, stream>>>(cd);

    // 1) Projections (MFMA bf16)
    mfma_gemm<1,0,0><<<dim3(16,12), 256, 0, stream>>>(s_bf, Wq_bf,   bq,   qb,     nullptr, 1024, 256, 1024);
    mfma_gemm<1,0,0><<<dim3(32,12), 256, 0, stream>>>(s_bf, Wkv_bf,  bkv,  kvb,    nullptr, 2048, 256, 2048);
    mfma_gemm<1,0,0><<<dim3(3,12),  256, 0, stream>>>(s_bf, Wqp_bf,  bqp,  qpraw,  nullptr, 192,  256, 192);
    mfma_gemm<1,0,0><<<dim3(8,12),  256, 0, stream>>>(s_bf, Wkvp_bf, bkvp, kvpraw, nullptr, 480,  256, 480);

    // 2) Small prep
    prep_kernel<<<1, 64, 0, stream>>>(head_w, hw8);
    rotate_kernel<<<(NN*HH*28 + 255)/256, 256, 0, stream>>>(qpraw, kvpraw, rot, trans, qpb, kpb, vpb);
    sq_kernel<<<(NN*HH + 255)/256, 256, 0, stream>>>(qpb, kpb, Qsq, Ksq);

    // 3) bias_p streamed into att, then logits RMW, softmax
    biasp_kernel<<<(768*768)/16, 256, 0, stream>>>(p, Wpb, bpb, att);
    logits_kernel<<<dim3(24, 24, 8), dim3(16,16), 0, stream>>>(qb, kvb, qpb, kpb, Qsq, Ksq, mask, hw8, att);
    softmax_kernel<<<dim3(768, 8), 64, 0, stream>>>(att);

    // 4) Attention outputs -> concat buffer (bf16)
    attv_kernel<<<dim3(4, 24, 8), dim3(16,16), 0, stream>>>(att, kvb, concat);
    optv_kernel<<<dim3(768, 8), 64, 0, stream>>>(att, vpb, optb);
    optfinal_kernel<<<(NN*96 + 255)/256, 256, 0, stream>>>(optb, rot, trans, concat);
    opair_kernel<<<768, 256, 0, stream>>>(att, p, concat);

    // 5) Output projection (split-K MFMA) + residual LN
    ipa_init_kernel<<<768, 256, 0, stream>>>(bo, ipa);
    mfma_gemm<4,0,0><<<dim3(4,12,4), 256, 0, stream>>>(concat, Wo_bf, nullptr, ipa, nullptr, 256, 2432, 256);
    add_ln_kernel<1><<<768, 256, 0, stream>>>(s, ipa, g1, be1, s1, s1b);

    // 6) Transition MLP (MFMA, bf16 chained) + residual LN
    mfma_gemm<1,2,1><<<dim3(4,12), 256, 0, stream>>>(s1b, Wt1_bf, bt1, nullptr, x1b, 256, 256, 256);
    mfma_gemm<1,2,1><<<dim3(4,12), 256, 0, stream>>>(x1b, Wt2_bf, bt2, nullptr, x2b, 256, 256, 256);
    mfma_gemm<1,0,0><<<dim3(4,12), 256, 0, stream>>>(x2b, Wt3_bf, bt3, y3, nullptr, 256, 256, 256);
    add_ln_kernel<0><<<768, 256, 0, stream>>>(s1, y3, g2, be2, out, nullptr);

    // 7) Backbone update + frame composition
    upd_kernel<<<768, 256, 0, stream>>>(out, Wbb, bbb, mask, updb);
    frame_kernel<<<12, 64, 0, stream>>>(updb, rot, trans, out + (size_t)NN*256, out + (size_t)NN*256 + (size_t)NN*9);
}

// Round 3
// 307.438 us; speedup vs baseline: 2.4314x; 1.5072x over previous
//
#include <hip/hip_runtime.h>
#include <hip/hip_bf16.h>
#include <math.h>

// Problem constants
#define NN 768
#define CS 256
#define CZ 128
#define CH 128
#define HH 8
#define PQK 8
#define PV 12
#define CONCAT 2432   // 1024 + 288 + 96 + 1024
#define ATT_HSTRIDE (768*768)

typedef __bf16 v8bf __attribute__((ext_vector_type(8)));
typedef float  v4f  __attribute__((ext_vector_type(4)));
typedef unsigned short ushort_t;

__device__ inline unsigned short f2bf(float f) {
    union { float f; unsigned u; } v; v.f = f;
    unsigned r = v.u + 0x7FFFu + ((v.u >> 16) & 1u);
    return (unsigned short)(r >> 16);
}
__device__ inline float bf2f(unsigned short u) {
    union { unsigned u; float f; } v; v.u = ((unsigned)u) << 16; return v.f;
}

// ---------------------------------------------------------------------------
// Batched f32 -> bf16 conversion for s + all weight matrices (one launch)
// ---------------------------------------------------------------------------
#define NCVT 9
struct CvtDesc {
    const float* src[NCVT];
    unsigned short* dst[NCVT];
    int nelem[NCVT];
    int blk_start[NCVT + 1];
};

__global__ __launch_bounds__(256) void cvt_many(CvtDesc d)
{
    int b = blockIdx.x;
    int seg = 0;
    #pragma unroll
    for (int i = 0; i < NCVT - 1; i++) if (b >= d.blk_start[i + 1]) seg = i + 1;
    int local = b - d.blk_start[seg];
    int base = local * 2048 + threadIdx.x;
    const float* s = d.src[seg];
    unsigned short* o = d.dst[seg];
    int n = d.nelem[seg];
    #pragma unroll
    for (int r = 0; r < 8; r++) {
        int idx = base + r * 256;
        if (idx < n) o[idx] = f2bf(s[idx]);
    }
}

// ---------------------------------------------------------------------------
// MFMA bf16 GEMM: C[M,D] = A[M,K](bf16) @ W[D,K](bf16)^T + bias
// SPLITK>1: C pre-initialized with bias, atomicAdd partials
// MODE: 0 = f32 out, 1 = f32 + bf16 out, 2 = bf16 out only
// ---------------------------------------------------------------------------
template<int SPLITK, int MODE, int RELU>
__global__ __launch_bounds__(256) void mfma_gemm(
    const unsigned short* __restrict__ A,
    const unsigned short* __restrict__ W,
    const float* __restrict__ bias,
    float* __restrict__ C,
    unsigned short* __restrict__ Cb,
    int D, int K, int ldc)
{
    __shared__ unsigned short As[64][40];
    __shared__ unsigned short Ws[64][40];
    int tid = threadIdx.x;
    int bi = blockIdx.y * 64;
    int bd = blockIdx.x * 64;
    int kpb = K / SPLITK;
    int k0b = blockIdx.z * kpb;
    int lane = tid & 63;
    int wid = tid >> 6;
    int wr = (wid >> 1) * 32, wc = (wid & 1) * 32;
    v4f acc[2][2] = {};
    int lrow = tid >> 2;
    int lcol = (tid & 3) * 8;
    const unsigned short* Ap = A + (size_t)(bi + lrow) * K + lcol;
    const unsigned short* Wp = W + (size_t)(bd + lrow) * K + lcol;
    bool wv = (bd + lrow) < D;
    int fr = lane & 15, fc = (lane >> 4) * 8;

    for (int k0 = k0b; k0 < k0b + kpb; k0 += 32) {
        *(int4*)&As[lrow][lcol] = *(const int4*)(Ap + k0);
        int4 wz = {0, 0, 0, 0};
        *(int4*)&Ws[lrow][lcol] = wv ? *(const int4*)(Wp + k0) : wz;
        __syncthreads();
        v8bf a0 = *(const v8bf*)&As[wr + fr][fc];
        v8bf a1 = *(const v8bf*)&As[wr + 16 + fr][fc];
        v8bf b0 = *(const v8bf*)&Ws[wc + fr][fc];
        v8bf b1 = *(const v8bf*)&Ws[wc + 16 + fr][fc];
        acc[0][0] = __builtin_amdgcn_mfma_f32_16x16x32_bf16(a0, b0, acc[0][0], 0, 0, 0);
        acc[0][1] = __builtin_amdgcn_mfma_f32_16x16x32_bf16(a0, b1, acc[0][1], 0, 0, 0);
        acc[1][0] = __builtin_amdgcn_mfma_f32_16x16x32_bf16(a1, b0, acc[1][0], 0, 0, 0);
        acc[1][1] = __builtin_amdgcn_mfma_f32_16x16x32_bf16(a1, b1, acc[1][1], 0, 0, 0);
        __syncthreads();
    }
    int mrow = (lane >> 4) * 4;
    #pragma unroll
    for (int mi = 0; mi < 2; mi++) {
        #pragma unroll
        for (int ni = 0; ni < 2; ni++) {
            int d = bd + wc + ni * 16 + fr;
            if (d < D) {
                #pragma unroll
                for (int r = 0; r < 4; r++) {
                    int m = bi + wr + mi * 16 + mrow + r;
                    float v = acc[mi][ni][r];
                    if (SPLITK > 1) {
                        atomicAdd(&C[(size_t)m * ldc + d], v);
                    } else {
                        v += bias[d];
                        if (RELU) v = fmaxf(v, 0.f);
                        if (MODE != 2) C[(size_t)m * ldc + d] = v;
                        if (MODE >= 1) Cb[(size_t)m * ldc + d] = f2bf(v);
                    }
                }
            }
        }
    }
}

// ipa[i][d] = bo[d]   (pre-bias for split-K atomic GEMM)
__global__ __launch_bounds__(256) void ipa_init_kernel(
    const float* __restrict__ bo, float* __restrict__ ipa)
{
    ipa[blockIdx.x * 256 + threadIdx.x] = bo[threadIdx.x];
}

// ---------------------------------------------------------------------------
__global__ void prep_kernel(const float* __restrict__ head_w, float* __restrict__ hw8)
{
    int t = threadIdx.x;
    if (t < HH) {
        float x = head_w[t];
        float sp = (x > 20.f) ? x : log1pf(expf(x));
        hw8[t] = sp * 0.09622504486493764f;
    }
}

// ---------------------------------------------------------------------------
// Rotate points to global frame. Writes:
//   qpb/kpb f32 [i][h*24+m]       (for Qsq/Ksq)
//   qph/qpl/kph/kpl bf16 [i][h*32+m] (m 0..23 data, 24..31 zero) hi/lo split
//   Vc vp-part bf16: Vc[(h*192+128+pp)*768 + i]
// ---------------------------------------------------------------------------
__global__ void rotate_kernel(
    const float* __restrict__ qpraw, const float* __restrict__ kvpraw,
    const float* __restrict__ rot, const float* __restrict__ trans,
    float* __restrict__ qpb, float* __restrict__ kpb,
    unsigned short* __restrict__ qph, unsigned short* __restrict__ qpl,
    unsigned short* __restrict__ kph, unsigned short* __restrict__ kpl,
    unsigned short* __restrict__ Vc)
{
    int id = blockIdx.x*256 + threadIdx.x;
    if (id >= NN*HH*28) return;
    int i = id / (HH*28);
    int rem = id % (HH*28);
    int h = rem / 28;
    int idx = rem % 28;
    const float* R = rot + i*9;
    const float* T = trans + i*3;
    float s0, s1, s2;
    if (idx < 8) {
        s0 = qpraw[i*192 +   0 + h*8 + idx];
        s1 = qpraw[i*192 +  64 + h*8 + idx];
        s2 = qpraw[i*192 + 128 + h*8 + idx];
    } else {
        int pp = idx - 8;
        s0 = kvpraw[i*480 +   0 + h*20 + pp];
        s1 = kvpraw[i*480 + 160 + h*20 + pp];
        s2 = kvpraw[i*480 + 320 + h*20 + pp];
    }
    float ov[3];
    ov[0] = R[0]*s0 + R[1]*s1 + R[2]*s2 + T[0];
    ov[1] = R[3]*s0 + R[4]*s1 + R[5]*s2 + T[1];
    ov[2] = R[6]*s0 + R[7]*s1 + R[8]*s2 + T[2];
    if (idx < 8) {
        #pragma unroll
        for (int x = 0; x < 3; x++) {
            qpb[i*192 + h*24 + idx*3 + x] = ov[x];
            unsigned short hi = f2bf(ov[x]);
            qph[i*256 + h*32 + idx*3 + x] = hi;
            qpl[i*256 + h*32 + idx*3 + x] = f2bf(ov[x] - bf2f(hi));
        }
        if (idx == 0) {
            #pragma unroll
            for (int m = 24; m < 32; m++) { qph[i*256+h*32+m] = 0; qpl[i*256+h*32+m] = 0; }
        }
    } else if (idx < 16) {
        int pp = idx - 8;
        #pragma unroll
        for (int x = 0; x < 3; x++) {
            kpb[i*192 + h*24 + pp*3 + x] = ov[x];
            unsigned short hi = f2bf(ov[x]);
            kph[i*256 + h*32 + pp*3 + x] = hi;
            kpl[i*256 + h*32 + pp*3 + x] = f2bf(ov[x] - bf2f(hi));
        }
        if (idx == 8) {
            #pragma unroll
            for (int m = 24; m < 32; m++) { kph[i*256+h*32+m] = 0; kpl[i*256+h*32+m] = 0; }
        }
    } else {
        int ppv = idx - 16;
        #pragma unroll
        for (int x = 0; x < 3; x++)
            Vc[((size_t)h*192 + 128 + ppv*3 + x)*768 + i] = f2bf(ov[x]);
    }
}

__global__ void sq_kernel(const float* __restrict__ qpb, const float* __restrict__ kpb,
                          float* __restrict__ Qsq, float* __restrict__ Ksq)
{
    int id = blockIdx.x*256 + threadIdx.x;
    if (id >= NN*HH) return;
    const float* qq = qpb + id*24;
    const float* kk = kpb + id*24;
    float a = 0.f, b = 0.f;
    #pragma unroll
    for (int m = 0; m < 24; m++) { a += qq[m]*qq[m]; b += kk[m]*kk[m]; }
    Qsq[id] = a; Ksq[id] = b;
}

// ---------------------------------------------------------------------------
// Vc v-part: Vc[h][c][j] = kv_bf[j][h*256+128+c]  (32j x 128c tile transpose)
// ---------------------------------------------------------------------------
__global__ __launch_bounds__(256) void vtrans_kernel(
    const unsigned short* __restrict__ kv_bf, unsigned short* __restrict__ Vc)
{
    __shared__ unsigned short tile[32][136];
    int h = blockIdx.x & 7, jt = blockIdx.x >> 3;
    int t = threadIdx.x;
    int r = t >> 3, c0 = (t & 7) * 16;
    const unsigned short* src = kv_bf + (size_t)(jt*32 + r)*2048 + h*256 + 128 + c0;
    *(int4*)&tile[r][c0]     = *(const int4*)src;
    *(int4*)&tile[r][c0 + 8] = *(const int4*)(src + 8);
    __syncthreads();
    int c = t >> 1, jh = (t & 1) * 16;
    unsigned short tmp[16];
    #pragma unroll
    for (int k = 0; k < 16; k++) tmp[k] = tile[jh + k][c];
    unsigned short* dst = Vc + ((size_t)h*192 + c)*768 + jt*32 + jh;
    *(int4*)dst       = *(int4*)&tmp[0];
    *(int4*)(dst + 8) = *(int4*)&tmp[8];
}

// ---------------------------------------------------------------------------
// bias_p folded into att (f32)
// ---------------------------------------------------------------------------
__global__ __launch_bounds__(256) void biasp_kernel(
    const float* __restrict__ p, const float* __restrict__ Wpb,
    const float* __restrict__ bpb, float* __restrict__ att)
{
    __shared__ float wpb_s[8][128];
    __shared__ float bpb_s[8];
    int tid = threadIdx.x;
    for (int idx = tid; idx < 1024; idx += 256) wpb_s[idx >> 7][idx & 127] = Wpb[idx];
    if (tid < 8) bpb_s[tid] = bpb[tid];
    __syncthreads();
    int lane = tid & 63, wv = tid >> 6;
    int pl = lane >> 4, zg = lane & 15;
    size_t pair = (size_t)blockIdx.x*16 + wv*4 + pl;
    const float* prow = p + pair*128 + zg*8;
    float4 a0 = *(const float4*)prow;
    float4 a1 = *(const float4*)(prow + 4);
    float acc[8];
    #pragma unroll
    for (int h = 0; h < 8; h++) {
        const float* wr = &wpb_s[h][zg*8];
        acc[h] = a0.x*wr[0] + a0.y*wr[1] + a0.z*wr[2] + a0.w*wr[3]
               + a1.x*wr[4] + a1.y*wr[5] + a1.z*wr[6] + a1.w*wr[7];
    }
    #pragma unroll
    for (int m = 1; m < 16; m <<= 1) {
        #pragma unroll
        for (int h = 0; h < 8; h++) acc[h] += __shfl_xor(acc[h], m);
    }
    if (zg == 0) {
        #pragma unroll
        for (int h = 0; h < 8; h++)
            att[(size_t)h*ATT_HSTRIDE + pair] = 0.57735026918962576f*(acc[h] + bpb_s[h]);
    }
}

// ---------------------------------------------------------------------------
// Logits via MFMA: att += scale*q.k + hw*(qp.kp split-bf16) - 0.5hw(|qp|²+|kp|²) + mask
// grid (12 j-tiles, 12 i-tiles, 8 h), 64x64 tile, 4 waves
// ---------------------------------------------------------------------------
__global__ __launch_bounds__(256) void logits_mfma(
    const unsigned short* __restrict__ q_bf, const unsigned short* __restrict__ kv_bf,
    const unsigned short* __restrict__ qph, const unsigned short* __restrict__ qpl,
    const unsigned short* __restrict__ kph, const unsigned short* __restrict__ kpl,
    const float* __restrict__ Qsq, const float* __restrict__ Ksq,
    const float* __restrict__ mask, const float* __restrict__ hw8,
    float* __restrict__ att)
{
    __shared__ unsigned short Qs[64][136];
    __shared__ unsigned short Ks[64][136];
    __shared__ unsigned short Aph[64][40], Apl[64][40], Bph[64][40], Bpl[64][40];
    __shared__ float Qss[64], Kss[64], Mi[64], Mj[64];
    int h = blockIdx.z;
    int i0 = blockIdx.y * 64, j0 = blockIdx.x * 64;
    int tid = threadIdx.x, lane = tid & 63, wid = tid >> 6;
    int wr = (wid >> 1) * 32, wc = (wid & 1) * 32;
    int r = tid >> 2, cq = (tid & 3) * 32;
    const unsigned short* qg = q_bf  + (size_t)(i0 + r)*1024 + h*128 + cq;
    const unsigned short* kg = kv_bf + (size_t)(j0 + r)*2048 + h*256 + cq;
    #pragma unroll
    for (int kk = 0; kk < 4; kk++) {
        *(int4*)&Qs[r][cq + kk*8] = *(const int4*)(qg + kk*8);
        *(int4*)&Ks[r][cq + kk*8] = *(const int4*)(kg + kk*8);
    }
    int cp = (tid & 3) * 8;
    *(int4*)&Aph[r][cp] = *(const int4*)(qph + (size_t)(i0 + r)*256 + h*32 + cp);
    *(int4*)&Apl[r][cp] = *(const int4*)(qpl + (size_t)(i0 + r)*256 + h*32 + cp);
    *(int4*)&Bph[r][cp] = *(const int4*)(kph + (size_t)(j0 + r)*256 + h*32 + cp);
    *(int4*)&Bpl[r][cp] = *(const int4*)(kpl + (size_t)(j0 + r)*256 + h*32 + cp);
    if (tid < 64) {
        Qss[tid] = Qsq[(i0 + tid)*8 + h];
        Kss[tid] = Ksq[(j0 + tid)*8 + h];
        Mi[tid] = mask[i0 + tid];
        Mj[tid] = mask[j0 + tid];
    }
    __syncthreads();
    int fr = lane & 15, fc = (lane >> 4) * 8;
    v4f aqk[2][2] = {}, ap[2][2] = {};
    #pragma unroll
    for (int ks = 0; ks < 4; ks++) {
        v8bf a0 = *(const v8bf*)&Qs[wr + fr][ks*32 + fc];
        v8bf a1 = *(const v8bf*)&Qs[wr + 16 + fr][ks*32 + fc];
        v8bf b0 = *(const v8bf*)&Ks[wc + fr][ks*32 + fc];
        v8bf b1 = *(const v8bf*)&Ks[wc + 16 + fr][ks*32 + fc];
        aqk[0][0] = __builtin_amdgcn_mfma_f32_16x16x32_bf16(a0, b0, aqk[0][0], 0, 0, 0);
        aqk[0][1] = __builtin_amdgcn_mfma_f32_16x16x32_bf16(a0, b1, aqk[0][1], 0, 0, 0);
        aqk[1][0] = __builtin_amdgcn_mfma_f32_16x16x32_bf16(a1, b0, aqk[1][0], 0, 0, 0);
        aqk[1][1] = __builtin_amdgcn_mfma_f32_16x16x32_bf16(a1, b1, aqk[1][1], 0, 0, 0);
    }
    {
        v8bf ah0 = *(const v8bf*)&Aph[wr + fr][fc];
        v8bf ah1 = *(const v8bf*)&Aph[wr + 16 + fr][fc];
        v8bf al0 = *(const v8bf*)&Apl[wr + fr][fc];
        v8bf al1 = *(const v8bf*)&Apl[wr + 16 + fr][fc];
        v8bf bh0 = *(const v8bf*)&Bph[wc + fr][fc];
        v8bf bh1 = *(const v8bf*)&Bph[wc + 16 + fr][fc];
        v8bf bl0 = *(const v8bf*)&Bpl[wc + fr][fc];
        v8bf bl1 = *(const v8bf*)&Bpl[wc + 16 + fr][fc];
        ap[0][0] = __builtin_amdgcn_mfma_f32_16x16x32_bf16(ah0, bh0, ap[0][0], 0, 0, 0);
        ap[0][1] = __builtin_amdgcn_mfma_f32_16x16x32_bf16(ah0, bh1, ap[0][1], 0, 0, 0);
        ap[1][0] = __builtin_amdgcn_mfma_f32_16x16x32_bf16(ah1, bh0, ap[1][0], 0, 0, 0);
        ap[1][1] = __builtin_amdgcn_mfma_f32_16x16x32_bf16(ah1, bh1, ap[1][1], 0, 0, 0);
        ap[0][0] = __builtin_amdgcn_mfma_f32_16x16x32_bf16(ah0, bl0, ap[0][0], 0, 0, 0);
        ap[0][1] = __builtin_amdgcn_mfma_f32_16x16x32_bf16(ah0, bl1, ap[0][1], 0, 0, 0);
        ap[1][0] = __builtin_amdgcn_mfma_f32_16x16x32_bf16(ah1, bl0, ap[1][0], 0, 0, 0);
        ap[1][1] = __builtin_amdgcn_mfma_f32_16x16x32_bf16(ah1, bl1, ap[1][1], 0, 0, 0);
        ap[0][0] = __builtin_amdgcn_mfma_f32_16x16x32_bf16(al0, bh0, ap[0][0], 0, 0, 0);
        ap[0][1] = __builtin_amdgcn_mfma_f32_16x16x32_bf16(al0, bh1, ap[0][1], 0, 0, 0);
        ap[1][0] = __builtin_amdgcn_mfma_f32_16x16x32_bf16(al1, bh0, ap[1][0], 0, 0, 0);
        ap[1][1] = __builtin_amdgcn_mfma_f32_16x16x32_bf16(al1, bh1, ap[1][1], 0, 0, 0);
    }
    float hw = hw8[h];
    const float scale_qk = 0.05103103630798288f;  // sqrt(1/384)
    int mrow = (lane >> 4) * 4;
    #pragma unroll
    for (int mi = 0; mi < 2; mi++) {
        #pragma unroll
        for (int ni = 0; ni < 2; ni++) {
            int jl = wc + ni*16 + fr;
            #pragma unroll
            for (int rr = 0; rr < 4; rr++) {
                int il = wr + mi*16 + mrow + rr;
                size_t aidx = (size_t)h*ATT_HSTRIDE + (size_t)(i0 + il)*768 + (j0 + jl);
                att[aidx] += aqk[mi][ni][rr]*scale_qk + hw*ap[mi][ni][rr]
                           - 0.5f*hw*(Qss[il] + Kss[jl])
                           + 100000.0f*(Mi[il]*Mj[jl] - 1.0f);
            }
        }
    }
}

// ---------------------------------------------------------------------------
// Softmax over j: reads f32 att, writes bf16 att
// ---------------------------------------------------------------------------
__global__ __launch_bounds__(64) void softmax_kernel(
    const float* __restrict__ att, unsigned short* __restrict__ att_bf)
{
    int i = blockIdx.x, h = blockIdx.y, lane = threadIdx.x;
    const float* row = att + ((size_t)h*768 + i)*768;
    unsigned short* rowb = att_bf + ((size_t)h*768 + i)*768;
    float v[12];
    float m = -3.0e38f;
    #pragma unroll
    for (int e = 0; e < 12; e++) { v[e] = row[lane + e*64]; m = fmaxf(m, v[e]); }
    #pragma unroll
    for (int d = 1; d < 64; d <<= 1) m = fmaxf(m, __shfl_xor(m, d));
    float ssum = 0.f;
    #pragma unroll
    for (int e = 0; e < 12; e++) { v[e] = expf(v[e] - m); ssum += v[e]; }
    #pragma unroll
    for (int d = 1; d < 64; d <<= 1) ssum += __shfl_xor(ssum, d);
    float inv = 1.0f/ssum;
    #pragma unroll
    for (int e = 0; e < 12; e++) rowb[lane + e*64] = f2bf(v[e]*inv);
}

// ---------------------------------------------------------------------------
// Fused (o | opt) = att @ Vc^T per h. Vc[h][192][768] bf16 (rows 164..191 pad).
// grid (3 n-tiles, 12 i-tiles, 8 h)
// ---------------------------------------------------------------------------
__global__ __launch_bounds__(256) void attvc_mfma(
    const unsigned short* __restrict__ att_bf, const unsigned short* __restrict__ Vc,
    unsigned short* __restrict__ concat, float* __restrict__ optb)
{
    __shared__ unsigned short As[64][72];
    __shared__ unsigned short Bs[64][72];
    int h = blockIdx.z;
    int i0 = blockIdx.y * 64, nd0 = blockIdx.x * 64;
    int tid = threadIdx.x, lane = tid & 63, wid = tid >> 6;
    int wr = (wid >> 1) * 32, wc = (wid & 1) * 32;
    int r = tid >> 2, c8 = (tid & 3) * 16;
    int fr = lane & 15, fc = (lane >> 4) * 8;
    v4f acc[2][2] = {};
    for (int k0 = 0; k0 < 768; k0 += 64) {
        const unsigned short* ag = att_bf + ((size_t)h*768 + i0 + r)*768 + k0 + c8;
        const unsigned short* bg = Vc + ((size_t)h*192 + nd0 + r)*768 + k0 + c8;
        *(int4*)&As[r][c8]     = *(const int4*)ag;
        *(int4*)&As[r][c8 + 8] = *(const int4*)(ag + 8);
        *(int4*)&Bs[r][c8]     = *(const int4*)bg;
        *(int4*)&Bs[r][c8 + 8] = *(const int4*)(bg + 8);
        __syncthreads();
        #pragma unroll
        for (int ks = 0; ks < 2; ks++) {
            v8bf a0 = *(const v8bf*)&As[wr + fr][ks*32 + fc];
            v8bf a1 = *(const v8bf*)&As[wr + 16 + fr][ks*32 + fc];
            v8bf b0 = *(const v8bf*)&Bs[wc + fr][ks*32 + fc];
            v8bf b1 = *(const v8bf*)&Bs[wc + 16 + fr][ks*32 + fc];
            acc[0][0] = __builtin_amdgcn_mfma_f32_16x16x32_bf16(a0, b0, acc[0][0], 0, 0, 0);
            acc[0][1] = __builtin_amdgcn_mfma_f32_16x16x32_bf16(a0, b1, acc[0][1], 0, 0, 0);
            acc[1][0] = __builtin_amdgcn_mfma_f32_16x16x32_bf16(a1, b0, acc[1][0], 0, 0, 0);
            acc[1][1] = __builtin_amdgcn_mfma_f32_16x16x32_bf16(a1, b1, acc[1][1], 0, 0, 0);
        }
        __syncthreads();
    }
    int mrow = (lane >> 4) * 4;
    #pragma unroll
    for (int mi = 0; mi < 2; mi++) {
        #pragma unroll
        for (int ni = 0; ni < 2; ni++) {
            int d = nd0 + wc + ni*16 + fr;
            #pragma unroll
            for (int rr = 0; rr < 4; rr++) {
                int i = i0 + wr + mi*16 + mrow + rr;
                float v = acc[mi][ni][rr];
                if (d < 128) {
                    concat[(size_t)i*CONCAT + h*128 + d] = f2bf(v);
                } else if (d < 164) {
                    optb[(size_t)i*288 + h*36 + (d - 128)] = v;
                }
            }
        }
    }
}

// ---------------------------------------------------------------------------
// opt2 = rot^T (opt - trans); write opt_flat + opt_norm into concat (bf16)
// ---------------------------------------------------------------------------
__global__ void optfinal_kernel(
    const float* __restrict__ optb, const float* __restrict__ rot,
    const float* __restrict__ trans, unsigned short* __restrict__ concat)
{
    int id = blockIdx.x*256 + threadIdx.x;
    if (id >= NN*96) return;
    int i = id / 96;
    int hp = id % 96;
    const float* ob = optb + i*288 + hp*3;
    float y0 = ob[0] - trans[i*3+0];
    float y1 = ob[1] - trans[i*3+1];
    float y2 = ob[2] - trans[i*3+2];
    const float* R = rot + i*9;
    float o0 = R[0]*y0 + R[3]*y1 + R[6]*y2;
    float o1 = R[1]*y0 + R[4]*y1 + R[7]*y2;
    float o2 = R[2]*y0 + R[5]*y1 + R[8]*y2;
    float nrm = sqrtf(o0*o0 + o1*o1 + o2*o2 + 1e-8f);
    unsigned short* cb = concat + (size_t)i*CONCAT;
    cb[1024 +   0 + hp] = f2bf(o0);
    cb[1024 +  96 + hp] = f2bf(o1);
    cb[1024 + 192 + hp] = f2bf(o2);
    cb[1312 + hp] = f2bf(nrm);
}

// ---------------------------------------------------------------------------
// opair partials: grid (768 i, 4 jc). part[(jc*768+i)*1024 + h*128+z]
// ---------------------------------------------------------------------------
__global__ __launch_bounds__(256) void opair_part_kernel(
    const unsigned short* __restrict__ att_bf, const float* __restrict__ p,
    float* __restrict__ part)
{
    int i = blockIdx.x, jc = blockIdx.y;
    int t = threadIdx.x;
    __shared__ float att_s[192][8];
    __shared__ float red[2][128][8];
    for (int idx = t; idx < 192*8; idx += 256) {
        int lj = idx >> 3, hh = idx & 7;
        att_s[lj][hh] = bf2f(att_bf[((size_t)hh*768 + i)*768 + jc*192 + lj]);
    }
    __syncthreads();
    int z = t & 127, jj = t >> 7;
    float acc[8] = {0.f,0.f,0.f,0.f,0.f,0.f,0.f,0.f};
    const float* prow = p + (size_t)i*98304 + (size_t)jc*192*128 + z;
    #pragma unroll 4
    for (int lj = jj; lj < 192; lj += 2) {
        float pv = prow[(size_t)lj*128];
        float4 w0 = *(const float4*)&att_s[lj][0];
        float4 w1 = *(const float4*)&att_s[lj][4];
        acc[0] += w0.x*pv; acc[1] += w0.y*pv; acc[2] += w0.z*pv; acc[3] += w0.w*pv;
        acc[4] += w1.x*pv; acc[5] += w1.y*pv; acc[6] += w1.z*pv; acc[7] += w1.w*pv;
    }
    #pragma unroll
    for (int h = 0; h < 8; h++) red[jj][z][h] = acc[h];
    __syncthreads();
    if (jj == 0) {
        #pragma unroll
        for (int h = 0; h < 8; h++)
            part[((size_t)jc*768 + i)*1024 + h*128 + z] = red[0][z][h] + red[1][z][h];
    }
}

__global__ __launch_bounds__(256) void opair_reduce_kernel(
    const float* __restrict__ part, unsigned short* __restrict__ concat)
{
    int i = blockIdx.x, t = threadIdx.x;
    for (int c = t; c < 1024; c += 256) {
        float s = part[((size_t)0*768 + i)*1024 + c]
                + part[((size_t)1*768 + i)*1024 + c]
                + part[((size_t)2*768 + i)*1024 + c]
                + part[((size_t)3*768 + i)*1024 + c];
        concat[(size_t)i*CONCAT + 1408 + c] = f2bf(s);
    }
}

// ---------------------------------------------------------------------------
// s_out = LN(A + B) * g + be ; optional bf16 copy
// ---------------------------------------------------------------------------
template<int BF>
__global__ __launch_bounds__(256) void add_ln_kernel(
    const float* __restrict__ A, const float* __restrict__ Bv,
    const float* __restrict__ g, const float* __restrict__ be,
    float* __restrict__ out, unsigned short* __restrict__ outb)
{
    int i = blockIdx.x, t = threadIdx.x;
    float x = A[i*256 + t] + Bv[i*256 + t];
    __shared__ float red[4];
    float v = x;
    #pragma unroll
    for (int m = 1; m < 64; m <<= 1) v += __shfl_xor(v, m);
    if ((t & 63) == 0) red[t >> 6] = v;
    __syncthreads();
    float mu = (red[0] + red[1] + red[2] + red[3]) * (1.0f/256.0f);
    __syncthreads();
    float d = x - mu;
    float v2 = d*d;
    #pragma unroll
    for (int m = 1; m < 64; m <<= 1) v2 += __shfl_xor(v2, m);
    if ((t & 63) == 0) red[t >> 6] = v2;
    __syncthreads();
    float var = (red[0] + red[1] + red[2] + red[3]) * (1.0f/256.0f);
    float o = d * (1.0f/sqrtf(var + 1e-5f)) * g[t] + be[t];
    out[i*256 + t] = o;
    if (BF) outb[i*256 + t] = f2bf(o);
}

// ---------------------------------------------------------------------------
__global__ __launch_bounds__(256) void upd_kernel(
    const float* __restrict__ s2, const float* __restrict__ Wbb,
    const float* __restrict__ bbb, const float* __restrict__ mask,
    float* __restrict__ upd)
{
    int i = blockIdx.x, t = threadIdx.x;
    __shared__ float row[256];
    row[t] = s2[i*256 + t];
    __syncthreads();
    if (t < 6) {
        float acc = bbb[t];
        #pragma unroll 8
        for (int c = 0; c < 256; c++) acc += row[c]*Wbb[t*256 + c];
        upd[i*6 + t] = acc * mask[i];
    }
}

__global__ void frame_kernel(
    const float* __restrict__ upd, const float* __restrict__ rot,
    const float* __restrict__ trans, float* __restrict__ rot_out,
    float* __restrict__ trans_out)
{
    int i = blockIdx.x*64 + threadIdx.x;
    if (i >= NN) return;
    float u0 = upd[i*6+0], u1 = upd[i*6+1], u2 = upd[i*6+2];
    float t0 = upd[i*6+3], t1 = upd[i*6+4], t2 = upd[i*6+5];
    float n = sqrtf(1.f + u0*u0 + u1*u1 + u2*u2);
    float w = 1.f/n, x = u0/n, y = u1/n, z = u2/n;
    float R[3][3];
    R[0][0] = 1.f - 2.f*(y*y + z*z); R[0][1] = 2.f*(x*y - w*z);       R[0][2] = 2.f*(x*z + w*y);
    R[1][0] = 2.f*(x*y + w*z);       R[1][1] = 1.f - 2.f*(x*x + z*z); R[1][2] = 2.f*(y*z - w*x);
    R[2][0] = 2.f*(x*z - w*y);       R[2][1] = 2.f*(y*z + w*x);       R[2][2] = 1.f - 2.f*(x*x + y*y);
    const float* Ri = rot + i*9;
    #pragma unroll
    for (int a = 0; a < 3; a++) {
        #pragma unroll
        for (int b = 0; b < 3; b++) {
            float acc = 0.f;
            #pragma unroll
            for (int j = 0; j < 3; j++) acc += Ri[a*3+j]*R[j][b];
            rot_out[i*9 + a*3 + b] = acc;
        }
        trans_out[i*3 + a] = trans[i*3 + a] + Ri[a*3+0]*t0 + Ri[a*3+1]*t1 + Ri[a*3+2]*t2;
    }
}

// ---------------------------------------------------------------------------
extern "C" void kernel_launch(void* const* d_in, const int* in_sizes, int n_in,
                              void* d_out, int out_size, void* d_ws, size_t ws_size,
                              hipStream_t stream)
{
    const float* s      = (const float*)d_in[0];
    const float* p      = (const float*)d_in[1];
    const float* rot    = (const float*)d_in[2];
    const float* trans  = (const float*)d_in[3];
    const float* mask   = (const float*)d_in[4];
    const float* Wq     = (const float*)d_in[5];
    const float* bq     = (const float*)d_in[6];
    const float* Wkv    = (const float*)d_in[7];
    const float* bkv    = (const float*)d_in[8];
    const float* Wqp    = (const float*)d_in[9];
    const float* bqp    = (const float*)d_in[10];
    const float* Wkvp   = (const float*)d_in[11];
    const float* bkvp   = (const float*)d_in[12];
    const float* Wpb    = (const float*)d_in[13];
    const float* bpb    = (const float*)d_in[14];
    const float* Wo     = (const float*)d_in[15];
    const float* bo     = (const float*)d_in[16];
    const float* Wt1    = (const float*)d_in[17];
    const float* bt1    = (const float*)d_in[18];
    const float* Wt2    = (const float*)d_in[19];
    const float* bt2    = (const float*)d_in[20];
    const float* Wt3    = (const float*)d_in[21];
    const float* bt3    = (const float*)d_in[22];
    const float* Wbb    = (const float*)d_in[23];
    const float* bbb    = (const float*)d_in[24];
    const float* head_w = (const float*)d_in[25];
    const float* g1     = (const float*)d_in[26];
    const float* be1    = (const float*)d_in[27];
    const float* g2     = (const float*)d_in[28];
    const float* be2    = (const float*)d_in[29];

    float* out = (float*)d_out;
    char*  wsb = (char*)d_ws;

    size_t off = 0;
    auto alloc = [&](size_t bytes) -> char* {
        char* ptr = wsb + off;
        off += (bytes + 255) & ~(size_t)255;
        return ptr;
    };
    float* qpraw   = (float*)alloc((size_t)NN*192*4);
    float* kvpraw  = (float*)alloc((size_t)NN*480*4);
    float* qpb     = (float*)alloc((size_t)NN*192*4);
    float* kpb     = (float*)alloc((size_t)NN*192*4);
    float* Qsq     = (float*)alloc((size_t)NN*8*4);
    float* Ksq     = (float*)alloc((size_t)NN*8*4);
    float* hw8     = (float*)alloc(64);
    float* att     = (float*)alloc((size_t)8*768*768*4);
    float* optb    = (float*)alloc((size_t)NN*288*4);
    float* ipa     = (float*)alloc((size_t)NN*256*4);
    float* s1      = (float*)alloc((size_t)NN*256*4);
    float* y3      = (float*)alloc((size_t)NN*256*4);
    float* updb    = (float*)alloc((size_t)NN*6*4);
    float* part    = (float*)alloc((size_t)4*768*1024*4);
    unsigned short* s_bf    = (unsigned short*)alloc((size_t)NN*256*2);
    unsigned short* Wq_bf   = (unsigned short*)alloc((size_t)1024*256*2);
    unsigned short* Wkv_bf  = (unsigned short*)alloc((size_t)2048*256*2);
    unsigned short* Wqp_bf  = (unsigned short*)alloc((size_t)192*256*2);
    unsigned short* Wkvp_bf = (unsigned short*)alloc((size_t)480*256*2);
    unsigned short* Wo_bf   = (unsigned short*)alloc((size_t)256*2432*2);
    unsigned short* Wt1_bf  = (unsigned short*)alloc((size_t)256*256*2);
    unsigned short* Wt2_bf  = (unsigned short*)alloc((size_t)256*256*2);
    unsigned short* Wt3_bf  = (unsigned short*)alloc((size_t)256*256*2);
    unsigned short* q_bf    = (unsigned short*)alloc((size_t)NN*1024*2);
    unsigned short* kv_bf   = (unsigned short*)alloc((size_t)NN*2048*2);
    unsigned short* qph     = (unsigned short*)alloc((size_t)NN*256*2);
    unsigned short* qpl     = (unsigned short*)alloc((size_t)NN*256*2);
    unsigned short* kph     = (unsigned short*)alloc((size_t)NN*256*2);
    unsigned short* kpl     = (unsigned short*)alloc((size_t)NN*256*2);
    unsigned short* Vc      = (unsigned short*)alloc((size_t)8*192*768*2);
    unsigned short* att_bf  = (unsigned short*)alloc((size_t)8*768*768*2);
    unsigned short* concat  = (unsigned short*)alloc((size_t)NN*CONCAT*2);
    unsigned short* s1b     = (unsigned short*)alloc((size_t)NN*256*2);
    unsigned short* x1b     = (unsigned short*)alloc((size_t)NN*256*2);
    unsigned short* x2b     = (unsigned short*)alloc((size_t)NN*256*2);

    // 0) Convert s + weights to bf16
    CvtDesc cd;
    const float* csrc[NCVT]    = {s, Wq, Wkv, Wqp, Wkvp, Wo, Wt1, Wt2, Wt3};
    unsigned short* cdst[NCVT] = {s_bf, Wq_bf, Wkv_bf, Wqp_bf, Wkvp_bf, Wo_bf, Wt1_bf, Wt2_bf, Wt3_bf};
    int csz[NCVT] = {NN*256, 1024*256, 2048*256, 192*256, 480*256, 256*2432, 256*256, 256*256, 256*256};
    int cum = 0;
    for (int i2 = 0; i2 < NCVT; i2++) {
        cd.src[i2] = csrc[i2]; cd.dst[i2] = cdst[i2]; cd.nelem[i2] = csz[i2];
        cd.blk_start[i2] = cum;
        cum += (csz[i2] + 2047) / 2048;
    }
    cd.blk_start[NCVT] = cum;
    cvt_many<<<cum, 256, 0, stream>>>(cd);

    // 1) Projections
    mfma_gemm<1,2,0><<<dim3(16,12), 256, 0, stream>>>(s_bf, Wq_bf,   bq,   nullptr, q_bf,  1024, 256, 1024);
    mfma_gemm<1,2,0><<<dim3(32,12), 256, 0, stream>>>(s_bf, Wkv_bf,  bkv,  nullptr, kv_bf, 2048, 256, 2048);
    mfma_gemm<1,0,0><<<dim3(3,12),  256, 0, stream>>>(s_bf, Wqp_bf,  bqp,  qpraw,  nullptr, 192, 256, 192);
    mfma_gemm<1,0,0><<<dim3(8,12),  256, 0, stream>>>(s_bf, Wkvp_bf, bkvp, kvpraw, nullptr, 480, 256, 480);

    // 2) Small prep
    prep_kernel<<<1, 64, 0, stream>>>(head_w, hw8);
    rotate_kernel<<<(NN*HH*28 + 255)/256, 256, 0, stream>>>(
        qpraw, kvpraw, rot, trans, qpb, kpb, qph, qpl, kph, kpl, Vc);
    sq_kernel<<<(NN*HH + 255)/256, 256, 0, stream>>>(qpb, kpb, Qsq, Ksq);
    vtrans_kernel<<<8*24, 256, 0, stream>>>(kv_bf, Vc);

    // 3) bias_p -> att(f32), logits MFMA RMW, softmax -> att_bf
    biasp_kernel<<<(768*768)/16, 256, 0, stream>>>(p, Wpb, bpb, att);
    logits_mfma<<<dim3(12, 12, 8), 256, 0, stream>>>(
        q_bf, kv_bf, qph, qpl, kph, kpl, Qsq, Ksq, mask, hw8, att);
    softmax_kernel<<<dim3(768, 8), 64, 0, stream>>>(att, att_bf);

    // 4) Attention outputs -> concat (bf16)
    attvc_mfma<<<dim3(3, 12, 8), 256, 0, stream>>>(att_bf, Vc, concat, optb);
    optfinal_kernel<<<(NN*96 + 255)/256, 256, 0, stream>>>(optb, rot, trans, concat);
    opair_part_kernel<<<dim3(768, 4), 256, 0, stream>>>(att_bf, p, part);
    opair_reduce_kernel<<<768, 256, 0, stream>>>(part, concat);

    // 5) Output projection (split-K MFMA) + residual LN
    ipa_init_kernel<<<768, 256, 0, stream>>>(bo, ipa);
    mfma_gemm<4,0,0><<<dim3(4,12,4), 256, 0, stream>>>(concat, Wo_bf, nullptr, ipa, nullptr, 256, 2432, 256);
    add_ln_kernel<1><<<768, 256, 0, stream>>>(s, ipa, g1, be1, s1, s1b);

    // 6) Transition MLP + residual LN
    mfma_gemm<1,2,1><<<dim3(4,12), 256, 0, stream>>>(s1b, Wt1_bf, bt1, nullptr, x1b, 256, 256, 256);
    mfma_gemm<1,2,1><<<dim3(4,12), 256, 0, stream>>>(x1b, Wt2_bf, bt2, nullptr, x2b, 256, 256, 256);
    mfma_gemm<1,0,0><<<dim3(4,12), 256, 0, stream>>>(x2b, Wt3_bf, bt3, y3, nullptr, 256, 256, 256);
    add_ln_kernel<0><<<768, 256, 0, stream>>>(s1, y3, g2, be2, out, nullptr);

    // 7) Backbone update + frame composition
    upd_kernel<<<768, 256, 0, stream>>>(out, Wbb, bbb, mask, updb);
    frame_kernel<<<12, 64, 0, stream>>>(updb, rot, trans, out + (size_t)NN*256, out + (size_t)NN*256 + (size_t)NN*9);
}

// Round 4
// 296.224 us; speedup vs baseline: 2.5234x; 1.0379x over previous
//
#include <hip/hip_runtime.h>
#include <hip/hip_bf16.h>
#include <math.h>

// Problem constants
#define NN 768
#define CS 256
#define CZ 128
#define CH 128
#define HH 8
#define PQK 8
#define PV 12
#define CONCAT 2432   // 1024 + 288 + 96 + 1024
#define ATT_HSTRIDE (768*768)

typedef __bf16 v8bf __attribute__((ext_vector_type(8)));
typedef float  v4f  __attribute__((ext_vector_type(4)));

__device__ inline unsigned short f2bf(float f) {
    union { float f; unsigned u; } v; v.f = f;
    unsigned r = v.u + 0x7FFFu + ((v.u >> 16) & 1u);
    return (unsigned short)(r >> 16);
}
__device__ inline float bf2f(unsigned short u) {
    union { unsigned u; float f; } v; v.u = ((unsigned)u) << 16; return v.f;
}

// ---------------------------------------------------------------------------
// Batched f32 -> bf16 conversion for s + all weight matrices (one launch)
// ---------------------------------------------------------------------------
#define NCVT 9
struct CvtDesc {
    const float* src[NCVT];
    unsigned short* dst[NCVT];
    int nelem[NCVT];
    int blk_start[NCVT + 1];
};

__global__ __launch_bounds__(256) void cvt_many(CvtDesc d)
{
    int b = blockIdx.x;
    int seg = 0;
    #pragma unroll
    for (int i = 0; i < NCVT - 1; i++) if (b >= d.blk_start[i + 1]) seg = i + 1;
    int local = b - d.blk_start[seg];
    int base = local * 2048 + threadIdx.x;
    const float* s = d.src[seg];
    unsigned short* o = d.dst[seg];
    int n = d.nelem[seg];
    #pragma unroll
    for (int r = 0; r < 8; r++) {
        int idx = base + r * 256;
        if (idx < n) o[idx] = f2bf(s[idx]);
    }
}

// ---------------------------------------------------------------------------
// MFMA bf16 GEMM: C[M,D] = A[M,K](bf16) @ W[D,K](bf16)^T + bias
// SPLITK>1: C pre-initialized with bias, atomicAdd partials
// MODE: 0 = f32 out, 1 = f32 + bf16 out, 2 = bf16 out only
// ---------------------------------------------------------------------------
template<int SPLITK, int MODE, int RELU>
__global__ __launch_bounds__(256) void mfma_gemm(
    const unsigned short* __restrict__ A,
    const unsigned short* __restrict__ W,
    const float* __restrict__ bias,
    float* __restrict__ C,
    unsigned short* __restrict__ Cb,
    int D, int K, int ldc)
{
    __shared__ unsigned short As[64][40];
    __shared__ unsigned short Ws[64][40];
    int tid = threadIdx.x;
    int bi = blockIdx.y * 64;
    int bd = blockIdx.x * 64;
    int kpb = K / SPLITK;
    int k0b = blockIdx.z * kpb;
    int lane = tid & 63;
    int wid = tid >> 6;
    int wr = (wid >> 1) * 32, wc = (wid & 1) * 32;
    v4f acc[2][2] = {};
    int lrow = tid >> 2;
    int lcol = (tid & 3) * 8;
    const unsigned short* Ap = A + (size_t)(bi + lrow) * K + lcol;
    const unsigned short* Wp = W + (size_t)(bd + lrow) * K + lcol;
    bool wv = (bd + lrow) < D;
    int fr = lane & 15, fc = (lane >> 4) * 8;

    for (int k0 = k0b; k0 < k0b + kpb; k0 += 32) {
        *(int4*)&As[lrow][lcol] = *(const int4*)(Ap + k0);
        int4 wz = {0, 0, 0, 0};
        *(int4*)&Ws[lrow][lcol] = wv ? *(const int4*)(Wp + k0) : wz;
        __syncthreads();
        v8bf a0 = *(const v8bf*)&As[wr + fr][fc];
        v8bf a1 = *(const v8bf*)&As[wr + 16 + fr][fc];
        v8bf b0 = *(const v8bf*)&Ws[wc + fr][fc];
        v8bf b1 = *(const v8bf*)&Ws[wc + 16 + fr][fc];
        acc[0][0] = __builtin_amdgcn_mfma_f32_16x16x32_bf16(a0, b0, acc[0][0], 0, 0, 0);
        acc[0][1] = __builtin_amdgcn_mfma_f32_16x16x32_bf16(a0, b1, acc[0][1], 0, 0, 0);
        acc[1][0] = __builtin_amdgcn_mfma_f32_16x16x32_bf16(a1, b0, acc[1][0], 0, 0, 0);
        acc[1][1] = __builtin_amdgcn_mfma_f32_16x16x32_bf16(a1, b1, acc[1][1], 0, 0, 0);
        __syncthreads();
    }
    int mrow = (lane >> 4) * 4;
    #pragma unroll
    for (int mi = 0; mi < 2; mi++) {
        #pragma unroll
        for (int ni = 0; ni < 2; ni++) {
            int d = bd + wc + ni * 16 + fr;
            if (d < D) {
                #pragma unroll
                for (int r = 0; r < 4; r++) {
                    int m = bi + wr + mi * 16 + mrow + r;
                    float v = acc[mi][ni][r];
                    if (SPLITK > 1) {
                        atomicAdd(&C[(size_t)m * ldc + d], v);
                    } else {
                        v += bias[d];
                        if (RELU) v = fmaxf(v, 0.f);
                        if (MODE != 2) C[(size_t)m * ldc + d] = v;
                        if (MODE >= 1) Cb[(size_t)m * ldc + d] = f2bf(v);
                    }
                }
            }
        }
    }
}

// ipa[i][d] = bo[d]   (pre-bias for split-K atomic GEMM)
__global__ __launch_bounds__(256) void ipa_init_kernel(
    const float* __restrict__ bo, float* __restrict__ ipa)
{
    ipa[blockIdx.x * 256 + threadIdx.x] = bo[threadIdx.x];
}

// ---------------------------------------------------------------------------
__global__ void prep_kernel(const float* __restrict__ head_w, float* __restrict__ hw8)
{
    int t = threadIdx.x;
    if (t < HH) {
        float x = head_w[t];
        float sp = (x > 20.f) ? x : log1pf(expf(x));
        hw8[t] = sp * 0.09622504486493764f;
    }
}

// ---------------------------------------------------------------------------
// Rotate points to global frame.
// ---------------------------------------------------------------------------
__global__ void rotate_kernel(
    const float* __restrict__ qpraw, const float* __restrict__ kvpraw,
    const float* __restrict__ rot, const float* __restrict__ trans,
    float* __restrict__ qpb, float* __restrict__ kpb,
    unsigned short* __restrict__ qph, unsigned short* __restrict__ qpl,
    unsigned short* __restrict__ kph, unsigned short* __restrict__ kpl,
    unsigned short* __restrict__ Vc)
{
    int id = blockIdx.x*256 + threadIdx.x;
    if (id >= NN*HH*28) return;
    int i = id / (HH*28);
    int rem = id % (HH*28);
    int h = rem / 28;
    int idx = rem % 28;
    const float* R = rot + i*9;
    const float* T = trans + i*3;
    float s0, s1, s2;
    if (idx < 8) {
        s0 = qpraw[i*192 +   0 + h*8 + idx];
        s1 = qpraw[i*192 +  64 + h*8 + idx];
        s2 = qpraw[i*192 + 128 + h*8 + idx];
    } else {
        int pp = idx - 8;
        s0 = kvpraw[i*480 +   0 + h*20 + pp];
        s1 = kvpraw[i*480 + 160 + h*20 + pp];
        s2 = kvpraw[i*480 + 320 + h*20 + pp];
    }
    float ov[3];
    ov[0] = R[0]*s0 + R[1]*s1 + R[2]*s2 + T[0];
    ov[1] = R[3]*s0 + R[4]*s1 + R[5]*s2 + T[1];
    ov[2] = R[6]*s0 + R[7]*s1 + R[8]*s2 + T[2];
    if (idx < 8) {
        #pragma unroll
        for (int x = 0; x < 3; x++) {
            qpb[i*192 + h*24 + idx*3 + x] = ov[x];
            unsigned short hi = f2bf(ov[x]);
            qph[i*256 + h*32 + idx*3 + x] = hi;
            qpl[i*256 + h*32 + idx*3 + x] = f2bf(ov[x] - bf2f(hi));
        }
        if (idx == 0) {
            #pragma unroll
            for (int m = 24; m < 32; m++) { qph[i*256+h*32+m] = 0; qpl[i*256+h*32+m] = 0; }
        }
    } else if (idx < 16) {
        int pp = idx - 8;
        #pragma unroll
        for (int x = 0; x < 3; x++) {
            kpb[i*192 + h*24 + pp*3 + x] = ov[x];
            unsigned short hi = f2bf(ov[x]);
            kph[i*256 + h*32 + pp*3 + x] = hi;
            kpl[i*256 + h*32 + pp*3 + x] = f2bf(ov[x] - bf2f(hi));
        }
        if (idx == 8) {
            #pragma unroll
            for (int m = 24; m < 32; m++) { kph[i*256+h*32+m] = 0; kpl[i*256+h*32+m] = 0; }
        }
    } else {
        int ppv = idx - 16;
        #pragma unroll
        for (int x = 0; x < 3; x++)
            Vc[((size_t)h*192 + 128 + ppv*3 + x)*768 + i] = f2bf(ov[x]);
    }
}

__global__ void sq_kernel(const float* __restrict__ qpb, const float* __restrict__ kpb,
                          float* __restrict__ Qsq, float* __restrict__ Ksq)
{
    int id = blockIdx.x*256 + threadIdx.x;
    if (id >= NN*HH) return;
    const float* qq = qpb + id*24;
    const float* kk = kpb + id*24;
    float a = 0.f, b = 0.f;
    #pragma unroll
    for (int m = 0; m < 24; m++) { a += qq[m]*qq[m]; b += kk[m]*kk[m]; }
    Qsq[id] = a; Ksq[id] = b;
}

// ---------------------------------------------------------------------------
// Vc v-part: Vc[h][c][j] = kv_bf[j][h*256+128+c]
// ---------------------------------------------------------------------------
__global__ __launch_bounds__(256) void vtrans_kernel(
    const unsigned short* __restrict__ kv_bf, unsigned short* __restrict__ Vc)
{
    __shared__ unsigned short tile[32][136];
    int h = blockIdx.x & 7, jt = blockIdx.x >> 3;
    int t = threadIdx.x;
    int r = t >> 3, c0 = (t & 7) * 16;
    const unsigned short* src = kv_bf + (size_t)(jt*32 + r)*2048 + h*256 + 128 + c0;
    *(int4*)&tile[r][c0]     = *(const int4*)src;
    *(int4*)&tile[r][c0 + 8] = *(const int4*)(src + 8);
    __syncthreads();
    int c = t >> 1, jh = (t & 1) * 16;
    unsigned short tmp[16];
    #pragma unroll
    for (int k = 0; k < 16; k++) tmp[k] = tile[jh + k][c];
    unsigned short* dst = Vc + ((size_t)h*192 + c)*768 + jt*32 + jh;
    *(int4*)dst       = *(int4*)&tmp[0];
    *(int4*)(dst + 8) = *(int4*)&tmp[8];
}

// ---------------------------------------------------------------------------
// Logits via MFMA: att0 = scale*q.k + hw*(qp.kp split-bf16) - 0.5hw(|qp|²+|kp|²) + mask
// Plain store (no RMW): bias_p is added later in fused_p_kernel.
// ---------------------------------------------------------------------------
__global__ __launch_bounds__(256) void logits_mfma(
    const unsigned short* __restrict__ q_bf, const unsigned short* __restrict__ kv_bf,
    const unsigned short* __restrict__ qph, const unsigned short* __restrict__ qpl,
    const unsigned short* __restrict__ kph, const unsigned short* __restrict__ kpl,
    const float* __restrict__ Qsq, const float* __restrict__ Ksq,
    const float* __restrict__ mask, const float* __restrict__ hw8,
    float* __restrict__ att)
{
    __shared__ unsigned short Qs[64][136];
    __shared__ unsigned short Ks[64][136];
    __shared__ unsigned short Aph[64][40], Apl[64][40], Bph[64][40], Bpl[64][40];
    __shared__ float Qss[64], Kss[64], Mi[64], Mj[64];
    int h = blockIdx.z;
    int i0 = blockIdx.y * 64, j0 = blockIdx.x * 64;
    int tid = threadIdx.x, lane = tid & 63, wid = tid >> 6;
    int wr = (wid >> 1) * 32, wc = (wid & 1) * 32;
    int r = tid >> 2, cq = (tid & 3) * 32;
    const unsigned short* qg = q_bf  + (size_t)(i0 + r)*1024 + h*128 + cq;
    const unsigned short* kg = kv_bf + (size_t)(j0 + r)*2048 + h*256 + cq;
    #pragma unroll
    for (int kk = 0; kk < 4; kk++) {
        *(int4*)&Qs[r][cq + kk*8] = *(const int4*)(qg + kk*8);
        *(int4*)&Ks[r][cq + kk*8] = *(const int4*)(kg + kk*8);
    }
    int cp = (tid & 3) * 8;
    *(int4*)&Aph[r][cp] = *(const int4*)(qph + (size_t)(i0 + r)*256 + h*32 + cp);
    *(int4*)&Apl[r][cp] = *(const int4*)(qpl + (size_t)(i0 + r)*256 + h*32 + cp);
    *(int4*)&Bph[r][cp] = *(const int4*)(kph + (size_t)(j0 + r)*256 + h*32 + cp);
    *(int4*)&Bpl[r][cp] = *(const int4*)(kpl + (size_t)(j0 + r)*256 + h*32 + cp);
    if (tid < 64) {
        Qss[tid] = Qsq[(i0 + tid)*8 + h];
        Kss[tid] = Ksq[(j0 + tid)*8 + h];
        Mi[tid] = mask[i0 + tid];
        Mj[tid] = mask[j0 + tid];
    }
    __syncthreads();
    int fr = lane & 15, fc = (lane >> 4) * 8;
    v4f aqk[2][2] = {}, ap[2][2] = {};
    #pragma unroll
    for (int ks = 0; ks < 4; ks++) {
        v8bf a0 = *(const v8bf*)&Qs[wr + fr][ks*32 + fc];
        v8bf a1 = *(const v8bf*)&Qs[wr + 16 + fr][ks*32 + fc];
        v8bf b0 = *(const v8bf*)&Ks[wc + fr][ks*32 + fc];
        v8bf b1 = *(const v8bf*)&Ks[wc + 16 + fr][ks*32 + fc];
        aqk[0][0] = __builtin_amdgcn_mfma_f32_16x16x32_bf16(a0, b0, aqk[0][0], 0, 0, 0);
        aqk[0][1] = __builtin_amdgcn_mfma_f32_16x16x32_bf16(a0, b1, aqk[0][1], 0, 0, 0);
        aqk[1][0] = __builtin_amdgcn_mfma_f32_16x16x32_bf16(a1, b0, aqk[1][0], 0, 0, 0);
        aqk[1][1] = __builtin_amdgcn_mfma_f32_16x16x32_bf16(a1, b1, aqk[1][1], 0, 0, 0);
    }
    {
        v8bf ah0 = *(const v8bf*)&Aph[wr + fr][fc];
        v8bf ah1 = *(const v8bf*)&Aph[wr + 16 + fr][fc];
        v8bf al0 = *(const v8bf*)&Apl[wr + fr][fc];
        v8bf al1 = *(const v8bf*)&Apl[wr + 16 + fr][fc];
        v8bf bh0 = *(const v8bf*)&Bph[wc + fr][fc];
        v8bf bh1 = *(const v8bf*)&Bph[wc + 16 + fr][fc];
        v8bf bl0 = *(const v8bf*)&Bpl[wc + fr][fc];
        v8bf bl1 = *(const v8bf*)&Bpl[wc + 16 + fr][fc];
        ap[0][0] = __builtin_amdgcn_mfma_f32_16x16x32_bf16(ah0, bh0, ap[0][0], 0, 0, 0);
        ap[0][1] = __builtin_amdgcn_mfma_f32_16x16x32_bf16(ah0, bh1, ap[0][1], 0, 0, 0);
        ap[1][0] = __builtin_amdgcn_mfma_f32_16x16x32_bf16(ah1, bh0, ap[1][0], 0, 0, 0);
        ap[1][1] = __builtin_amdgcn_mfma_f32_16x16x32_bf16(ah1, bh1, ap[1][1], 0, 0, 0);
        ap[0][0] = __builtin_amdgcn_mfma_f32_16x16x32_bf16(ah0, bl0, ap[0][0], 0, 0, 0);
        ap[0][1] = __builtin_amdgcn_mfma_f32_16x16x32_bf16(ah0, bl1, ap[0][1], 0, 0, 0);
        ap[1][0] = __builtin_amdgcn_mfma_f32_16x16x32_bf16(ah1, bl0, ap[1][0], 0, 0, 0);
        ap[1][1] = __builtin_amdgcn_mfma_f32_16x16x32_bf16(ah1, bl1, ap[1][1], 0, 0, 0);
        ap[0][0] = __builtin_amdgcn_mfma_f32_16x16x32_bf16(al0, bh0, ap[0][0], 0, 0, 0);
        ap[0][1] = __builtin_amdgcn_mfma_f32_16x16x32_bf16(al0, bh1, ap[0][1], 0, 0, 0);
        ap[1][0] = __builtin_amdgcn_mfma_f32_16x16x32_bf16(al1, bh0, ap[1][0], 0, 0, 0);
        ap[1][1] = __builtin_amdgcn_mfma_f32_16x16x32_bf16(al1, bh1, ap[1][1], 0, 0, 0);
    }
    float hw = hw8[h];
    const float scale_qk = 0.05103103630798288f;  // sqrt(1/384)
    int mrow = (lane >> 4) * 4;
    #pragma unroll
    for (int mi = 0; mi < 2; mi++) {
        #pragma unroll
        for (int ni = 0; ni < 2; ni++) {
            int jl = wc + ni*16 + fr;
            #pragma unroll
            for (int rr = 0; rr < 4; rr++) {
                int il = wr + mi*16 + mrow + rr;
                size_t aidx = (size_t)h*ATT_HSTRIDE + (size_t)(i0 + il)*768 + (j0 + jl);
                att[aidx] = aqk[mi][ni][rr]*scale_qk + hw*ap[mi][ni][rr]
                          - 0.5f*hw*(Qss[il] + Kss[jl])
                          + 100000.0f*(Mi[il]*Mj[jl] - 1.0f);
            }
        }
    }
}

// ---------------------------------------------------------------------------
// Fused single-pass over p: bias_p + softmax (shifted by pre-bias max) + opair.
// One block per residue i. Reads p[i,:,:] exactly once.
// ---------------------------------------------------------------------------
__global__ __launch_bounds__(256) void fused_p_kernel(
    const float* __restrict__ att0,   // [h][i][j] pre-bias logits
    const float* __restrict__ p,      // [i][j][z]
    const float* __restrict__ Wpb, const float* __restrict__ bpb,
    unsigned short* __restrict__ att_bf,  // out [h][i][j] softmax weights
    unsigned short* __restrict__ concat)  // opair -> concat[i][1408+h*128+z]
{
    __shared__ float att_s[8][776];   // pad: h-stride 776 -> bank offset 8
    __shared__ float wpb_s[8][128];
    __shared__ float bpb_s[8];
    __shared__ float m8[8];
    __shared__ float inv_s[8];
    __shared__ float red[128][8];
    int i = blockIdx.x;
    int t = threadIdx.x;
    int wv = t >> 6, lane = t & 63;

    for (int idx = t; idx < 1024; idx += 256) wpb_s[idx >> 7][idx & 127] = Wpb[idx];
    if (t < 8) bpb_s[t] = bpb[t];
    for (int idx = t; idx < 8*768; idx += 256) {
        int h = idx >> 9 | 0; // placeholder (replaced below)
        ;
    }
    // coalesced att0 load: 3 rows of 768 per 256-thread sweep
    for (int idx = t; idx < 8*768; idx += 256) {
        int h = idx / 768, j = idx - h*768;
        att_s[h][j] = att0[((size_t)h*768 + i)*768 + j];
    }
    __syncthreads();
    // M0[h]: wave wv handles rows 2wv, 2wv+1
    #pragma unroll
    for (int hh = 0; hh < 2; hh++) {
        int h = wv*2 + hh;
        float m = -3.0e38f;
        #pragma unroll
        for (int e = 0; e < 12; e++) m = fmaxf(m, att_s[h][lane + e*64]);
        #pragma unroll
        for (int d2 = 1; d2 < 64; d2 <<= 1) m = fmaxf(m, __shfl_xor(m, d2));
        if (lane == 0) m8[h] = m;
    }
    __syncthreads();
    float m0[8];
    #pragma unroll
    for (int h = 0; h < 8; h++) m0[h] = m8[h];

    // Single pass over p: bias + w' + opair accumulation
    int jl = t >> 4;         // 0..15: j within 16-group
    int zg = t & 15;         // z-slice: z = zg*8 + zz
    const float* pbase = p + (size_t)i*98304;
    float accop[8][8] = {};  // [h][zz]
    const float sqrt13 = 0.57735026918962576f;
    for (int j0 = 0; j0 < 768; j0 += 16) {
        int j = j0 + jl;
        const float* prow = pbase + (size_t)j*128 + zg*8;
        float4 a0 = *(const float4*)prow;
        float4 a1 = *(const float4*)(prow + 4);
        float acc[8];
        #pragma unroll
        for (int h = 0; h < 8; h++) {
            const float* wr2 = &wpb_s[h][zg*8];
            acc[h] = a0.x*wr2[0] + a0.y*wr2[1] + a0.z*wr2[2] + a0.w*wr2[3]
                   + a1.x*wr2[4] + a1.y*wr2[5] + a1.z*wr2[6] + a1.w*wr2[7];
        }
        #pragma unroll
        for (int m = 1; m < 16; m <<= 1) {
            #pragma unroll
            for (int h = 0; h < 8; h++) acc[h] += __shfl_xor(acc[h], m);
        }
        float w8[8];
        #pragma unroll
        for (int h = 0; h < 8; h++) {
            float L = att_s[h][j] + sqrt13*(acc[h] + bpb_s[h]);
            w8[h] = expf(fminf(L - m0[h], 60.f));
        }
        if (zg == 0) {
            #pragma unroll
            for (int h = 0; h < 8; h++) att_s[h][j] = w8[h];
        }
        #pragma unroll
        for (int h = 0; h < 8; h++) {
            accop[h][0] += w8[h]*a0.x; accop[h][1] += w8[h]*a0.y;
            accop[h][2] += w8[h]*a0.z; accop[h][3] += w8[h]*a0.w;
            accop[h][4] += w8[h]*a1.x; accop[h][5] += w8[h]*a1.y;
            accop[h][6] += w8[h]*a1.z; accop[h][7] += w8[h]*a1.w;
        }
    }
    __syncthreads();
    // l[h] = row sums of w'; write normalized att_bf
    #pragma unroll
    for (int hh = 0; hh < 2; hh++) {
        int h = wv*2 + hh;
        float ss = 0.f;
        float v[12];
        #pragma unroll
        for (int e = 0; e < 12; e++) { v[e] = att_s[h][lane + e*64]; ss += v[e]; }
        #pragma unroll
        for (int d2 = 1; d2 < 64; d2 <<= 1) ss += __shfl_xor(ss, d2);
        float inv = 1.0f/ss;
        if (lane == 0) inv_s[h] = inv;
        unsigned short* rowb = att_bf + ((size_t)h*768 + i)*768;
        #pragma unroll
        for (int e = 0; e < 12; e++) rowb[lane + e*64] = f2bf(v[e]*inv);
    }
    // 16-round jl reduction of accop into red[z][h]
    for (int r = 0; r < 16; r++) {
        if (jl == r) {
            #pragma unroll
            for (int zz = 0; zz < 8; zz++) {
                int z = zg*8 + zz;
                #pragma unroll
                for (int h = 0; h < 8; h++) {
                    if (r == 0) red[z][h] = accop[h][zz];
                    else        red[z][h] += accop[h][zz];
                }
            }
        }
        __syncthreads();
    }
    if (t < 128) {
        int z = t;
        #pragma unroll
        for (int h = 0; h < 8; h++)
            concat[(size_t)i*CONCAT + 1408 + h*128 + z] = f2bf(red[z][h]*inv_s[h]);
    }
}

// ---------------------------------------------------------------------------
// Fused (o | opt) = att @ Vc^T per h. Vc[h][192][768] bf16 (rows 164..191 pad).
// ---------------------------------------------------------------------------
__global__ __launch_bounds__(256) void attvc_mfma(
    const unsigned short* __restrict__ att_bf, const unsigned short* __restrict__ Vc,
    unsigned short* __restrict__ concat, float* __restrict__ optb)
{
    __shared__ unsigned short As[64][72];
    __shared__ unsigned short Bs[64][72];
    int h = blockIdx.z;
    int i0 = blockIdx.y * 64, nd0 = blockIdx.x * 64;
    int tid = threadIdx.x, lane = tid & 63, wid = tid >> 6;
    int wr = (wid >> 1) * 32, wc = (wid & 1) * 32;
    int r = tid >> 2, c8 = (tid & 3) * 16;
    int fr = lane & 15, fc = (lane >> 4) * 8;
    v4f acc[2][2] = {};
    for (int k0 = 0; k0 < 768; k0 += 64) {
        const unsigned short* ag = att_bf + ((size_t)h*768 + i0 + r)*768 + k0 + c8;
        const unsigned short* bg = Vc + ((size_t)h*192 + nd0 + r)*768 + k0 + c8;
        *(int4*)&As[r][c8]     = *(const int4*)ag;
        *(int4*)&As[r][c8 + 8] = *(const int4*)(ag + 8);
        *(int4*)&Bs[r][c8]     = *(const int4*)bg;
        *(int4*)&Bs[r][c8 + 8] = *(const int4*)(bg + 8);
        __syncthreads();
        #pragma unroll
        for (int ks = 0; ks < 2; ks++) {
            v8bf a0 = *(const v8bf*)&As[wr + fr][ks*32 + fc];
            v8bf a1 = *(const v8bf*)&As[wr + 16 + fr][ks*32 + fc];
            v8bf b0 = *(const v8bf*)&Bs[wc + fr][ks*32 + fc];
            v8bf b1 = *(const v8bf*)&Bs[wc + 16 + fr][ks*32 + fc];
            acc[0][0] = __builtin_amdgcn_mfma_f32_16x16x32_bf16(a0, b0, acc[0][0], 0, 0, 0);
            acc[0][1] = __builtin_amdgcn_mfma_f32_16x16x32_bf16(a0, b1, acc[0][1], 0, 0, 0);
            acc[1][0] = __builtin_amdgcn_mfma_f32_16x16x32_bf16(a1, b0, acc[1][0], 0, 0, 0);
            acc[1][1] = __builtin_amdgcn_mfma_f32_16x16x32_bf16(a1, b1, acc[1][1], 0, 0, 0);
        }
        __syncthreads();
    }
    int mrow = (lane >> 4) * 4;
    #pragma unroll
    for (int mi = 0; mi < 2; mi++) {
        #pragma unroll
        for (int ni = 0; ni < 2; ni++) {
            int d = nd0 + wc + ni*16 + fr;
            #pragma unroll
            for (int rr = 0; rr < 4; rr++) {
                int i = i0 + wr + mi*16 + mrow + rr;
                float v = acc[mi][ni][rr];
                if (d < 128) {
                    concat[(size_t)i*CONCAT + h*128 + d] = f2bf(v);
                } else if (d < 164) {
                    optb[(size_t)i*288 + h*36 + (d - 128)] = v;
                }
            }
        }
    }
}

// ---------------------------------------------------------------------------
// opt2 = rot^T (opt - trans); write opt_flat + opt_norm into concat (bf16)
// ---------------------------------------------------------------------------
__global__ void optfinal_kernel(
    const float* __restrict__ optb, const float* __restrict__ rot,
    const float* __restrict__ trans, unsigned short* __restrict__ concat)
{
    int id = blockIdx.x*256 + threadIdx.x;
    if (id >= NN*96) return;
    int i = id / 96;
    int hp = id % 96;
    const float* ob = optb + i*288 + hp*3;
    float y0 = ob[0] - trans[i*3+0];
    float y1 = ob[1] - trans[i*3+1];
    float y2 = ob[2] - trans[i*3+2];
    const float* R = rot + i*9;
    float o0 = R[0]*y0 + R[3]*y1 + R[6]*y2;
    float o1 = R[1]*y0 + R[4]*y1 + R[7]*y2;
    float o2 = R[2]*y0 + R[5]*y1 + R[8]*y2;
    float nrm = sqrtf(o0*o0 + o1*o1 + o2*o2 + 1e-8f);
    unsigned short* cb = concat + (size_t)i*CONCAT;
    cb[1024 +   0 + hp] = f2bf(o0);
    cb[1024 +  96 + hp] = f2bf(o1);
    cb[1024 + 192 + hp] = f2bf(o2);
    cb[1312 + hp] = f2bf(nrm);
}

// ---------------------------------------------------------------------------
// s_out = LN(A + B) * g + be ; optional bf16 copy
// ---------------------------------------------------------------------------
template<int BF>
__global__ __launch_bounds__(256) void add_ln_kernel(
    const float* __restrict__ A, const float* __restrict__ Bv,
    const float* __restrict__ g, const float* __restrict__ be,
    float* __restrict__ out, unsigned short* __restrict__ outb)
{
    int i = blockIdx.x, t = threadIdx.x;
    float x = A[i*256 + t] + Bv[i*256 + t];
    __shared__ float red[4];
    float v = x;
    #pragma unroll
    for (int m = 1; m < 64; m <<= 1) v += __shfl_xor(v, m);
    if ((t & 63) == 0) red[t >> 6] = v;
    __syncthreads();
    float mu = (red[0] + red[1] + red[2] + red[3]) * (1.0f/256.0f);
    __syncthreads();
    float d = x - mu;
    float v2 = d*d;
    #pragma unroll
    for (int m = 1; m < 64; m <<= 1) v2 += __shfl_xor(v2, m);
    if ((t & 63) == 0) red[t >> 6] = v2;
    __syncthreads();
    float var = (red[0] + red[1] + red[2] + red[3]) * (1.0f/256.0f);
    float o = d * (1.0f/sqrtf(var + 1e-5f)) * g[t] + be[t];
    out[i*256 + t] = o;
    if (BF) outb[i*256 + t] = f2bf(o);
}

// ---------------------------------------------------------------------------
__global__ __launch_bounds__(256) void upd_kernel(
    const float* __restrict__ s2, const float* __restrict__ Wbb,
    const float* __restrict__ bbb, const float* __restrict__ mask,
    float* __restrict__ upd)
{
    int i = blockIdx.x, t = threadIdx.x;
    __shared__ float row[256];
    row[t] = s2[i*256 + t];
    __syncthreads();
    if (t < 6) {
        float acc = bbb[t];
        #pragma unroll 8
        for (int c = 0; c < 256; c++) acc += row[c]*Wbb[t*256 + c];
        upd[i*6 + t] = acc * mask[i];
    }
}

__global__ void frame_kernel(
    const float* __restrict__ upd, const float* __restrict__ rot,
    const float* __restrict__ trans, float* __restrict__ rot_out,
    float* __restrict__ trans_out)
{
    int i = blockIdx.x*64 + threadIdx.x;
    if (i >= NN) return;
    float u0 = upd[i*6+0], u1 = upd[i*6+1], u2 = upd[i*6+2];
    float t0 = upd[i*6+3], t1 = upd[i*6+4], t2 = upd[i*6+5];
    float n = sqrtf(1.f + u0*u0 + u1*u1 + u2*u2);
    float w = 1.f/n, x = u0/n, y = u1/n, z = u2/n;
    float R[3][3];
    R[0][0] = 1.f - 2.f*(y*y + z*z); R[0][1] = 2.f*(x*y - w*z);       R[0][2] = 2.f*(x*z + w*y);
    R[1][0] = 2.f*(x*y + w*z);       R[1][1] = 1.f - 2.f*(x*x + z*z); R[1][2] = 2.f*(y*z - w*x);
    R[2][0] = 2.f*(x*z - w*y);       R[2][1] = 2.f*(y*z + w*x);       R[2][2] = 1.f - 2.f*(x*x + y*y);
    const float* Ri = rot + i*9;
    #pragma unroll
    for (int a = 0; a < 3; a++) {
        #pragma unroll
        for (int b = 0; b < 3; b++) {
            float acc = 0.f;
            #pragma unroll
            for (int j = 0; j < 3; j++) acc += Ri[a*3+j]*R[j][b];
            rot_out[i*9 + a*3 + b] = acc;
        }
        trans_out[i*3 + a] = trans[i*3 + a] + Ri[a*3+0]*t0 + Ri[a*3+1]*t1 + Ri[a*3+2]*t2;
    }
}

// ---------------------------------------------------------------------------
extern "C" void kernel_launch(void* const* d_in, const int* in_sizes, int n_in,
                              void* d_out, int out_size, void* d_ws, size_t ws_size,
                              hipStream_t stream)
{
    const float* s      = (const float*)d_in[0];
    const float* p      = (const float*)d_in[1];
    const float* rot    = (const float*)d_in[2];
    const float* trans  = (const float*)d_in[3];
    const float* mask   = (const float*)d_in[4];
    const float* Wq     = (const float*)d_in[5];
    const float* bq     = (const float*)d_in[6];
    const float* Wkv    = (const float*)d_in[7];
    const float* bkv    = (const float*)d_in[8];
    const float* Wqp    = (const float*)d_in[9];
    const float* bqp    = (const float*)d_in[10];
    const float* Wkvp   = (const float*)d_in[11];
    const float* bkvp   = (const float*)d_in[12];
    const float* Wpb    = (const float*)d_in[13];
    const float* bpb    = (const float*)d_in[14];
    const float* Wo     = (const float*)d_in[15];
    const float* bo     = (const float*)d_in[16];
    const float* Wt1    = (const float*)d_in[17];
    const float* bt1    = (const float*)d_in[18];
    const float* Wt2    = (const float*)d_in[19];
    const float* bt2    = (const float*)d_in[20];
    const float* Wt3    = (const float*)d_in[21];
    const float* bt3    = (const float*)d_in[22];
    const float* Wbb    = (const float*)d_in[23];
    const float* bbb    = (const float*)d_in[24];
    const float* head_w = (const float*)d_in[25];
    const float* g1     = (const float*)d_in[26];
    const float* be1    = (const float*)d_in[27];
    const float* g2     = (const float*)d_in[28];
    const float* be2    = (const float*)d_in[29];

    float* out = (float*)d_out;
    char*  wsb = (char*)d_ws;

    size_t off = 0;
    auto alloc = [&](size_t bytes) -> char* {
        char* ptr = wsb + off;
        off += (bytes + 255) & ~(size_t)255;
        return ptr;
    };
    float* qpraw   = (float*)alloc((size_t)NN*192*4);
    float* kvpraw  = (float*)alloc((size_t)NN*480*4);
    float* qpb     = (float*)alloc((size_t)NN*192*4);
    float* kpb     = (float*)alloc((size_t)NN*192*4);
    float* Qsq     = (float*)alloc((size_t)NN*8*4);
    float* Ksq     = (float*)alloc((size_t)NN*8*4);
    float* hw8     = (float*)alloc(64);
    float* att     = (float*)alloc((size_t)8*768*768*4);
    float* optb    = (float*)alloc((size_t)NN*288*4);
    float* ipa     = (float*)alloc((size_t)NN*256*4);
    float* s1      = (float*)alloc((size_t)NN*256*4);
    float* y3      = (float*)alloc((size_t)NN*256*4);
    float* updb    = (float*)alloc((size_t)NN*6*4);
    unsigned short* s_bf    = (unsigned short*)alloc((size_t)NN*256*2);
    unsigned short* Wq_bf   = (unsigned short*)alloc((size_t)1024*256*2);
    unsigned short* Wkv_bf  = (unsigned short*)alloc((size_t)2048*256*2);
    unsigned short* Wqp_bf  = (unsigned short*)alloc((size_t)192*256*2);
    unsigned short* Wkvp_bf = (unsigned short*)alloc((size_t)480*256*2);
    unsigned short* Wo_bf   = (unsigned short*)alloc((size_t)256*2432*2);
    unsigned short* Wt1_bf  = (unsigned short*)alloc((size_t)256*256*2);
    unsigned short* Wt2_bf  = (unsigned short*)alloc((size_t)256*256*2);
    unsigned short* Wt3_bf  = (unsigned short*)alloc((size_t)256*256*2);
    unsigned short* q_bf    = (unsigned short*)alloc((size_t)NN*1024*2);
    unsigned short* kv_bf   = (unsigned short*)alloc((size_t)NN*2048*2);
    unsigned short* qph     = (unsigned short*)alloc((size_t)NN*256*2);
    unsigned short* qpl     = (unsigned short*)alloc((size_t)NN*256*2);
    unsigned short* kph     = (unsigned short*)alloc((size_t)NN*256*2);
    unsigned short* kpl     = (unsigned short*)alloc((size_t)NN*256*2);
    unsigned short* Vc      = (unsigned short*)alloc((size_t)8*192*768*2);
    unsigned short* att_bf  = (unsigned short*)alloc((size_t)8*768*768*2);
    unsigned short* concat  = (unsigned short*)alloc((size_t)NN*CONCAT*2);
    unsigned short* s1b     = (unsigned short*)alloc((size_t)NN*256*2);
    unsigned short* x1b     = (unsigned short*)alloc((size_t)NN*256*2);
    unsigned short* x2b     = (unsigned short*)alloc((size_t)NN*256*2);

    // 0) Convert s + weights to bf16
    CvtDesc cd;
    const float* csrc[NCVT]    = {s, Wq, Wkv, Wqp, Wkvp, Wo, Wt1, Wt2, Wt3};
    unsigned short* cdst[NCVT] = {s_bf, Wq_bf, Wkv_bf, Wqp_bf, Wkvp_bf, Wo_bf, Wt1_bf, Wt2_bf, Wt3_bf};
    int csz[NCVT] = {NN*256, 1024*256, 2048*256, 192*256, 480*256, 256*2432, 256*256, 256*256, 256*256};
    int cum = 0;
    for (int i2 = 0; i2 < NCVT; i2++) {
        cd.src[i2] = csrc[i2]; cd.dst[i2] = cdst[i2]; cd.nelem[i2] = csz[i2];
        cd.blk_start[i2] = cum;
        cum += (csz[i2] + 2047) / 2048;
    }
    cd.blk_start[NCVT] = cum;
    cvt_many<<<cum, 256, 0, stream>>>(cd);

    // 1) Projections
    mfma_gemm<1,2,0><<<dim3(16,12), 256, 0, stream>>>(s_bf, Wq_bf,   bq,   nullptr, q_bf,  1024, 256, 1024);
    mfma_gemm<1,2,0><<<dim3(32,12), 256, 0, stream>>>(s_bf, Wkv_bf,  bkv,  nullptr, kv_bf, 2048, 256, 2048);
    mfma_gemm<1,0,0><<<dim3(3,12),  256, 0, stream>>>(s_bf, Wqp_bf,  bqp,  qpraw,  nullptr, 192, 256, 192);
    mfma_gemm<1,0,0><<<dim3(8,12),  256, 0, stream>>>(s_bf, Wkvp_bf, bkvp, kvpraw, nullptr, 480, 256, 480);

    // 2) Small prep
    prep_kernel<<<1, 64, 0, stream>>>(head_w, hw8);
    rotate_kernel<<<(NN*HH*28 + 255)/256, 256, 0, stream>>>(
        qpraw, kvpraw, rot, trans, qpb, kpb, qph, qpl, kph, kpl, Vc);
    sq_kernel<<<(NN*HH + 255)/256, 256, 0, stream>>>(qpb, kpb, Qsq, Ksq);
    vtrans_kernel<<<8*24, 256, 0, stream>>>(kv_bf, Vc);

    // 3) Pre-bias logits (plain store), then fused p-pass (bias+softmax+opair)
    logits_mfma<<<dim3(12, 12, 8), 256, 0, stream>>>(
        q_bf, kv_bf, qph, qpl, kph, kpl, Qsq, Ksq, mask, hw8, att);
    fused_p_kernel<<<768, 256, 0, stream>>>(att, p, Wpb, bpb, att_bf, concat);

    // 4) Attention outputs -> concat (bf16)
    attvc_mfma<<<dim3(3, 12, 8), 256, 0, stream>>>(att_bf, Vc, concat, optb);
    optfinal_kernel<<<(NN*96 + 255)/256, 256, 0, stream>>>(optb, rot, trans, concat);

    // 5) Output projection (split-K MFMA) + residual LN
    ipa_init_kernel<<<768, 256, 0, stream>>>(bo, ipa);
    mfma_gemm<4,0,0><<<dim3(4,12,4), 256, 0, stream>>>(concat, Wo_bf, nullptr, ipa, nullptr, 256, 2432, 256);
    add_ln_kernel<1><<<768, 256, 0, stream>>>(s, ipa, g1, be1, s1, s1b);

    // 6) Transition MLP + residual LN
    mfma_gemm<1,2,1><<<dim3(4,12), 256, 0, stream>>>(s1b, Wt1_bf, bt1, nullptr, x1b, 256, 256, 256);
    mfma_gemm<1,2,1><<<dim3(4,12), 256, 0, stream>>>(x1b, Wt2_bf, bt2, nullptr, x2b, 256, 256, 256);
    mfma_gemm<1,0,0><<<dim3(4,12), 256, 0, stream>>>(x2b, Wt3_bf, bt3, y3, nullptr, 256, 256, 256);
    add_ln_kernel<0><<<768, 256, 0, stream>>>(s1, y3, g2, be2, out, nullptr);

    // 7) Backbone update + frame composition
    upd_kernel<<<768, 256, 0, stream>>>(out, Wbb, bbb, mask, updb);
    frame_kernel<<<12, 64, 0, stream>>>(updb, rot, trans, out + (size_t)NN*256, out + (size_t)NN*256 + (size_t)NN*9);
}

// Round 5
// 213.734 us; speedup vs baseline: 3.4973x; 1.3859x over previous
//
#include <hip/hip_runtime.h>
#include <hip/hip_bf16.h>
#include <math.h>

// Problem constants
#define NN 768
#define CS 256
#define CZ 128
#define CH 128
#define HH 8
#define PQK 8
#define PV 12
#define CONCAT 2432   // 1024 + 288 + 96 + 1024
#define ATT_HSTRIDE (768*768)

typedef __bf16 v8bf __attribute__((ext_vector_type(8)));
typedef float  v4f  __attribute__((ext_vector_type(4)));

__device__ inline unsigned short f2bf(float f) {
    union { float f; unsigned u; } v; v.f = f;
    unsigned r = v.u + 0x7FFFu + ((v.u >> 16) & 1u);
    return (unsigned short)(r >> 16);
}
__device__ inline float bf2f(unsigned short u) {
    union { unsigned u; float f; } v; v.u = ((unsigned)u) << 16; return v.f;
}

// ---------------------------------------------------------------------------
// Batched f32 -> bf16 conversion for s + all weight matrices (one launch)
// ---------------------------------------------------------------------------
#define NCVT 9
struct CvtDesc {
    const float* src[NCVT];
    unsigned short* dst[NCVT];
    int nelem[NCVT];
    int blk_start[NCVT + 1];
};

__global__ __launch_bounds__(256) void cvt_many(CvtDesc d)
{
    int b = blockIdx.x;
    int seg = 0;
    #pragma unroll
    for (int i = 0; i < NCVT - 1; i++) if (b >= d.blk_start[i + 1]) seg = i + 1;
    int local = b - d.blk_start[seg];
    int base = local * 2048 + threadIdx.x;
    const float* s = d.src[seg];
    unsigned short* o = d.dst[seg];
    int n = d.nelem[seg];
    #pragma unroll
    for (int r = 0; r < 8; r++) {
        int idx = base + r * 256;
        if (idx < n) o[idx] = f2bf(s[idx]);
    }
}

// ---------------------------------------------------------------------------
// MFMA bf16 GEMM: C[M,D] = A[M,K](bf16) @ W[D,K](bf16)^T + bias
// SPLITK>1: C pre-initialized with bias, atomicAdd partials
// MODE: 0 = f32 out, 1 = f32 + bf16 out, 2 = bf16 out only
// ---------------------------------------------------------------------------
template<int SPLITK, int MODE, int RELU>
__global__ __launch_bounds__(256) void mfma_gemm(
    const unsigned short* __restrict__ A,
    const unsigned short* __restrict__ W,
    const float* __restrict__ bias,
    float* __restrict__ C,
    unsigned short* __restrict__ Cb,
    int D, int K, int ldc)
{
    __shared__ unsigned short As[64][40];
    __shared__ unsigned short Ws[64][40];
    int tid = threadIdx.x;
    int bi = blockIdx.y * 64;
    int bd = blockIdx.x * 64;
    int kpb = K / SPLITK;
    int k0b = blockIdx.z * kpb;
    int lane = tid & 63;
    int wid = tid >> 6;
    int wr = (wid >> 1) * 32, wc = (wid & 1) * 32;
    v4f acc[2][2] = {};
    int lrow = tid >> 2;
    int lcol = (tid & 3) * 8;
    const unsigned short* Ap = A + (size_t)(bi + lrow) * K + lcol;
    const unsigned short* Wp = W + (size_t)(bd + lrow) * K + lcol;
    bool wv = (bd + lrow) < D;
    int fr = lane & 15, fc = (lane >> 4) * 8;

    for (int k0 = k0b; k0 < k0b + kpb; k0 += 32) {
        *(int4*)&As[lrow][lcol] = *(const int4*)(Ap + k0);
        int4 wz = {0, 0, 0, 0};
        *(int4*)&Ws[lrow][lcol] = wv ? *(const int4*)(Wp + k0) : wz;
        __syncthreads();
        v8bf a0 = *(const v8bf*)&As[wr + fr][fc];
        v8bf a1 = *(const v8bf*)&As[wr + 16 + fr][fc];
        v8bf b0 = *(const v8bf*)&Ws[wc + fr][fc];
        v8bf b1 = *(const v8bf*)&Ws[wc + 16 + fr][fc];
        acc[0][0] = __builtin_amdgcn_mfma_f32_16x16x32_bf16(a0, b0, acc[0][0], 0, 0, 0);
        acc[0][1] = __builtin_amdgcn_mfma_f32_16x16x32_bf16(a0, b1, acc[0][1], 0, 0, 0);
        acc[1][0] = __builtin_amdgcn_mfma_f32_16x16x32_bf16(a1, b0, acc[1][0], 0, 0, 0);
        acc[1][1] = __builtin_amdgcn_mfma_f32_16x16x32_bf16(a1, b1, acc[1][1], 0, 0, 0);
        __syncthreads();
    }
    int mrow = (lane >> 4) * 4;
    #pragma unroll
    for (int mi = 0; mi < 2; mi++) {
        #pragma unroll
        for (int ni = 0; ni < 2; ni++) {
            int d = bd + wc + ni * 16 + fr;
            if (d < D) {
                #pragma unroll
                for (int r = 0; r < 4; r++) {
                    int m = bi + wr + mi * 16 + mrow + r;
                    float v = acc[mi][ni][r];
                    if (SPLITK > 1) {
                        atomicAdd(&C[(size_t)m * ldc + d], v);
                    } else {
                        v += bias[d];
                        if (RELU) v = fmaxf(v, 0.f);
                        if (MODE != 2) C[(size_t)m * ldc + d] = v;
                        if (MODE >= 1) Cb[(size_t)m * ldc + d] = f2bf(v);
                    }
                }
            }
        }
    }
}

// ipa[i][d] = bo[d]   (pre-bias for split-K atomic GEMM)
__global__ __launch_bounds__(256) void ipa_init_kernel(
    const float* __restrict__ bo, float* __restrict__ ipa)
{
    ipa[blockIdx.x * 256 + threadIdx.x] = bo[threadIdx.x];
}

// ---------------------------------------------------------------------------
__global__ void prep_kernel(const float* __restrict__ head_w, float* __restrict__ hw8)
{
    int t = threadIdx.x;
    if (t < HH) {
        float x = head_w[t];
        float sp = (x > 20.f) ? x : log1pf(expf(x));
        hw8[t] = sp * 0.09622504486493764f;
    }
}

// ---------------------------------------------------------------------------
// Rotate points to global frame.
// ---------------------------------------------------------------------------
__global__ void rotate_kernel(
    const float* __restrict__ qpraw, const float* __restrict__ kvpraw,
    const float* __restrict__ rot, const float* __restrict__ trans,
    float* __restrict__ qpb, float* __restrict__ kpb,
    unsigned short* __restrict__ qph, unsigned short* __restrict__ qpl,
    unsigned short* __restrict__ kph, unsigned short* __restrict__ kpl,
    unsigned short* __restrict__ Vc)
{
    int id = blockIdx.x*256 + threadIdx.x;
    if (id >= NN*HH*28) return;
    int i = id / (HH*28);
    int rem = id % (HH*28);
    int h = rem / 28;
    int idx = rem % 28;
    const float* R = rot + i*9;
    const float* T = trans + i*3;
    float s0, s1, s2;
    if (idx < 8) {
        s0 = qpraw[i*192 +   0 + h*8 + idx];
        s1 = qpraw[i*192 +  64 + h*8 + idx];
        s2 = qpraw[i*192 + 128 + h*8 + idx];
    } else {
        int pp = idx - 8;
        s0 = kvpraw[i*480 +   0 + h*20 + pp];
        s1 = kvpraw[i*480 + 160 + h*20 + pp];
        s2 = kvpraw[i*480 + 320 + h*20 + pp];
    }
    float ov[3];
    ov[0] = R[0]*s0 + R[1]*s1 + R[2]*s2 + T[0];
    ov[1] = R[3]*s0 + R[4]*s1 + R[5]*s2 + T[1];
    ov[2] = R[6]*s0 + R[7]*s1 + R[8]*s2 + T[2];
    if (idx < 8) {
        #pragma unroll
        for (int x = 0; x < 3; x++) {
            qpb[i*192 + h*24 + idx*3 + x] = ov[x];
            unsigned short hi = f2bf(ov[x]);
            qph[i*256 + h*32 + idx*3 + x] = hi;
            qpl[i*256 + h*32 + idx*3 + x] = f2bf(ov[x] - bf2f(hi));
        }
        if (idx == 0) {
            #pragma unroll
            for (int m = 24; m < 32; m++) { qph[i*256+h*32+m] = 0; qpl[i*256+h*32+m] = 0; }
        }
    } else if (idx < 16) {
        int pp = idx - 8;
        #pragma unroll
        for (int x = 0; x < 3; x++) {
            kpb[i*192 + h*24 + pp*3 + x] = ov[x];
            unsigned short hi = f2bf(ov[x]);
            kph[i*256 + h*32 + pp*3 + x] = hi;
            kpl[i*256 + h*32 + pp*3 + x] = f2bf(ov[x] - bf2f(hi));
        }
        if (idx == 8) {
            #pragma unroll
            for (int m = 24; m < 32; m++) { kph[i*256+h*32+m] = 0; kpl[i*256+h*32+m] = 0; }
        }
    } else {
        int ppv = idx - 16;
        #pragma unroll
        for (int x = 0; x < 3; x++)
            Vc[((size_t)h*192 + 128 + ppv*3 + x)*768 + i] = f2bf(ov[x]);
    }
}

__global__ void sq_kernel(const float* __restrict__ qpb, const float* __restrict__ kpb,
                          float* __restrict__ Qsq, float* __restrict__ Ksq)
{
    int id = blockIdx.x*256 + threadIdx.x;
    if (id >= NN*HH) return;
    const float* qq = qpb + id*24;
    const float* kk = kpb + id*24;
    float a = 0.f, b = 0.f;
    #pragma unroll
    for (int m = 0; m < 24; m++) { a += qq[m]*qq[m]; b += kk[m]*kk[m]; }
    Qsq[id] = a; Ksq[id] = b;
}

// ---------------------------------------------------------------------------
// Vc v-part: Vc[h][c][j] = kv_bf[j][h*256+128+c]
// ---------------------------------------------------------------------------
__global__ __launch_bounds__(256) void vtrans_kernel(
    const unsigned short* __restrict__ kv_bf, unsigned short* __restrict__ Vc)
{
    __shared__ unsigned short tile[32][136];
    int h = blockIdx.x & 7, jt = blockIdx.x >> 3;
    int t = threadIdx.x;
    int r = t >> 3, c0 = (t & 7) * 16;
    const unsigned short* src = kv_bf + (size_t)(jt*32 + r)*2048 + h*256 + 128 + c0;
    *(int4*)&tile[r][c0]     = *(const int4*)src;
    *(int4*)&tile[r][c0 + 8] = *(const int4*)(src + 8);
    __syncthreads();
    int c = t >> 1, jh = (t & 1) * 16;
    unsigned short tmp[16];
    #pragma unroll
    for (int k = 0; k < 16; k++) tmp[k] = tile[jh + k][c];
    unsigned short* dst = Vc + ((size_t)h*192 + c)*768 + jt*32 + jh;
    *(int4*)dst       = *(int4*)&tmp[0];
    *(int4*)(dst + 8) = *(int4*)&tmp[8];
}

// ---------------------------------------------------------------------------
// Logits via MFMA: att0 = scale*q.k + hw*(qp.kp split-bf16) - 0.5hw(|qp|²+|kp|²) + mask
// ---------------------------------------------------------------------------
__global__ __launch_bounds__(256) void logits_mfma(
    const unsigned short* __restrict__ q_bf, const unsigned short* __restrict__ kv_bf,
    const unsigned short* __restrict__ qph, const unsigned short* __restrict__ qpl,
    const unsigned short* __restrict__ kph, const unsigned short* __restrict__ kpl,
    const float* __restrict__ Qsq, const float* __restrict__ Ksq,
    const float* __restrict__ mask, const float* __restrict__ hw8,
    float* __restrict__ att)
{
    __shared__ unsigned short Qs[64][136];
    __shared__ unsigned short Ks[64][136];
    __shared__ unsigned short Aph[64][40], Apl[64][40], Bph[64][40], Bpl[64][40];
    __shared__ float Qss[64], Kss[64], Mi[64], Mj[64];
    int h = blockIdx.z;
    int i0 = blockIdx.y * 64, j0 = blockIdx.x * 64;
    int tid = threadIdx.x, lane = tid & 63, wid = tid >> 6;
    int wr = (wid >> 1) * 32, wc = (wid & 1) * 32;
    int r = tid >> 2, cq = (tid & 3) * 32;
    const unsigned short* qg = q_bf  + (size_t)(i0 + r)*1024 + h*128 + cq;
    const unsigned short* kg = kv_bf + (size_t)(j0 + r)*2048 + h*256 + cq;
    #pragma unroll
    for (int kk = 0; kk < 4; kk++) {
        *(int4*)&Qs[r][cq + kk*8] = *(const int4*)(qg + kk*8);
        *(int4*)&Ks[r][cq + kk*8] = *(const int4*)(kg + kk*8);
    }
    int cp = (tid & 3) * 8;
    *(int4*)&Aph[r][cp] = *(const int4*)(qph + (size_t)(i0 + r)*256 + h*32 + cp);
    *(int4*)&Apl[r][cp] = *(const int4*)(qpl + (size_t)(i0 + r)*256 + h*32 + cp);
    *(int4*)&Bph[r][cp] = *(const int4*)(kph + (size_t)(j0 + r)*256 + h*32 + cp);
    *(int4*)&Bpl[r][cp] = *(const int4*)(kpl + (size_t)(j0 + r)*256 + h*32 + cp);
    if (tid < 64) {
        Qss[tid] = Qsq[(i0 + tid)*8 + h];
        Kss[tid] = Ksq[(j0 + tid)*8 + h];
        Mi[tid] = mask[i0 + tid];
        Mj[tid] = mask[j0 + tid];
    }
    __syncthreads();
    int fr = lane & 15, fc = (lane >> 4) * 8;
    v4f aqk[2][2] = {}, ap[2][2] = {};
    #pragma unroll
    for (int ks = 0; ks < 4; ks++) {
        v8bf a0 = *(const v8bf*)&Qs[wr + fr][ks*32 + fc];
        v8bf a1 = *(const v8bf*)&Qs[wr + 16 + fr][ks*32 + fc];
        v8bf b0 = *(const v8bf*)&Ks[wc + fr][ks*32 + fc];
        v8bf b1 = *(const v8bf*)&Ks[wc + 16 + fr][ks*32 + fc];
        aqk[0][0] = __builtin_amdgcn_mfma_f32_16x16x32_bf16(a0, b0, aqk[0][0], 0, 0, 0);
        aqk[0][1] = __builtin_amdgcn_mfma_f32_16x16x32_bf16(a0, b1, aqk[0][1], 0, 0, 0);
        aqk[1][0] = __builtin_amdgcn_mfma_f32_16x16x32_bf16(a1, b0, aqk[1][0], 0, 0, 0);
        aqk[1][1] = __builtin_amdgcn_mfma_f32_16x16x32_bf16(a1, b1, aqk[1][1], 0, 0, 0);
    }
    {
        v8bf ah0 = *(const v8bf*)&Aph[wr + fr][fc];
        v8bf ah1 = *(const v8bf*)&Aph[wr + 16 + fr][fc];
        v8bf al0 = *(const v8bf*)&Apl[wr + fr][fc];
        v8bf al1 = *(const v8bf*)&Apl[wr + 16 + fr][fc];
        v8bf bh0 = *(const v8bf*)&Bph[wc + fr][fc];
        v8bf bh1 = *(const v8bf*)&Bph[wc + 16 + fr][fc];
        v8bf bl0 = *(const v8bf*)&Bpl[wc + fr][fc];
        v8bf bl1 = *(const v8bf*)&Bpl[wc + 16 + fr][fc];
        ap[0][0] = __builtin_amdgcn_mfma_f32_16x16x32_bf16(ah0, bh0, ap[0][0], 0, 0, 0);
        ap[0][1] = __builtin_amdgcn_mfma_f32_16x16x32_bf16(ah0, bh1, ap[0][1], 0, 0, 0);
        ap[1][0] = __builtin_amdgcn_mfma_f32_16x16x32_bf16(ah1, bh0, ap[1][0], 0, 0, 0);
        ap[1][1] = __builtin_amdgcn_mfma_f32_16x16x32_bf16(ah1, bh1, ap[1][1], 0, 0, 0);
        ap[0][0] = __builtin_amdgcn_mfma_f32_16x16x32_bf16(ah0, bl0, ap[0][0], 0, 0, 0);
        ap[0][1] = __builtin_amdgcn_mfma_f32_16x16x32_bf16(ah0, bl1, ap[0][1], 0, 0, 0);
        ap[1][0] = __builtin_amdgcn_mfma_f32_16x16x32_bf16(ah1, bl0, ap[1][0], 0, 0, 0);
        ap[1][1] = __builtin_amdgcn_mfma_f32_16x16x32_bf16(ah1, bl1, ap[1][1], 0, 0, 0);
        ap[0][0] = __builtin_amdgcn_mfma_f32_16x16x32_bf16(al0, bh0, ap[0][0], 0, 0, 0);
        ap[0][1] = __builtin_amdgcn_mfma_f32_16x16x32_bf16(al0, bh1, ap[0][1], 0, 0, 0);
        ap[1][0] = __builtin_amdgcn_mfma_f32_16x16x32_bf16(al1, bh0, ap[1][0], 0, 0, 0);
        ap[1][1] = __builtin_amdgcn_mfma_f32_16x16x32_bf16(al1, bh1, ap[1][1], 0, 0, 0);
    }
    float hw = hw8[h];
    const float scale_qk = 0.05103103630798288f;  // sqrt(1/384)
    int mrow = (lane >> 4) * 4;
    #pragma unroll
    for (int mi = 0; mi < 2; mi++) {
        #pragma unroll
        for (int ni = 0; ni < 2; ni++) {
            int jl = wc + ni*16 + fr;
            #pragma unroll
            for (int rr = 0; rr < 4; rr++) {
                int il = wr + mi*16 + mrow + rr;
                size_t aidx = (size_t)h*ATT_HSTRIDE + (size_t)(i0 + il)*768 + (j0 + jl);
                att[aidx] = aqk[mi][ni][rr]*scale_qk + hw*ap[mi][ni][rr]
                          - 0.5f*hw*(Qss[il] + Kss[jl])
                          + 100000.0f*(Mi[il]*Mj[jl] - 1.0f);
            }
        }
    }
}

// ---------------------------------------------------------------------------
// fused_p2: single pass over p[i,:,:] with MFMA for bias (K=z) and opair (K=j).
// Writes UNNORMALIZED w' to att_bf, 1/rowsum to linv, normalized opair->concat.
// One block per residue i; 4 waves; 12 tiles of 64 j.
// ---------------------------------------------------------------------------
__global__ __launch_bounds__(256) void fused_p2_kernel(
    const float* __restrict__ att0,
    const float* __restrict__ p,
    const float* __restrict__ Wpb, const float* __restrict__ bpb,
    unsigned short* __restrict__ att_bf,
    float* __restrict__ linv,
    unsigned short* __restrict__ concat)
{
    __shared__ unsigned short ptile[64][136];   // [j][z] bf16
    __shared__ unsigned short pT[128][88];      // [z][j] bf16
    __shared__ unsigned short wt[16][72];       // w' tile [h][j], rows 8-15 zero
    __shared__ unsigned short Wpb16[16][136];   // rows 8-15 zero
    __shared__ float bpb_s[8], m8[8], inv_s[8], lsum_w[4][8];

    int i = blockIdx.x;
    int tid = threadIdx.x, lane = tid & 63, wid = tid >> 6;
    int fr = lane & 15, fc = (lane >> 4) * 8;
    int mrow = (lane >> 4) * 4;

    // init: zero wt, load Wpb16 (rows 8-15 zero), bpb
    for (int idx = tid; idx < 16*72; idx += 256) wt[idx / 72][idx % 72] = 0;
    for (int idx = tid; idx < 16*136; idx += 256) {
        int h = idx / 136, z = idx % 136;
        Wpb16[h][z] = (h < 8 && z < 128) ? f2bf(Wpb[h*128 + z]) : 0;
    }
    if (tid < 8) bpb_s[tid] = bpb[tid];

    // m0[h] = max_j att0[h][i][j]
    {
        const float* abase = att0 + (size_t)i*768;
        #pragma unroll
        for (int hh = 0; hh < 2; hh++) {
            int h = wid*2 + hh;
            const float* row = abase + (size_t)h*ATT_HSTRIDE;
            float m = -3.0e38f;
            #pragma unroll
            for (int e = 0; e < 12; e++) m = fmaxf(m, row[lane + e*64]);
            #pragma unroll
            for (int d2 = 1; d2 < 64; d2 <<= 1) m = fmaxf(m, __shfl_xor(m, d2));
            if (lane == 0) m8[h] = m;
        }
    }

    const float* pbase = p + (size_t)i*98304;
    // prologue: load tile 0 into regs
    float4 pfA[4], pfB[4];
    #pragma unroll
    for (int r = 0; r < 4; r++) {
        int idx = r*256 + tid;
        const float* src = pbase + (idx >> 4)*128 + (idx & 15)*8;
        pfA[r] = *(const float4*)src;
        pfB[r] = *(const float4*)(src + 4);
    }

    v4f accop[2] = {};       // opair accumulators: M-tiles {2wid, 2wid+1}
    float lacc[4] = {0.f, 0.f, 0.f, 0.f};
    const float sqrt13 = 0.57735026918962576f;

    for (int t64 = 0; t64 < 12; t64++) {
        int j0 = t64 * 64;
        // stage regs -> ptile (b128, conflict-free)
        #pragma unroll
        for (int r = 0; r < 4; r++) {
            int idx = r*256 + tid;
            int j = idx >> 4, zo = (idx & 15) * 8;
            unsigned u0 = (unsigned)f2bf(pfA[r].x) | ((unsigned)f2bf(pfA[r].y) << 16);
            unsigned u1 = (unsigned)f2bf(pfA[r].z) | ((unsigned)f2bf(pfA[r].w) << 16);
            unsigned u2 = (unsigned)f2bf(pfB[r].x) | ((unsigned)f2bf(pfB[r].y) << 16);
            unsigned u3 = (unsigned)f2bf(pfB[r].z) | ((unsigned)f2bf(pfB[r].w) << 16);
            int4 val; val.x = (int)u0; val.y = (int)u1; val.z = (int)u2; val.w = (int)u3;
            *(int4*)&ptile[j][zo] = val;
        }
        // issue next tile's global loads
        if (t64 < 11) {
            int j0n = j0 + 64;
            #pragma unroll
            for (int r = 0; r < 4; r++) {
                int idx = r*256 + tid;
                const float* src = pbase + (size_t)(j0n + (idx >> 4))*128 + (idx & 15)*8;
                pfA[r] = *(const float4*)src;
                pfB[r] = *(const float4*)(src + 4);
            }
        }
        __syncthreads();   // B1: ptile ready; prev tile's pT/wt readers done

        // att0 prefetch for this wave's j-column
        float a0v[4];
        if (mrow < 8) {
            int j = 16*wid + fr;
            #pragma unroll
            for (int r = 0; r < 4; r++)
                a0v[r] = att0[((size_t)(mrow + r)*768 + i)*768 + j0 + j];
        }

        // transpose ptile -> pT (16 b32 reads + 4 b128 writes per thread)
        #pragma unroll
        for (int rep = 0; rep < 2; rep++) {
            int item = rep*256 + tid;
            int zp = item & 63, jg = item >> 6;
            unsigned v[8];
            #pragma unroll
            for (int k = 0; k < 8; k++)
                v[k] = *(const unsigned*)&ptile[jg*8 + k][zp*2];
            unsigned r0[4], r1[4];
            #pragma unroll
            for (int q = 0; q < 4; q++) {
                unsigned a = v[2*q], b = v[2*q + 1];
                r0[q] = (a & 0xffffu) | ((b & 0xffffu) << 16);
                r1[q] = (a >> 16) | (b & 0xffff0000u);
            }
            int4 w0; w0.x = (int)r0[0]; w0.y = (int)r0[1]; w0.z = (int)r0[2]; w0.w = (int)r0[3];
            int4 w1; w1.x = (int)r1[0]; w1.y = (int)r1[1]; w1.z = (int)r1[2]; w1.w = (int)r1[3];
            *(int4*)&pT[2*zp][jg*8]     = w0;
            *(int4*)&pT[2*zp + 1][jg*8] = w1;
        }

        // bias mfma: D[h][j] over this wave's 16-j column
        v4f bd = {};
        #pragma unroll
        for (int ks = 0; ks < 4; ks++) {
            v8bf a = *(const v8bf*)&Wpb16[fr][ks*32 + fc];
            v8bf b = *(const v8bf*)&ptile[16*wid + fr][ks*32 + fc];
            bd = __builtin_amdgcn_mfma_f32_16x16x32_bf16(a, b, bd, 0, 0, 0);
        }

        // w' = exp(att0 + sqrt13*(bias+bpb) - m0); write wt + att_bf; row-sum
        if (mrow < 8) {
            int j = 16*wid + fr;
            float w8[4];
            #pragma unroll
            for (int r = 0; r < 4; r++) {
                int h = mrow + r;
                float L = a0v[r] + sqrt13*(bd[r] + bpb_s[h]);
                w8[r] = expf(fminf(L - m8[h], 60.f));
            }
            #pragma unroll
            for (int r = 0; r < 4; r++) {
                int h = mrow + r;
                unsigned short wb = f2bf(w8[r]);
                wt[h][j] = wb;
                att_bf[((size_t)h*768 + i)*768 + j0 + j] = wb;
            }
            #pragma unroll
            for (int m = 1; m < 16; m <<= 1) {
                #pragma unroll
                for (int r = 0; r < 4; r++) w8[r] += __shfl_xor(w8[r], m);
            }
            #pragma unroll
            for (int r = 0; r < 4; r++) lacc[r] += w8[r];
        }
        __syncthreads();   // B2: pT + wt ready

        // opair mfma: D[z][h], K = 64 j
        #pragma unroll
        for (int mm = 0; mm < 2; mm++) {
            #pragma unroll
            for (int ks = 0; ks < 2; ks++) {
                v8bf a = *(const v8bf*)&pT[(2*wid + mm)*16 + fr][ks*32 + fc];
                v8bf b = *(const v8bf*)&wt[fr][ks*32 + fc];
                accop[mm] = __builtin_amdgcn_mfma_f32_16x16x32_bf16(a, b, accop[mm], 0, 0, 0);
            }
        }
    }

    __syncthreads();
    if (fr == 0 && mrow < 8) {
        #pragma unroll
        for (int r = 0; r < 4; r++) lsum_w[wid][mrow + r] = lacc[r];
    }
    __syncthreads();
    if (tid < 8) {
        float l = lsum_w[0][tid] + lsum_w[1][tid] + lsum_w[2][tid] + lsum_w[3][tid];
        float iv = 1.0f / l;
        inv_s[tid] = iv;
        linv[(size_t)tid*768 + i] = iv;
    }
    __syncthreads();
    // opair write: col = h (fr), rows z
    if (fr < 8) {
        int h = fr;
        float iv = inv_s[h];
        #pragma unroll
        for (int mm = 0; mm < 2; mm++) {
            #pragma unroll
            for (int r = 0; r < 4; r++) {
                int z = (2*wid + mm)*16 + mrow + r;
                concat[(size_t)i*CONCAT + 1408 + h*128 + z] = f2bf(accop[mm][r] * iv);
            }
        }
    }
}

// ---------------------------------------------------------------------------
// Fused (o | opt) = (att_unnorm @ Vc^T) * linv per h. Vc[h][192][768] bf16.
// ---------------------------------------------------------------------------
__global__ __launch_bounds__(256) void attvc_mfma(
    const unsigned short* __restrict__ att_bf, const unsigned short* __restrict__ Vc,
    const float* __restrict__ linv,
    unsigned short* __restrict__ concat, float* __restrict__ optb)
{
    __shared__ unsigned short As[64][72];
    __shared__ unsigned short Bs[64][72];
    int h = blockIdx.z;
    int i0 = blockIdx.y * 64, nd0 = blockIdx.x * 64;
    int tid = threadIdx.x, lane = tid & 63, wid = tid >> 6;
    int wr = (wid >> 1) * 32, wc = (wid & 1) * 32;
    int r = tid >> 2, c8 = (tid & 3) * 16;
    int fr = lane & 15, fc = (lane >> 4) * 8;
    v4f acc[2][2] = {};
    for (int k0 = 0; k0 < 768; k0 += 64) {
        const unsigned short* ag = att_bf + ((size_t)h*768 + i0 + r)*768 + k0 + c8;
        const unsigned short* bg = Vc + ((size_t)h*192 + nd0 + r)*768 + k0 + c8;
        *(int4*)&As[r][c8]     = *(const int4*)ag;
        *(int4*)&As[r][c8 + 8] = *(const int4*)(ag + 8);
        *(int4*)&Bs[r][c8]     = *(const int4*)bg;
        *(int4*)&Bs[r][c8 + 8] = *(const int4*)(bg + 8);
        __syncthreads();
        #pragma unroll
        for (int ks = 0; ks < 2; ks++) {
            v8bf a0 = *(const v8bf*)&As[wr + fr][ks*32 + fc];
            v8bf a1 = *(const v8bf*)&As[wr + 16 + fr][ks*32 + fc];
            v8bf b0 = *(const v8bf*)&Bs[wc + fr][ks*32 + fc];
            v8bf b1 = *(const v8bf*)&Bs[wc + 16 + fr][ks*32 + fc];
            acc[0][0] = __builtin_amdgcn_mfma_f32_16x16x32_bf16(a0, b0, acc[0][0], 0, 0, 0);
            acc[0][1] = __builtin_amdgcn_mfma_f32_16x16x32_bf16(a0, b1, acc[0][1], 0, 0, 0);
            acc[1][0] = __builtin_amdgcn_mfma_f32_16x16x32_bf16(a1, b0, acc[1][0], 0, 0, 0);
            acc[1][1] = __builtin_amdgcn_mfma_f32_16x16x32_bf16(a1, b1, acc[1][1], 0, 0, 0);
        }
        __syncthreads();
    }
    int mrow = (lane >> 4) * 4;
    // per-row normalization factors
    float lv[2][4];
    #pragma unroll
    for (int mi = 0; mi < 2; mi++) {
        int ibase = i0 + wr + mi*16 + mrow;
        float4 l4 = *(const float4*)&linv[(size_t)h*768 + ibase];
        lv[mi][0] = l4.x; lv[mi][1] = l4.y; lv[mi][2] = l4.z; lv[mi][3] = l4.w;
    }
    #pragma unroll
    for (int mi = 0; mi < 2; mi++) {
        #pragma unroll
        for (int ni = 0; ni < 2; ni++) {
            int d = nd0 + wc + ni*16 + fr;
            #pragma unroll
            for (int rr = 0; rr < 4; rr++) {
                int i = i0 + wr + mi*16 + mrow + rr;
                float v = acc[mi][ni][rr] * lv[mi][rr];
                if (d < 128) {
                    concat[(size_t)i*CONCAT + h*128 + d] = f2bf(v);
                } else if (d < 164) {
                    optb[(size_t)i*288 + h*36 + (d - 128)] = v;
                }
            }
        }
    }
}

// ---------------------------------------------------------------------------
// opt2 = rot^T (opt - trans); write opt_flat + opt_norm into concat (bf16)
// ---------------------------------------------------------------------------
__global__ void optfinal_kernel(
    const float* __restrict__ optb, const float* __restrict__ rot,
    const float* __restrict__ trans, unsigned short* __restrict__ concat)
{
    int id = blockIdx.x*256 + threadIdx.x;
    if (id >= NN*96) return;
    int i = id / 96;
    int hp = id % 96;
    const float* ob = optb + i*288 + hp*3;
    float y0 = ob[0] - trans[i*3+0];
    float y1 = ob[1] - trans[i*3+1];
    float y2 = ob[2] - trans[i*3+2];
    const float* R = rot + i*9;
    float o0 = R[0]*y0 + R[3]*y1 + R[6]*y2;
    float o1 = R[1]*y0 + R[4]*y1 + R[7]*y2;
    float o2 = R[2]*y0 + R[5]*y1 + R[8]*y2;
    float nrm = sqrtf(o0*o0 + o1*o1 + o2*o2 + 1e-8f);
    unsigned short* cb = concat + (size_t)i*CONCAT;
    cb[1024 +   0 + hp] = f2bf(o0);
    cb[1024 +  96 + hp] = f2bf(o1);
    cb[1024 + 192 + hp] = f2bf(o2);
    cb[1312 + hp] = f2bf(nrm);
}

// ---------------------------------------------------------------------------
// s_out = LN(A + B) * g + be ; optional bf16 copy
// ---------------------------------------------------------------------------
template<int BF>
__global__ __launch_bounds__(256) void add_ln_kernel(
    const float* __restrict__ A, const float* __restrict__ Bv,
    const float* __restrict__ g, const float* __restrict__ be,
    float* __restrict__ out, unsigned short* __restrict__ outb)
{
    int i = blockIdx.x, t = threadIdx.x;
    float x = A[i*256 + t] + Bv[i*256 + t];
    __shared__ float red[4];
    float v = x;
    #pragma unroll
    for (int m = 1; m < 64; m <<= 1) v += __shfl_xor(v, m);
    if ((t & 63) == 0) red[t >> 6] = v;
    __syncthreads();
    float mu = (red[0] + red[1] + red[2] + red[3]) * (1.0f/256.0f);
    __syncthreads();
    float d = x - mu;
    float v2 = d*d;
    #pragma unroll
    for (int m = 1; m < 64; m <<= 1) v2 += __shfl_xor(v2, m);
    if ((t & 63) == 0) red[t >> 6] = v2;
    __syncthreads();
    float var = (red[0] + red[1] + red[2] + red[3]) * (1.0f/256.0f);
    float o = d * (1.0f/sqrtf(var + 1e-5f)) * g[t] + be[t];
    out[i*256 + t] = o;
    if (BF) outb[i*256 + t] = f2bf(o);
}

// ---------------------------------------------------------------------------
__global__ __launch_bounds__(256) void upd_kernel(
    const float* __restrict__ s2, const float* __restrict__ Wbb,
    const float* __restrict__ bbb, const float* __restrict__ mask,
    float* __restrict__ upd)
{
    int i = blockIdx.x, t = threadIdx.x;
    __shared__ float row[256];
    row[t] = s2[i*256 + t];
    __syncthreads();
    if (t < 6) {
        float acc = bbb[t];
        #pragma unroll 8
        for (int c = 0; c < 256; c++) acc += row[c]*Wbb[t*256 + c];
        upd[i*6 + t] = acc * mask[i];
    }
}

__global__ void frame_kernel(
    const float* __restrict__ upd, const float* __restrict__ rot,
    const float* __restrict__ trans, float* __restrict__ rot_out,
    float* __restrict__ trans_out)
{
    int i = blockIdx.x*64 + threadIdx.x;
    if (i >= NN) return;
    float u0 = upd[i*6+0], u1 = upd[i*6+1], u2 = upd[i*6+2];
    float t0 = upd[i*6+3], t1 = upd[i*6+4], t2 = upd[i*6+5];
    float n = sqrtf(1.f + u0*u0 + u1*u1 + u2*u2);
    float w = 1.f/n, x = u0/n, y = u1/n, z = u2/n;
    float R[3][3];
    R[0][0] = 1.f - 2.f*(y*y + z*z); R[0][1] = 2.f*(x*y - w*z);       R[0][2] = 2.f*(x*z + w*y);
    R[1][0] = 2.f*(x*y + w*z);       R[1][1] = 1.f - 2.f*(x*x + z*z); R[1][2] = 2.f*(y*z - w*x);
    R[2][0] = 2.f*(x*z - w*y);       R[2][1] = 2.f*(y*z + w*x);       R[2][2] = 1.f - 2.f*(x*x + y*y);
    const float* Ri = rot + i*9;
    #pragma unroll
    for (int a = 0; a < 3; a++) {
        #pragma unroll
        for (int b = 0; b < 3; b++) {
            float acc = 0.f;
            #pragma unroll
            for (int j = 0; j < 3; j++) acc += Ri[a*3+j]*R[j][b];
            rot_out[i*9 + a*3 + b] = acc;
        }
        trans_out[i*3 + a] = trans[i*3 + a] + Ri[a*3+0]*t0 + Ri[a*3+1]*t1 + Ri[a*3+2]*t2;
    }
}

// ---------------------------------------------------------------------------
extern "C" void kernel_launch(void* const* d_in, const int* in_sizes, int n_in,
                              void* d_out, int out_size, void* d_ws, size_t ws_size,
                              hipStream_t stream)
{
    const float* s      = (const float*)d_in[0];
    const float* p      = (const float*)d_in[1];
    const float* rot    = (const float*)d_in[2];
    const float* trans  = (const float*)d_in[3];
    const float* mask   = (const float*)d_in[4];
    const float* Wq     = (const float*)d_in[5];
    const float* bq     = (const float*)d_in[6];
    const float* Wkv    = (const float*)d_in[7];
    const float* bkv    = (const float*)d_in[8];
    const float* Wqp    = (const float*)d_in[9];
    const float* bqp    = (const float*)d_in[10];
    const float* Wkvp   = (const float*)d_in[11];
    const float* bkvp   = (const float*)d_in[12];
    const float* Wpb    = (const float*)d_in[13];
    const float* bpb    = (const float*)d_in[14];
    const float* Wo     = (const float*)d_in[15];
    const float* bo     = (const float*)d_in[16];
    const float* Wt1    = (const float*)d_in[17];
    const float* bt1    = (const float*)d_in[18];
    const float* Wt2    = (const float*)d_in[19];
    const float* bt2    = (const float*)d_in[20];
    const float* Wt3    = (const float*)d_in[21];
    const float* bt3    = (const float*)d_in[22];
    const float* Wbb    = (const float*)d_in[23];
    const float* bbb    = (const float*)d_in[24];
    const float* head_w = (const float*)d_in[25];
    const float* g1     = (const float*)d_in[26];
    const float* be1    = (const float*)d_in[27];
    const float* g2     = (const float*)d_in[28];
    const float* be2    = (const float*)d_in[29];

    float* out = (float*)d_out;
    char*  wsb = (char*)d_ws;

    size_t off = 0;
    auto alloc = [&](size_t bytes) -> char* {
        char* ptr = wsb + off;
        off += (bytes + 255) & ~(size_t)255;
        return ptr;
    };
    float* qpraw   = (float*)alloc((size_t)NN*192*4);
    float* kvpraw  = (float*)alloc((size_t)NN*480*4);
    float* qpb     = (float*)alloc((size_t)NN*192*4);
    float* kpb     = (float*)alloc((size_t)NN*192*4);
    float* Qsq     = (float*)alloc((size_t)NN*8*4);
    float* Ksq     = (float*)alloc((size_t)NN*8*4);
    float* hw8     = (float*)alloc(64);
    float* att     = (float*)alloc((size_t)8*768*768*4);
    float* optb    = (float*)alloc((size_t)NN*288*4);
    float* ipa     = (float*)alloc((size_t)NN*256*4);
    float* s1      = (float*)alloc((size_t)NN*256*4);
    float* y3      = (float*)alloc((size_t)NN*256*4);
    float* updb    = (float*)alloc((size_t)NN*6*4);
    float* linv    = (float*)alloc((size_t)8*768*4);
    unsigned short* s_bf    = (unsigned short*)alloc((size_t)NN*256*2);
    unsigned short* Wq_bf   = (unsigned short*)alloc((size_t)1024*256*2);
    unsigned short* Wkv_bf  = (unsigned short*)alloc((size_t)2048*256*2);
    unsigned short* Wqp_bf  = (unsigned short*)alloc((size_t)192*256*2);
    unsigned short* Wkvp_bf = (unsigned short*)alloc((size_t)480*256*2);
    unsigned short* Wo_bf   = (unsigned short*)alloc((size_t)256*2432*2);
    unsigned short* Wt1_bf  = (unsigned short*)alloc((size_t)256*256*2);
    unsigned short* Wt2_bf  = (unsigned short*)alloc((size_t)256*256*2);
    unsigned short* Wt3_bf  = (unsigned short*)alloc((size_t)256*256*2);
    unsigned short* q_bf    = (unsigned short*)alloc((size_t)NN*1024*2);
    unsigned short* kv_bf   = (unsigned short*)alloc((size_t)NN*2048*2);
    unsigned short* qph     = (unsigned short*)alloc((size_t)NN*256*2);
    unsigned short* qpl     = (unsigned short*)alloc((size_t)NN*256*2);
    unsigned short* kph     = (unsigned short*)alloc((size_t)NN*256*2);
    unsigned short* kpl     = (unsigned short*)alloc((size_t)NN*256*2);
    unsigned short* Vc      = (unsigned short*)alloc((size_t)8*192*768*2);
    unsigned short* att_bf  = (unsigned short*)alloc((size_t)8*768*768*2);
    unsigned short* concat  = (unsigned short*)alloc((size_t)NN*CONCAT*2);
    unsigned short* s1b     = (unsigned short*)alloc((size_t)NN*256*2);
    unsigned short* x1b     = (unsigned short*)alloc((size_t)NN*256*2);
    unsigned short* x2b     = (unsigned short*)alloc((size_t)NN*256*2);

    // 0) Convert s + weights to bf16
    CvtDesc cd;
    const float* csrc[NCVT]    = {s, Wq, Wkv, Wqp, Wkvp, Wo, Wt1, Wt2, Wt3};
    unsigned short* cdst[NCVT] = {s_bf, Wq_bf, Wkv_bf, Wqp_bf, Wkvp_bf, Wo_bf, Wt1_bf, Wt2_bf, Wt3_bf};
    int csz[NCVT] = {NN*256, 1024*256, 2048*256, 192*256, 480*256, 256*2432, 256*256, 256*256, 256*256};
    int cum = 0;
    for (int i2 = 0; i2 < NCVT; i2++) {
        cd.src[i2] = csrc[i2]; cd.dst[i2] = cdst[i2]; cd.nelem[i2] = csz[i2];
        cd.blk_start[i2] = cum;
        cum += (csz[i2] + 2047) / 2048;
    }
    cd.blk_start[NCVT] = cum;
    cvt_many<<<cum, 256, 0, stream>>>(cd);

    // 1) Projections
    mfma_gemm<1,2,0><<<dim3(16,12), 256, 0, stream>>>(s_bf, Wq_bf,   bq,   nullptr, q_bf,  1024, 256, 1024);
    mfma_gemm<1,2,0><<<dim3(32,12), 256, 0, stream>>>(s_bf, Wkv_bf,  bkv,  nullptr, kv_bf, 2048, 256, 2048);
    mfma_gemm<1,0,0><<<dim3(3,12),  256, 0, stream>>>(s_bf, Wqp_bf,  bqp,  qpraw,  nullptr, 192, 256, 192);
    mfma_gemm<1,0,0><<<dim3(8,12),  256, 0, stream>>>(s_bf, Wkvp_bf, bkvp, kvpraw, nullptr, 480, 256, 480);

    // 2) Small prep
    prep_kernel<<<1, 64, 0, stream>>>(head_w, hw8);
    rotate_kernel<<<(NN*HH*28 + 255)/256, 256, 0, stream>>>(
        qpraw, kvpraw, rot, trans, qpb, kpb, qph, qpl, kph, kpl, Vc);
    sq_kernel<<<(NN*HH + 255)/256, 256, 0, stream>>>(qpb, kpb, Qsq, Ksq);
    vtrans_kernel<<<8*24, 256, 0, stream>>>(kv_bf, Vc);

    // 3) Pre-bias logits, then MFMA-based single-pass p kernel
    logits_mfma<<<dim3(12, 12, 8), 256, 0, stream>>>(
        q_bf, kv_bf, qph, qpl, kph, kpl, Qsq, Ksq, mask, hw8, att);
    fused_p2_kernel<<<768, 256, 0, stream>>>(att, p, Wpb, bpb, att_bf, linv, concat);

    // 4) Attention outputs -> concat (bf16)
    attvc_mfma<<<dim3(3, 12, 8), 256, 0, stream>>>(att_bf, Vc, linv, concat, optb);
    optfinal_kernel<<<(NN*96 + 255)/256, 256, 0, stream>>>(optb, rot, trans, concat);

    // 5) Output projection (split-K MFMA) + residual LN
    ipa_init_kernel<<<768, 256, 0, stream>>>(bo, ipa);
    mfma_gemm<4,0,0><<<dim3(4,12,4), 256, 0, stream>>>(concat, Wo_bf, nullptr, ipa, nullptr, 256, 2432, 256);
    add_ln_kernel<1><<<768, 256, 0, stream>>>(s, ipa, g1, be1, s1, s1b);

    // 6) Transition MLP + residual LN
    mfma_gemm<1,2,1><<<dim3(4,12), 256, 0, stream>>>(s1b, Wt1_bf, bt1, nullptr, x1b, 256, 256, 256);
    mfma_gemm<1,2,1><<<dim3(4,12), 256, 0, stream>>>(x1b, Wt2_bf, bt2, nullptr, x2b, 256, 256, 256);
    mfma_gemm<1,0,0><<<dim3(4,12), 256, 0, stream>>>(x2b, Wt3_bf, bt3, y3, nullptr, 256, 256, 256);
    add_ln_kernel<0><<<768, 256, 0, stream>>>(s1, y3, g2, be2, out, nullptr);

    // 7) Backbone update + frame composition
    upd_kernel<<<768, 256, 0, stream>>>(out, Wbb, bbb, mask, updb);
    frame_kernel<<<12, 64, 0, stream>>>(updb, rot, trans, out + (size_t)NN*256, out + (size_t)NN*256 + (size_t)NN*9);
}

// Round 6
// 195.120 us; speedup vs baseline: 3.8309x; 1.0954x over previous
//
#include <hip/hip_runtime.h>
#include <hip/hip_bf16.h>
#include <math.h>

// Problem constants
#define NN 768
#define CS 256
#define CZ 128
#define CH 128
#define HH 8
#define PQK 8
#define PV 12
#define CONCAT 2432   // 1024 + 288 + 96 + 1024
#define ATT_HSTRIDE (768*768)

typedef __bf16 v8bf __attribute__((ext_vector_type(8)));
typedef __bf16 v4bf __attribute__((ext_vector_type(4)));
typedef float  v4f  __attribute__((ext_vector_type(4)));

__device__ inline unsigned short f2bf(float f) {
    union { float f; unsigned u; } v; v.f = f;
    unsigned r = v.u + 0x7FFFu + ((v.u >> 16) & 1u);
    return (unsigned short)(r >> 16);
}
__device__ inline float bf2f(unsigned short u) {
    union { unsigned u; float f; } v; v.u = ((unsigned)u) << 16; return v.f;
}

// ---------------------------------------------------------------------------
// Batched f32 -> bf16 conversion for s + all weight matrices (one launch)
// ---------------------------------------------------------------------------
#define NCVT 9
struct CvtDesc {
    const float* src[NCVT];
    unsigned short* dst[NCVT];
    int nelem[NCVT];
    int blk_start[NCVT + 1];
};

__global__ __launch_bounds__(256) void cvt_many(CvtDesc d)
{
    int b = blockIdx.x;
    int seg = 0;
    #pragma unroll
    for (int i = 0; i < NCVT - 1; i++) if (b >= d.blk_start[i + 1]) seg = i + 1;
    int local = b - d.blk_start[seg];
    int base = local * 2048 + threadIdx.x;
    const float* s = d.src[seg];
    unsigned short* o = d.dst[seg];
    int n = d.nelem[seg];
    #pragma unroll
    for (int r = 0; r < 8; r++) {
        int idx = base + r * 256;
        if (idx < n) o[idx] = f2bf(s[idx]);
    }
}

// ---------------------------------------------------------------------------
// Combined projection GEMM: 4 weight segments, shared A = s_bf, K=256.
// mode 2: bf16 out; mode 0: f32 out.
// ---------------------------------------------------------------------------
struct ProjDesc {
    const unsigned short* W[4];
    const float* bias[4];
    unsigned short* dstb[4];
    float* dstf[4];
    int D[4];
    int ldc[4];
    int mode[4];
    int blk_start[5];
};

__global__ __launch_bounds__(256) void proj_all(const unsigned short* __restrict__ A, ProjDesc d)
{
    __shared__ unsigned short As[64][40];
    __shared__ unsigned short Ws[64][40];
    int bx = blockIdx.x;
    int seg = 0;
    #pragma unroll
    for (int q = 0; q < 3; q++) if (bx >= d.blk_start[q + 1]) seg = q + 1;
    int bd = (bx - d.blk_start[seg]) * 64;
    int bi = blockIdx.y * 64;
    const unsigned short* W = d.W[seg];
    int D = d.D[seg], ldc = d.ldc[seg];

    int tid = threadIdx.x, lane = tid & 63, wid = tid >> 6;
    int wr = (wid >> 1) * 32, wc = (wid & 1) * 32;
    v4f acc[2][2] = {};
    int lrow = tid >> 2, lcol = (tid & 3) * 8;
    const unsigned short* Ap = A + (size_t)(bi + lrow) * 256 + lcol;
    const unsigned short* Wp = W + (size_t)(bd + lrow) * 256 + lcol;
    bool wv = (bd + lrow) < D;
    int fr = lane & 15, fc = (lane >> 4) * 8;

    for (int k0 = 0; k0 < 256; k0 += 32) {
        *(int4*)&As[lrow][lcol] = *(const int4*)(Ap + k0);
        int4 wz = {0, 0, 0, 0};
        *(int4*)&Ws[lrow][lcol] = wv ? *(const int4*)(Wp + k0) : wz;
        __syncthreads();
        v8bf a0 = *(const v8bf*)&As[wr + fr][fc];
        v8bf a1 = *(const v8bf*)&As[wr + 16 + fr][fc];
        v8bf b0 = *(const v8bf*)&Ws[wc + fr][fc];
        v8bf b1 = *(const v8bf*)&Ws[wc + 16 + fr][fc];
        acc[0][0] = __builtin_amdgcn_mfma_f32_16x16x32_bf16(a0, b0, acc[0][0], 0, 0, 0);
        acc[0][1] = __builtin_amdgcn_mfma_f32_16x16x32_bf16(a0, b1, acc[0][1], 0, 0, 0);
        acc[1][0] = __builtin_amdgcn_mfma_f32_16x16x32_bf16(a1, b0, acc[1][0], 0, 0, 0);
        acc[1][1] = __builtin_amdgcn_mfma_f32_16x16x32_bf16(a1, b1, acc[1][1], 0, 0, 0);
        __syncthreads();
    }
    const float* bias = d.bias[seg];
    int mode = d.mode[seg];
    unsigned short* Cb = d.dstb[seg];
    float* Cf = d.dstf[seg];
    int mrow = (lane >> 4) * 4;
    #pragma unroll
    for (int mi = 0; mi < 2; mi++) {
        #pragma unroll
        for (int ni = 0; ni < 2; ni++) {
            int dd = bd + wc + ni * 16 + fr;
            if (dd < D) {
                #pragma unroll
                for (int r = 0; r < 4; r++) {
                    int m = bi + wr + mi * 16 + mrow + r;
                    float v = acc[mi][ni][r] + bias[dd];
                    if (mode == 2) Cb[(size_t)m * ldc + dd] = f2bf(v);
                    else           Cf[(size_t)m * ldc + dd] = v;
                }
            }
        }
    }
}

// ---------------------------------------------------------------------------
// Generic MFMA bf16 GEMM (Wo split-K + transition MLP)
// ---------------------------------------------------------------------------
template<int SPLITK, int MODE, int RELU>
__global__ __launch_bounds__(256) void mfma_gemm(
    const unsigned short* __restrict__ A,
    const unsigned short* __restrict__ W,
    const float* __restrict__ bias,
    float* __restrict__ C,
    unsigned short* __restrict__ Cb,
    int D, int K, int ldc)
{
    __shared__ unsigned short As[64][40];
    __shared__ unsigned short Ws[64][40];
    int tid = threadIdx.x;
    int bi = blockIdx.y * 64;
    int bd = blockIdx.x * 64;
    int kpb = K / SPLITK;
    int k0b = blockIdx.z * kpb;
    int lane = tid & 63;
    int wid = tid >> 6;
    int wr = (wid >> 1) * 32, wc = (wid & 1) * 32;
    v4f acc[2][2] = {};
    int lrow = tid >> 2;
    int lcol = (tid & 3) * 8;
    const unsigned short* Ap = A + (size_t)(bi + lrow) * K + lcol;
    const unsigned short* Wp = W + (size_t)(bd + lrow) * K + lcol;
    bool wv = (bd + lrow) < D;
    int fr = lane & 15, fc = (lane >> 4) * 8;

    for (int k0 = k0b; k0 < k0b + kpb; k0 += 32) {
        *(int4*)&As[lrow][lcol] = *(const int4*)(Ap + k0);
        int4 wz = {0, 0, 0, 0};
        *(int4*)&Ws[lrow][lcol] = wv ? *(const int4*)(Wp + k0) : wz;
        __syncthreads();
        v8bf a0 = *(const v8bf*)&As[wr + fr][fc];
        v8bf a1 = *(const v8bf*)&As[wr + 16 + fr][fc];
        v8bf b0 = *(const v8bf*)&Ws[wc + fr][fc];
        v8bf b1 = *(const v8bf*)&Ws[wc + 16 + fr][fc];
        acc[0][0] = __builtin_amdgcn_mfma_f32_16x16x32_bf16(a0, b0, acc[0][0], 0, 0, 0);
        acc[0][1] = __builtin_amdgcn_mfma_f32_16x16x32_bf16(a0, b1, acc[0][1], 0, 0, 0);
        acc[1][0] = __builtin_amdgcn_mfma_f32_16x16x32_bf16(a1, b0, acc[1][0], 0, 0, 0);
        acc[1][1] = __builtin_amdgcn_mfma_f32_16x16x32_bf16(a1, b1, acc[1][1], 0, 0, 0);
        __syncthreads();
    }
    int mrow = (lane >> 4) * 4;
    #pragma unroll
    for (int mi = 0; mi < 2; mi++) {
        #pragma unroll
        for (int ni = 0; ni < 2; ni++) {
            int d = bd + wc + ni * 16 + fr;
            if (d < D) {
                #pragma unroll
                for (int r = 0; r < 4; r++) {
                    int m = bi + wr + mi * 16 + mrow + r;
                    float v = acc[mi][ni][r];
                    if (SPLITK > 1) {
                        atomicAdd(&C[(size_t)m * ldc + d], v);
                    } else {
                        v += bias[d];
                        if (RELU) v = fmaxf(v, 0.f);
                        if (MODE != 2) C[(size_t)m * ldc + d] = v;
                        if (MODE >= 1) Cb[(size_t)m * ldc + d] = f2bf(v);
                    }
                }
            }
        }
    }
}

// ipa[i][d] = bo[d]   (pre-bias for split-K atomic GEMM)
__global__ __launch_bounds__(256) void ipa_init_kernel(
    const float* __restrict__ bo, float* __restrict__ ipa)
{
    ipa[blockIdx.x * 256 + threadIdx.x] = bo[threadIdx.x];
}

// ---------------------------------------------------------------------------
// Rotate points to global frame (hi/lo bf16 split; vp straight into Vc)
// ---------------------------------------------------------------------------
__global__ void rotate_kernel(
    const float* __restrict__ qpraw, const float* __restrict__ kvpraw,
    const float* __restrict__ rot, const float* __restrict__ trans,
    unsigned short* __restrict__ qph, unsigned short* __restrict__ qpl,
    unsigned short* __restrict__ kph, unsigned short* __restrict__ kpl,
    unsigned short* __restrict__ Vc)
{
    int id = blockIdx.x*256 + threadIdx.x;
    if (id >= NN*HH*28) return;
    int i = id / (HH*28);
    int rem = id % (HH*28);
    int h = rem / 28;
    int idx = rem % 28;
    const float* R = rot + i*9;
    const float* T = trans + i*3;
    float s0, s1, s2;
    if (idx < 8) {
        s0 = qpraw[i*192 +   0 + h*8 + idx];
        s1 = qpraw[i*192 +  64 + h*8 + idx];
        s2 = qpraw[i*192 + 128 + h*8 + idx];
    } else {
        int pp = idx - 8;
        s0 = kvpraw[i*480 +   0 + h*20 + pp];
        s1 = kvpraw[i*480 + 160 + h*20 + pp];
        s2 = kvpraw[i*480 + 320 + h*20 + pp];
    }
    float ov[3];
    ov[0] = R[0]*s0 + R[1]*s1 + R[2]*s2 + T[0];
    ov[1] = R[3]*s0 + R[4]*s1 + R[5]*s2 + T[1];
    ov[2] = R[6]*s0 + R[7]*s1 + R[8]*s2 + T[2];
    if (idx < 8) {
        #pragma unroll
        for (int x = 0; x < 3; x++) {
            unsigned short hi = f2bf(ov[x]);
            qph[i*256 + h*32 + idx*3 + x] = hi;
            qpl[i*256 + h*32 + idx*3 + x] = f2bf(ov[x] - bf2f(hi));
        }
        if (idx == 0) {
            #pragma unroll
            for (int m = 24; m < 32; m++) { qph[i*256+h*32+m] = 0; qpl[i*256+h*32+m] = 0; }
        }
    } else if (idx < 16) {
        int pp = idx - 8;
        #pragma unroll
        for (int x = 0; x < 3; x++) {
            unsigned short hi = f2bf(ov[x]);
            kph[i*256 + h*32 + pp*3 + x] = hi;
            kpl[i*256 + h*32 + pp*3 + x] = f2bf(ov[x] - bf2f(hi));
        }
        if (idx == 8) {
            #pragma unroll
            for (int m = 24; m < 32; m++) { kph[i*256+h*32+m] = 0; kpl[i*256+h*32+m] = 0; }
        }
    } else {
        int ppv = idx - 16;
        #pragma unroll
        for (int x = 0; x < 3; x++)
            Vc[((size_t)h*192 + 128 + ppv*3 + x)*768 + i] = f2bf(ov[x]);
    }
}

// ---------------------------------------------------------------------------
// Vc v-part: Vc[h][c][j] = kv_bf[j][h*256+128+c]
// ---------------------------------------------------------------------------
__global__ __launch_bounds__(256) void vtrans_kernel(
    const unsigned short* __restrict__ kv_bf, unsigned short* __restrict__ Vc)
{
    __shared__ unsigned short tile[32][136];
    int h = blockIdx.x & 7, jt = blockIdx.x >> 3;
    int t = threadIdx.x;
    int r = t >> 3, c0 = (t & 7) * 16;
    const unsigned short* src = kv_bf + (size_t)(jt*32 + r)*2048 + h*256 + 128 + c0;
    *(int4*)&tile[r][c0]     = *(const int4*)src;
    *(int4*)&tile[r][c0 + 8] = *(const int4*)(src + 8);
    __syncthreads();
    int c = t >> 1, jh = (t & 1) * 16;
    unsigned short tmp[16];
    #pragma unroll
    for (int k = 0; k < 16; k++) tmp[k] = tile[jh + k][c];
    unsigned short* dst = Vc + ((size_t)h*192 + c)*768 + jt*32 + jh;
    *(int4*)dst       = *(int4*)&tmp[0];
    *(int4*)(dst + 8) = *(int4*)&tmp[8];
}

// ---------------------------------------------------------------------------
// Logits via MFMA; Qsq/Ksq computed in-block from hi+lo; hw inline softplus.
// ---------------------------------------------------------------------------
__global__ __launch_bounds__(256) void logits_mfma(
    const unsigned short* __restrict__ q_bf, const unsigned short* __restrict__ kv_bf,
    const unsigned short* __restrict__ qph, const unsigned short* __restrict__ qpl,
    const unsigned short* __restrict__ kph, const unsigned short* __restrict__ kpl,
    const float* __restrict__ mask, const float* __restrict__ head_w,
    float* __restrict__ att)
{
    __shared__ unsigned short Qs[64][136];
    __shared__ unsigned short Ks[64][136];
    __shared__ unsigned short Aph[64][40], Apl[64][40], Bph[64][40], Bpl[64][40];
    __shared__ float Qss[64], Kss[64], Mi[64], Mj[64];
    int h = blockIdx.z;
    int i0 = blockIdx.y * 64, j0 = blockIdx.x * 64;
    int tid = threadIdx.x, lane = tid & 63, wid = tid >> 6;
    int wr = (wid >> 1) * 32, wc = (wid & 1) * 32;
    int r = tid >> 2, cq = (tid & 3) * 32;
    const unsigned short* qg = q_bf  + (size_t)(i0 + r)*1024 + h*128 + cq;
    const unsigned short* kg = kv_bf + (size_t)(j0 + r)*2048 + h*256 + cq;
    #pragma unroll
    for (int kk = 0; kk < 4; kk++) {
        *(int4*)&Qs[r][cq + kk*8] = *(const int4*)(qg + kk*8);
        *(int4*)&Ks[r][cq + kk*8] = *(const int4*)(kg + kk*8);
    }
    int cp = (tid & 3) * 8;
    *(int4*)&Aph[r][cp] = *(const int4*)(qph + (size_t)(i0 + r)*256 + h*32 + cp);
    *(int4*)&Apl[r][cp] = *(const int4*)(qpl + (size_t)(i0 + r)*256 + h*32 + cp);
    *(int4*)&Bph[r][cp] = *(const int4*)(kph + (size_t)(j0 + r)*256 + h*32 + cp);
    *(int4*)&Bpl[r][cp] = *(const int4*)(kpl + (size_t)(j0 + r)*256 + h*32 + cp);
    if (tid < 64) {
        Mi[tid] = mask[i0 + tid];
        Mj[tid] = mask[j0 + tid];
    }
    __syncthreads();
    // point-norms from staged hi/lo
    if (tid < 64) {
        float qs2 = 0.f, ks2 = 0.f;
        #pragma unroll
        for (int m = 0; m < 24; m++) {
            float qv = bf2f(Aph[tid][m]) + bf2f(Apl[tid][m]);
            float kv = bf2f(Bph[tid][m]) + bf2f(Bpl[tid][m]);
            qs2 += qv*qv; ks2 += kv*kv;
        }
        Qss[tid] = qs2; Kss[tid] = ks2;
    }
    int fr = lane & 15, fc = (lane >> 4) * 8;
    v4f aqk[2][2] = {}, ap[2][2] = {};
    #pragma unroll
    for (int ks = 0; ks < 4; ks++) {
        v8bf a0 = *(const v8bf*)&Qs[wr + fr][ks*32 + fc];
        v8bf a1 = *(const v8bf*)&Qs[wr + 16 + fr][ks*32 + fc];
        v8bf b0 = *(const v8bf*)&Ks[wc + fr][ks*32 + fc];
        v8bf b1 = *(const v8bf*)&Ks[wc + 16 + fr][ks*32 + fc];
        aqk[0][0] = __builtin_amdgcn_mfma_f32_16x16x32_bf16(a0, b0, aqk[0][0], 0, 0, 0);
        aqk[0][1] = __builtin_amdgcn_mfma_f32_16x16x32_bf16(a0, b1, aqk[0][1], 0, 0, 0);
        aqk[1][0] = __builtin_amdgcn_mfma_f32_16x16x32_bf16(a1, b0, aqk[1][0], 0, 0, 0);
        aqk[1][1] = __builtin_amdgcn_mfma_f32_16x16x32_bf16(a1, b1, aqk[1][1], 0, 0, 0);
    }
    {
        v8bf ah0 = *(const v8bf*)&Aph[wr + fr][fc];
        v8bf ah1 = *(const v8bf*)&Aph[wr + 16 + fr][fc];
        v8bf al0 = *(const v8bf*)&Apl[wr + fr][fc];
        v8bf al1 = *(const v8bf*)&Apl[wr + 16 + fr][fc];
        v8bf bh0 = *(const v8bf*)&Bph[wc + fr][fc];
        v8bf bh1 = *(const v8bf*)&Bph[wc + 16 + fr][fc];
        v8bf bl0 = *(const v8bf*)&Bpl[wc + fr][fc];
        v8bf bl1 = *(const v8bf*)&Bpl[wc + 16 + fr][fc];
        ap[0][0] = __builtin_amdgcn_mfma_f32_16x16x32_bf16(ah0, bh0, ap[0][0], 0, 0, 0);
        ap[0][1] = __builtin_amdgcn_mfma_f32_16x16x32_bf16(ah0, bh1, ap[0][1], 0, 0, 0);
        ap[1][0] = __builtin_amdgcn_mfma_f32_16x16x32_bf16(ah1, bh0, ap[1][0], 0, 0, 0);
        ap[1][1] = __builtin_amdgcn_mfma_f32_16x16x32_bf16(ah1, bh1, ap[1][1], 0, 0, 0);
        ap[0][0] = __builtin_amdgcn_mfma_f32_16x16x32_bf16(ah0, bl0, ap[0][0], 0, 0, 0);
        ap[0][1] = __builtin_amdgcn_mfma_f32_16x16x32_bf16(ah0, bl1, ap[0][1], 0, 0, 0);
        ap[1][0] = __builtin_amdgcn_mfma_f32_16x16x32_bf16(ah1, bl0, ap[1][0], 0, 0, 0);
        ap[1][1] = __builtin_amdgcn_mfma_f32_16x16x32_bf16(ah1, bl1, ap[1][1], 0, 0, 0);
        ap[0][0] = __builtin_amdgcn_mfma_f32_16x16x32_bf16(al0, bh0, ap[0][0], 0, 0, 0);
        ap[0][1] = __builtin_amdgcn_mfma_f32_16x16x32_bf16(al0, bh1, ap[0][1], 0, 0, 0);
        ap[1][0] = __builtin_amdgcn_mfma_f32_16x16x32_bf16(al1, bh0, ap[1][0], 0, 0, 0);
        ap[1][1] = __builtin_amdgcn_mfma_f32_16x16x32_bf16(al1, bh1, ap[1][1], 0, 0, 0);
    }
    __syncthreads();   // Qss/Kss visibility
    float hx = head_w[h];
    float sp = (hx > 20.f) ? hx : log1pf(__expf(hx));
    float hw = sp * 0.09622504486493764f;
    const float scale_qk = 0.05103103630798288f;  // sqrt(1/384)
    int mrow = (lane >> 4) * 4;
    #pragma unroll
    for (int mi = 0; mi < 2; mi++) {
        #pragma unroll
        for (int ni = 0; ni < 2; ni++) {
            int jl = wc + ni*16 + fr;
            #pragma unroll
            for (int rr = 0; rr < 4; rr++) {
                int il = wr + mi*16 + mrow + rr;
                size_t aidx = (size_t)h*ATT_HSTRIDE + (size_t)(i0 + il)*768 + (j0 + jl);
                att[aidx] = aqk[mi][ni][rr]*scale_qk + hw*ap[mi][ni][rr]
                          - 0.5f*hw*(Qss[il] + Kss[jl])
                          + 100000.0f*(Mi[il]*Mj[jl] - 1.0f);
            }
        }
    }
}

// ---------------------------------------------------------------------------
// fused_p3: single pass over p[i,:,:]; MFMA bias (K=z) + MFMA opair (K=j)
// reading opair B-fragments directly from ptile columns (no transpose).
// LDS ~19.4KB -> high occupancy. One block per residue i.
// ---------------------------------------------------------------------------
__global__ __launch_bounds__(256) void fused_p3_kernel(
    const float* __restrict__ att0,
    const float* __restrict__ p,
    const float* __restrict__ Wpb, const float* __restrict__ bpb,
    unsigned short* __restrict__ att_bf,
    float* __restrict__ linv,
    unsigned short* __restrict__ concat)
{
    __shared__ unsigned short ptile[64][132];   // [j][z] bf16, 8B-aligned rows
    __shared__ unsigned short wt[16][72];       // w' [h][j], rows 8-15 zero
    __shared__ float bpb_s[8], m8[8], inv_s[8], lsum_w[4][8];

    int i = blockIdx.x;
    int tid = threadIdx.x, lane = tid & 63, wid = tid >> 6;
    int fr = lane & 15, fc = (lane >> 4) * 8;
    int mrow = (lane >> 4) * 4;

    for (int idx = tid; idx < 16*72; idx += 256) ((unsigned short*)wt)[idx] = 0;
    if (tid < 8) bpb_s[tid] = bpb[tid];

    // Wpb A-fragments hoisted to registers (rows fr<8, else zero)
    v8bf aW[4];
    #pragma unroll
    for (int ks = 0; ks < 4; ks++) {
        v8bf v = {};
        if (fr < 8) {
            const float* wp = Wpb + fr*128 + ks*32 + fc;
            float4 w0 = *(const float4*)wp;
            float4 w1 = *(const float4*)(wp + 4);
            v[0] = (__bf16)w0.x; v[1] = (__bf16)w0.y; v[2] = (__bf16)w0.z; v[3] = (__bf16)w0.w;
            v[4] = (__bf16)w1.x; v[5] = (__bf16)w1.y; v[6] = (__bf16)w1.z; v[7] = (__bf16)w1.w;
        }
        aW[ks] = v;
    }

    // m0[h] = max_j att0[h][i][j]
    {
        const float* abase = att0 + (size_t)i*768;
        #pragma unroll
        for (int hh = 0; hh < 2; hh++) {
            int h = wid*2 + hh;
            const float* row = abase + (size_t)h*ATT_HSTRIDE;
            float m = -3.0e38f;
            #pragma unroll
            for (int e = 0; e < 12; e++) m = fmaxf(m, row[lane + e*64]);
            #pragma unroll
            for (int d2 = 1; d2 < 64; d2 <<= 1) m = fmaxf(m, __shfl_xor(m, d2));
            if (lane == 0) m8[h] = m;
        }
    }
    __syncthreads();
    float m0a[4], m0b[4];
    #pragma unroll
    for (int r = 0; r < 4; r++) { m0a[r] = m8[r]; m0b[r] = m8[4 + r]; }
    float m0l[4];
    #pragma unroll
    for (int r = 0; r < 4; r++) m0l[r] = (mrow == 0) ? m0a[r] : m0b[r];

    const float* pbase = p + (size_t)i*98304;
    // prologue: tile 0 into regs
    float4 pfA[4], pfB[4];
    #pragma unroll
    for (int r = 0; r < 4; r++) {
        int idx = r*256 + tid;
        const float* src = pbase + (idx >> 4)*128 + (idx & 15)*8;
        pfA[r] = *(const float4*)src;
        pfB[r] = *(const float4*)(src + 4);
    }

    v4f accD[2] = {};       // opair acc: z-tiles {2wid, 2wid+1}
    float lacc[4] = {0.f, 0.f, 0.f, 0.f};
    const float sqrt13 = 0.57735026918962576f;
    bool expo = (mrow < 8);

    for (int t64 = 0; t64 < 12; t64++) {
        int j0 = t64 * 64;
        // stage regs -> ptile (2x b64 per rep)
        #pragma unroll
        for (int r = 0; r < 4; r++) {
            int idx = r*256 + tid;
            int j = idx >> 4, zo = (idx & 15) * 8;
            v4bf lo, hi;
            lo[0] = (__bf16)pfA[r].x; lo[1] = (__bf16)pfA[r].y;
            lo[2] = (__bf16)pfA[r].z; lo[3] = (__bf16)pfA[r].w;
            hi[0] = (__bf16)pfB[r].x; hi[1] = (__bf16)pfB[r].y;
            hi[2] = (__bf16)pfB[r].z; hi[3] = (__bf16)pfB[r].w;
            *(v4bf*)&ptile[j][zo]     = lo;
            *(v4bf*)&ptile[j][zo + 4] = hi;
        }
        // prefetch next tile
        if (t64 < 11) {
            int j0n = j0 + 64;
            #pragma unroll
            for (int r = 0; r < 4; r++) {
                int idx = r*256 + tid;
                const float* src = pbase + (size_t)(j0n + (idx >> 4))*128 + (idx & 15)*8;
                pfA[r] = *(const float4*)src;
                pfB[r] = *(const float4*)(src + 4);
            }
        }
        __syncthreads();   // B1: ptile staged

        // att0 for this wave's 16-j column
        float a0v[4];
        if (expo) {
            int j = 16*wid + fr;
            #pragma unroll
            for (int r = 0; r < 4; r++)
                a0v[r] = att0[((size_t)(mrow + r)*768 + i)*768 + j0 + j];
        }

        // bias mfma: D[h][j16] for this wave's j-column
        v4f bd = {};
        #pragma unroll
        for (int ks = 0; ks < 4; ks++) {
            int c = ks*32 + fc;
            v4bf blo = *(const v4bf*)&ptile[16*wid + fr][c];
            v4bf bhi = *(const v4bf*)&ptile[16*wid + fr][c + 4];
            v8bf b;
            b[0]=blo[0]; b[1]=blo[1]; b[2]=blo[2]; b[3]=blo[3];
            b[4]=bhi[0]; b[5]=bhi[1]; b[6]=bhi[2]; b[7]=bhi[3];
            bd = __builtin_amdgcn_mfma_f32_16x16x32_bf16(aW[ks], b, bd, 0, 0, 0);
        }

        // w' = exp(att0 + sqrt13*(bias+bpb) - m0)
        if (expo) {
            int j = 16*wid + fr;
            float w8[4];
            #pragma unroll
            for (int r = 0; r < 4; r++) {
                int h = mrow + r;
                float L = a0v[r] + sqrt13*(bd[r] + bpb_s[h]);
                w8[r] = __expf(fminf(L - m0l[r], 60.f));
            }
            #pragma unroll
            for (int r = 0; r < 4; r++) {
                int h = mrow + r;
                unsigned short wb = f2bf(w8[r]);
                wt[h][j] = wb;
                att_bf[((size_t)h*768 + i)*768 + j0 + j] = wb;
            }
            #pragma unroll
            for (int m = 1; m < 16; m <<= 1) {
                #pragma unroll
                for (int r = 0; r < 4; r++) w8[r] += __shfl_xor(w8[r], m);
            }
            #pragma unroll
            for (int r = 0; r < 4; r++) lacc[r] += w8[r];
        }
        __syncthreads();   // B2: wt ready

        // opair mfma: D[h][z], A = wt rows, B = ptile columns
        #pragma unroll
        for (int mm = 0; mm < 2; mm++) {
            int zcol = (2*wid + mm)*16 + fr;
            #pragma unroll
            for (int ks = 0; ks < 2; ks++) {
                v8bf b;
                #pragma unroll
                for (int kk = 0; kk < 8; kk++)
                    b[kk] = *(const __bf16*)&ptile[ks*32 + fc + kk][zcol];
                v8bf a = *(const v8bf*)&wt[fr][ks*32 + fc];
                accD[mm] = __builtin_amdgcn_mfma_f32_16x16x32_bf16(a, b, accD[mm], 0, 0, 0);
            }
        }
        __syncthreads();   // B3: protect ptile for next stage
    }

    if (fr == 0 && expo) {
        #pragma unroll
        for (int r = 0; r < 4; r++) lsum_w[wid][mrow + r] = lacc[r];
    }
    __syncthreads();
    if (tid < 8) {
        float l = lsum_w[0][tid] + lsum_w[1][tid] + lsum_w[2][tid] + lsum_w[3][tid];
        float iv = 1.0f / l;
        inv_s[tid] = iv;
        linv[(size_t)tid*768 + i] = iv;
    }
    __syncthreads();
    // opair write: lane holds D[h=mrow+r][z = (2wid+mm)*16+fr]
    if (expo) {
        #pragma unroll
        for (int mm = 0; mm < 2; mm++) {
            int z = (2*wid + mm)*16 + fr;
            #pragma unroll
            for (int r = 0; r < 4; r++) {
                int h = mrow + r;
                concat[(size_t)i*CONCAT + 1408 + h*128 + z] = f2bf(accD[mm][r] * inv_s[h]);
            }
        }
    }
}

// ---------------------------------------------------------------------------
// Fused (o | opt) = (att_unnorm @ Vc^T) * linv per h; opt blocks (x==2) also
// apply rot^T/trans + norm and write opt_flat/opt_norm (optfinal fused).
// ---------------------------------------------------------------------------
__global__ __launch_bounds__(256) void attvc_mfma(
    const unsigned short* __restrict__ att_bf, const unsigned short* __restrict__ Vc,
    const float* __restrict__ linv, const float* __restrict__ rot,
    const float* __restrict__ trans, unsigned short* __restrict__ concat)
{
    __shared__ unsigned short As[64][72];
    __shared__ unsigned short Bs[64][72];
    int h = blockIdx.z;
    int i0 = blockIdx.y * 64, nd0 = blockIdx.x * 64;
    int tid = threadIdx.x, lane = tid & 63, wid = tid >> 6;
    int wr = (wid >> 1) * 32, wc = (wid & 1) * 32;
    int r = tid >> 2, c8 = (tid & 3) * 16;
    int fr = lane & 15, fc = (lane >> 4) * 8;
    v4f acc[2][2] = {};
    for (int k0 = 0; k0 < 768; k0 += 64) {
        const unsigned short* ag = att_bf + ((size_t)h*768 + i0 + r)*768 + k0 + c8;
        const unsigned short* bg = Vc + ((size_t)h*192 + nd0 + r)*768 + k0 + c8;
        *(int4*)&As[r][c8]     = *(const int4*)ag;
        *(int4*)&As[r][c8 + 8] = *(const int4*)(ag + 8);
        *(int4*)&Bs[r][c8]     = *(const int4*)bg;
        *(int4*)&Bs[r][c8 + 8] = *(const int4*)(bg + 8);
        __syncthreads();
        #pragma unroll
        for (int ks = 0; ks < 2; ks++) {
            v8bf a0 = *(const v8bf*)&As[wr + fr][ks*32 + fc];
            v8bf a1 = *(const v8bf*)&As[wr + 16 + fr][ks*32 + fc];
            v8bf b0 = *(const v8bf*)&Bs[wc + fr][ks*32 + fc];
            v8bf b1 = *(const v8bf*)&Bs[wc + 16 + fr][ks*32 + fc];
            acc[0][0] = __builtin_amdgcn_mfma_f32_16x16x32_bf16(a0, b0, acc[0][0], 0, 0, 0);
            acc[0][1] = __builtin_amdgcn_mfma_f32_16x16x32_bf16(a0, b1, acc[0][1], 0, 0, 0);
            acc[1][0] = __builtin_amdgcn_mfma_f32_16x16x32_bf16(a1, b0, acc[1][0], 0, 0, 0);
            acc[1][1] = __builtin_amdgcn_mfma_f32_16x16x32_bf16(a1, b1, acc[1][1], 0, 0, 0);
        }
        __syncthreads();
    }
    int mrow = (lane >> 4) * 4;
    float lv[2][4];
    #pragma unroll
    for (int mi = 0; mi < 2; mi++) {
        int ibase = i0 + wr + mi*16 + mrow;
        float4 l4 = *(const float4*)&linv[(size_t)h*768 + ibase];
        lv[mi][0] = l4.x; lv[mi][1] = l4.y; lv[mi][2] = l4.z; lv[mi][3] = l4.w;
    }
    if (nd0 < 128) {
        #pragma unroll
        for (int mi = 0; mi < 2; mi++) {
            #pragma unroll
            for (int ni = 0; ni < 2; ni++) {
                int d = nd0 + wc + ni*16 + fr;
                #pragma unroll
                for (int rr = 0; rr < 4; rr++) {
                    int i = i0 + wr + mi*16 + mrow + rr;
                    concat[(size_t)i*CONCAT + h*128 + d] = f2bf(acc[mi][ni][rr] * lv[mi][rr]);
                }
            }
        }
    } else {
        // opt path: write normalized opt into LDS, then rot^T/trans/norm epilogue
        float* opt_s = (float*)&As[0][0];    // 64*36*4 = 9216B == sizeof(As)
        #pragma unroll
        for (int mi = 0; mi < 2; mi++) {
            #pragma unroll
            for (int ni = 0; ni < 2; ni++) {
                int c = wc + ni*16 + fr;
                if (c < 36) {
                    #pragma unroll
                    for (int rr = 0; rr < 4; rr++) {
                        int rl = wr + mi*16 + mrow + rr;
                        opt_s[rl*36 + c] = acc[mi][ni][rr] * lv[mi][rr];
                    }
                }
            }
        }
        __syncthreads();
        for (int it = tid; it < 768; it += 256) {
            int rl = it / 12, pp = it % 12;
            int i = i0 + rl;
            const float* R = rot + i*9;
            const float* T = trans + i*3;
            float y0 = opt_s[rl*36 + pp*3 + 0] - T[0];
            float y1 = opt_s[rl*36 + pp*3 + 1] - T[1];
            float y2 = opt_s[rl*36 + pp*3 + 2] - T[2];
            float o0 = R[0]*y0 + R[3]*y1 + R[6]*y2;
            float o1 = R[1]*y0 + R[4]*y1 + R[7]*y2;
            float o2 = R[2]*y0 + R[5]*y1 + R[8]*y2;
            float nrm = sqrtf(o0*o0 + o1*o1 + o2*o2 + 1e-8f);
            int hp = h*12 + pp;
            unsigned short* cb = concat + (size_t)i*CONCAT;
            cb[1024 +   0 + hp] = f2bf(o0);
            cb[1024 +  96 + hp] = f2bf(o1);
            cb[1024 + 192 + hp] = f2bf(o2);
            cb[1312 + hp] = f2bf(nrm);
        }
    }
}

// ---------------------------------------------------------------------------
// s_out = LN(A + B) * g + be ; optional bf16 copy
// ---------------------------------------------------------------------------
template<int BF>
__global__ __launch_bounds__(256) void add_ln_kernel(
    const float* __restrict__ A, const float* __restrict__ Bv,
    const float* __restrict__ g, const float* __restrict__ be,
    float* __restrict__ out, unsigned short* __restrict__ outb)
{
    int i = blockIdx.x, t = threadIdx.x;
    float x = A[i*256 + t] + Bv[i*256 + t];
    __shared__ float red[4];
    float v = x;
    #pragma unroll
    for (int m = 1; m < 64; m <<= 1) v += __shfl_xor(v, m);
    if ((t & 63) == 0) red[t >> 6] = v;
    __syncthreads();
    float mu = (red[0] + red[1] + red[2] + red[3]) * (1.0f/256.0f);
    __syncthreads();
    float d = x - mu;
    float v2 = d*d;
    #pragma unroll
    for (int m = 1; m < 64; m <<= 1) v2 += __shfl_xor(v2, m);
    if ((t & 63) == 0) red[t >> 6] = v2;
    __syncthreads();
    float var = (red[0] + red[1] + red[2] + red[3]) * (1.0f/256.0f);
    float o = d * (1.0f/sqrtf(var + 1e-5f)) * g[t] + be[t];
    out[i*256 + t] = o;
    if (BF) outb[i*256 + t] = f2bf(o);
}

// ---------------------------------------------------------------------------
// upd head + frame composition (merged)
// ---------------------------------------------------------------------------
__global__ __launch_bounds__(256) void upd_frame_kernel(
    const float* __restrict__ s2, const float* __restrict__ Wbb,
    const float* __restrict__ bbb, const float* __restrict__ mask,
    const float* __restrict__ rot, const float* __restrict__ trans,
    float* __restrict__ rot_out, float* __restrict__ trans_out)
{
    int i = blockIdx.x, t = threadIdx.x;
    __shared__ float row[256];
    __shared__ float upd_s[6];
    row[t] = s2[i*256 + t];
    __syncthreads();
    if (t < 6) {
        float acc = bbb[t];
        #pragma unroll 8
        for (int c = 0; c < 256; c++) acc += row[c]*Wbb[t*256 + c];
        upd_s[t] = acc * mask[i];
    }
    __syncthreads();
    if (t == 0) {
        float u0 = upd_s[0], u1 = upd_s[1], u2 = upd_s[2];
        float t0 = upd_s[3], t1 = upd_s[4], t2 = upd_s[5];
        float n = sqrtf(1.f + u0*u0 + u1*u1 + u2*u2);
        float w = 1.f/n, x = u0/n, y = u1/n, z = u2/n;
        float R[3][3];
        R[0][0] = 1.f - 2.f*(y*y + z*z); R[0][1] = 2.f*(x*y - w*z);       R[0][2] = 2.f*(x*z + w*y);
        R[1][0] = 2.f*(x*y + w*z);       R[1][1] = 1.f - 2.f*(x*x + z*z); R[1][2] = 2.f*(y*z - w*x);
        R[2][0] = 2.f*(x*z - w*y);       R[2][1] = 2.f*(y*z + w*x);       R[2][2] = 1.f - 2.f*(x*x + y*y);
        const float* Ri = rot + i*9;
        #pragma unroll
        for (int a = 0; a < 3; a++) {
            #pragma unroll
            for (int b = 0; b < 3; b++) {
                float acc = 0.f;
                #pragma unroll
                for (int j = 0; j < 3; j++) acc += Ri[a*3+j]*R[j][b];
                rot_out[i*9 + a*3 + b] = acc;
            }
            trans_out[i*3 + a] = trans[i*3 + a] + Ri[a*3+0]*t0 + Ri[a*3+1]*t1 + Ri[a*3+2]*t2;
        }
    }
}

// ---------------------------------------------------------------------------
extern "C" void kernel_launch(void* const* d_in, const int* in_sizes, int n_in,
                              void* d_out, int out_size, void* d_ws, size_t ws_size,
                              hipStream_t stream)
{
    const float* s      = (const float*)d_in[0];
    const float* p      = (const float*)d_in[1];
    const float* rot    = (const float*)d_in[2];
    const float* trans  = (const float*)d_in[3];
    const float* mask   = (const float*)d_in[4];
    const float* Wq     = (const float*)d_in[5];
    const float* bq     = (const float*)d_in[6];
    const float* Wkv    = (const float*)d_in[7];
    const float* bkv    = (const float*)d_in[8];
    const float* Wqp    = (const float*)d_in[9];
    const float* bqp    = (const float*)d_in[10];
    const float* Wkvp   = (const float*)d_in[11];
    const float* bkvp   = (const float*)d_in[12];
    const float* Wpb    = (const float*)d_in[13];
    const float* bpb    = (const float*)d_in[14];
    const float* Wo     = (const float*)d_in[15];
    const float* bo     = (const float*)d_in[16];
    const float* Wt1    = (const float*)d_in[17];
    const float* bt1    = (const float*)d_in[18];
    const float* Wt2    = (const float*)d_in[19];
    const float* bt2    = (const float*)d_in[20];
    const float* Wt3    = (const float*)d_in[21];
    const float* bt3    = (const float*)d_in[22];
    const float* Wbb    = (const float*)d_in[23];
    const float* bbb    = (const float*)d_in[24];
    const float* head_w = (const float*)d_in[25];
    const float* g1     = (const float*)d_in[26];
    const float* be1    = (const float*)d_in[27];
    const float* g2     = (const float*)d_in[28];
    const float* be2    = (const float*)d_in[29];

    float* out = (float*)d_out;
    char*  wsb = (char*)d_ws;

    size_t off = 0;
    auto alloc = [&](size_t bytes) -> char* {
        char* ptr = wsb + off;
        off += (bytes + 255) & ~(size_t)255;
        return ptr;
    };
    float* qpraw   = (float*)alloc((size_t)NN*192*4);
    float* kvpraw  = (float*)alloc((size_t)NN*480*4);
    float* att     = (float*)alloc((size_t)8*768*768*4);
    float* ipa     = (float*)alloc((size_t)NN*256*4);
    float* s1      = (float*)alloc((size_t)NN*256*4);
    float* y3      = (float*)alloc((size_t)NN*256*4);
    float* linv    = (float*)alloc((size_t)8*768*4);
    unsigned short* s_bf    = (unsigned short*)alloc((size_t)NN*256*2);
    unsigned short* Wq_bf   = (unsigned short*)alloc((size_t)1024*256*2);
    unsigned short* Wkv_bf  = (unsigned short*)alloc((size_t)2048*256*2);
    unsigned short* Wqp_bf  = (unsigned short*)alloc((size_t)192*256*2);
    unsigned short* Wkvp_bf = (unsigned short*)alloc((size_t)480*256*2);
    unsigned short* Wo_bf   = (unsigned short*)alloc((size_t)256*2432*2);
    unsigned short* Wt1_bf  = (unsigned short*)alloc((size_t)256*256*2);
    unsigned short* Wt2_bf  = (unsigned short*)alloc((size_t)256*256*2);
    unsigned short* Wt3_bf  = (unsigned short*)alloc((size_t)256*256*2);
    unsigned short* q_bf    = (unsigned short*)alloc((size_t)NN*1024*2);
    unsigned short* kv_bf   = (unsigned short*)alloc((size_t)NN*2048*2);
    unsigned short* qph     = (unsigned short*)alloc((size_t)NN*256*2);
    unsigned short* qpl     = (unsigned short*)alloc((size_t)NN*256*2);
    unsigned short* kph     = (unsigned short*)alloc((size_t)NN*256*2);
    unsigned short* kpl     = (unsigned short*)alloc((size_t)NN*256*2);
    unsigned short* Vc      = (unsigned short*)alloc((size_t)8*192*768*2);
    unsigned short* att_bf  = (unsigned short*)alloc((size_t)8*768*768*2);
    unsigned short* concat  = (unsigned short*)alloc((size_t)NN*CONCAT*2);
    unsigned short* s1b     = (unsigned short*)alloc((size_t)NN*256*2);
    unsigned short* x1b     = (unsigned short*)alloc((size_t)NN*256*2);
    unsigned short* x2b     = (unsigned short*)alloc((size_t)NN*256*2);

    // 0) ipa pre-bias (independent) + weight conversion
    ipa_init_kernel<<<768, 256, 0, stream>>>(bo, ipa);

    CvtDesc cd;
    const float* csrc[NCVT]    = {s, Wq, Wkv, Wqp, Wkvp, Wo, Wt1, Wt2, Wt3};
    unsigned short* cdst[NCVT] = {s_bf, Wq_bf, Wkv_bf, Wqp_bf, Wkvp_bf, Wo_bf, Wt1_bf, Wt2_bf, Wt3_bf};
    int csz[NCVT] = {NN*256, 1024*256, 2048*256, 192*256, 480*256, 256*2432, 256*256, 256*256, 256*256};
    int cum = 0;
    for (int i2 = 0; i2 < NCVT; i2++) {
        cd.src[i2] = csrc[i2]; cd.dst[i2] = cdst[i2]; cd.nelem[i2] = csz[i2];
        cd.blk_start[i2] = cum;
        cum += (csz[i2] + 2047) / 2048;
    }
    cd.blk_start[NCVT] = cum;
    cvt_many<<<cum, 256, 0, stream>>>(cd);

    // 1) All projections in one GEMM launch
    ProjDesc pd;
    pd.W[0] = Wq_bf;   pd.bias[0] = bq;   pd.dstb[0] = q_bf;   pd.dstf[0] = nullptr; pd.D[0] = 1024; pd.ldc[0] = 1024; pd.mode[0] = 2;
    pd.W[1] = Wkv_bf;  pd.bias[1] = bkv;  pd.dstb[1] = kv_bf;  pd.dstf[1] = nullptr; pd.D[1] = 2048; pd.ldc[1] = 2048; pd.mode[1] = 2;
    pd.W[2] = Wqp_bf;  pd.bias[2] = bqp;  pd.dstb[2] = nullptr; pd.dstf[2] = qpraw;  pd.D[2] = 192;  pd.ldc[2] = 192;  pd.mode[2] = 0;
    pd.W[3] = Wkvp_bf; pd.bias[3] = bkvp; pd.dstb[3] = nullptr; pd.dstf[3] = kvpraw; pd.D[3] = 480;  pd.ldc[3] = 480;  pd.mode[3] = 0;
    pd.blk_start[0] = 0; pd.blk_start[1] = 16; pd.blk_start[2] = 48; pd.blk_start[3] = 51; pd.blk_start[4] = 59;
    proj_all<<<dim3(59, 12), 256, 0, stream>>>(s_bf, pd);

    // 2) Rotations + V transpose
    rotate_kernel<<<(NN*HH*28 + 255)/256, 256, 0, stream>>>(
        qpraw, kvpraw, rot, trans, qph, qpl, kph, kpl, Vc);
    vtrans_kernel<<<8*24, 256, 0, stream>>>(kv_bf, Vc);

    // 3) Pre-bias logits, then single-pass p kernel
    logits_mfma<<<dim3(12, 12, 8), 256, 0, stream>>>(
        q_bf, kv_bf, qph, qpl, kph, kpl, mask, head_w, att);
    fused_p3_kernel<<<768, 256, 0, stream>>>(att, p, Wpb, bpb, att_bf, linv, concat);

    // 4) Attention outputs -> concat (o, opt(+final), opair already done)
    attvc_mfma<<<dim3(3, 12, 8), 256, 0, stream>>>(att_bf, Vc, linv, rot, trans, concat);

    // 5) Output projection (split-K MFMA) + residual LN
    mfma_gemm<4,0,0><<<dim3(4,12,4), 256, 0, stream>>>(concat, Wo_bf, nullptr, ipa, nullptr, 256, 2432, 256);
    add_ln_kernel<1><<<768, 256, 0, stream>>>(s, ipa, g1, be1, s1, s1b);

    // 6) Transition MLP + residual LN
    mfma_gemm<1,2,1><<<dim3(4,12), 256, 0, stream>>>(s1b, Wt1_bf, bt1, nullptr, x1b, 256, 256, 256);
    mfma_gemm<1,2,1><<<dim3(4,12), 256, 0, stream>>>(x1b, Wt2_bf, bt2, nullptr, x2b, 256, 256, 256);
    mfma_gemm<1,0,0><<<dim3(4,12), 256, 0, stream>>>(x2b, Wt3_bf, bt3, y3, nullptr, 256, 256, 256);
    add_ln_kernel<0><<<768, 256, 0, stream>>>(s1, y3, g2, be2, out, nullptr);

    // 7) Backbone update + frame composition (merged)
    upd_frame_kernel<<<768, 256, 0, stream>>>(out, Wbb, bbb, mask, rot, trans,
                                              out + (size_t)NN*256, out + (size_t)NN*256 + (size_t)NN*9);
}

// Round 7
// 192.728 us; speedup vs baseline: 3.8785x; 1.0124x over previous
//
#include <hip/hip_runtime.h>
#include <hip/hip_bf16.h>
#include <math.h>

// Problem constants
#define NN 768
#define CS 256
#define CZ 128
#define CH 128
#define HH 8
#define PQK 8
#define PV 12
#define CONCAT 2432   // 1024 + 288 + 96 + 1024
#define ATT_HSTRIDE (768*768)

typedef __bf16 v8bf __attribute__((ext_vector_type(8)));
typedef __bf16 v4bf __attribute__((ext_vector_type(4)));
typedef float  v4f  __attribute__((ext_vector_type(4)));

__device__ inline unsigned short f2bf(float f) {
    union { float f; unsigned u; } v; v.f = f;
    unsigned r = v.u + 0x7FFFu + ((v.u >> 16) & 1u);
    return (unsigned short)(r >> 16);
}
__device__ inline float bf2f(unsigned short u) {
    union { unsigned u; float f; } v; v.u = ((unsigned)u) << 16; return v.f;
}
// order-preserving float<->uint encoding (for atomicMax on floats)
__device__ inline unsigned encf(float f) {
    unsigned u = __float_as_uint(f);
    return (u >> 31) ? ~u : (u | 0x80000000u);
}
__device__ inline float decf(unsigned e) {
    unsigned u = (e >> 31) ? (e & 0x7FFFFFFFu) : ~e;
    return __uint_as_float(u);
}

// ---------------------------------------------------------------------------
// Batched f32 -> bf16 conversion
// ---------------------------------------------------------------------------
#define NCVT 9
struct CvtDesc {
    const float* src[NCVT];
    unsigned short* dst[NCVT];
    int nelem[NCVT];
    int blk_start[NCVT + 1];
};

__global__ __launch_bounds__(256) void cvt_many(CvtDesc d)
{
    int b = blockIdx.x;
    int seg = 0;
    #pragma unroll
    for (int i = 0; i < NCVT - 1; i++) if (b >= d.blk_start[i + 1]) seg = i + 1;
    int local = b - d.blk_start[seg];
    int base = local * 2048 + threadIdx.x;
    const float* s = d.src[seg];
    unsigned short* o = d.dst[seg];
    int n = d.nelem[seg];
    #pragma unroll
    for (int r = 0; r < 8; r++) {
        int idx = base + r * 256;
        if (idx < n) o[idx] = f2bf(s[idx]);
    }
}

// ---------------------------------------------------------------------------
// Combined projection GEMM: 4 weight segments, shared A = s_bf, K=256.
// ---------------------------------------------------------------------------
struct ProjDesc {
    const unsigned short* W[4];
    const float* bias[4];
    unsigned short* dstb[4];
    float* dstf[4];
    int D[4];
    int ldc[4];
    int mode[4];
    int blk_start[5];
};

__global__ __launch_bounds__(256) void proj_all(const unsigned short* __restrict__ A, ProjDesc d)
{
    __shared__ unsigned short As[64][40];
    __shared__ unsigned short Ws[64][40];
    int bx = blockIdx.x;
    int seg = 0;
    #pragma unroll
    for (int q = 0; q < 3; q++) if (bx >= d.blk_start[q + 1]) seg = q + 1;
    int bd = (bx - d.blk_start[seg]) * 64;
    int bi = blockIdx.y * 64;
    const unsigned short* W = d.W[seg];
    int D = d.D[seg], ldc = d.ldc[seg];

    int tid = threadIdx.x, lane = tid & 63, wid = tid >> 6;
    int wr = (wid >> 1) * 32, wc = (wid & 1) * 32;
    v4f acc[2][2] = {};
    int lrow = tid >> 2, lcol = (tid & 3) * 8;
    const unsigned short* Ap = A + (size_t)(bi + lrow) * 256 + lcol;
    const unsigned short* Wp = W + (size_t)(bd + lrow) * 256 + lcol;
    bool wv = (bd + lrow) < D;
    int fr = lane & 15, fc = (lane >> 4) * 8;

    for (int k0 = 0; k0 < 256; k0 += 32) {
        *(int4*)&As[lrow][lcol] = *(const int4*)(Ap + k0);
        int4 wz = {0, 0, 0, 0};
        *(int4*)&Ws[lrow][lcol] = wv ? *(const int4*)(Wp + k0) : wz;
        __syncthreads();
        v8bf a0 = *(const v8bf*)&As[wr + fr][fc];
        v8bf a1 = *(const v8bf*)&As[wr + 16 + fr][fc];
        v8bf b0 = *(const v8bf*)&Ws[wc + fr][fc];
        v8bf b1 = *(const v8bf*)&Ws[wc + 16 + fr][fc];
        acc[0][0] = __builtin_amdgcn_mfma_f32_16x16x32_bf16(a0, b0, acc[0][0], 0, 0, 0);
        acc[0][1] = __builtin_amdgcn_mfma_f32_16x16x32_bf16(a0, b1, acc[0][1], 0, 0, 0);
        acc[1][0] = __builtin_amdgcn_mfma_f32_16x16x32_bf16(a1, b0, acc[1][0], 0, 0, 0);
        acc[1][1] = __builtin_amdgcn_mfma_f32_16x16x32_bf16(a1, b1, acc[1][1], 0, 0, 0);
        __syncthreads();
    }
    const float* bias = d.bias[seg];
    int mode = d.mode[seg];
    unsigned short* Cb = d.dstb[seg];
    float* Cf = d.dstf[seg];
    int mrow = (lane >> 4) * 4;
    #pragma unroll
    for (int mi = 0; mi < 2; mi++) {
        #pragma unroll
        for (int ni = 0; ni < 2; ni++) {
            int dd = bd + wc + ni * 16 + fr;
            if (dd < D) {
                #pragma unroll
                for (int r = 0; r < 4; r++) {
                    int m = bi + wr + mi * 16 + mrow + r;
                    float v = acc[mi][ni][r] + bias[dd];
                    if (mode == 2) Cb[(size_t)m * ldc + dd] = f2bf(v);
                    else           Cf[(size_t)m * ldc + dd] = v;
                }
            }
        }
    }
}

// ---------------------------------------------------------------------------
// Generic MFMA bf16 GEMM (used for Wo split-K)
// ---------------------------------------------------------------------------
template<int SPLITK, int MODE, int RELU>
__global__ __launch_bounds__(256) void mfma_gemm(
    const unsigned short* __restrict__ A,
    const unsigned short* __restrict__ W,
    const float* __restrict__ bias,
    float* __restrict__ C,
    unsigned short* __restrict__ Cb,
    int D, int K, int ldc)
{
    __shared__ unsigned short As[64][40];
    __shared__ unsigned short Ws[64][40];
    int tid = threadIdx.x;
    int bi = blockIdx.y * 64;
    int bd = blockIdx.x * 64;
    int kpb = K / SPLITK;
    int k0b = blockIdx.z * kpb;
    int lane = tid & 63;
    int wid = tid >> 6;
    int wr = (wid >> 1) * 32, wc = (wid & 1) * 32;
    v4f acc[2][2] = {};
    int lrow = tid >> 2;
    int lcol = (tid & 3) * 8;
    const unsigned short* Ap = A + (size_t)(bi + lrow) * K + lcol;
    const unsigned short* Wp = W + (size_t)(bd + lrow) * K + lcol;
    bool wv = (bd + lrow) < D;
    int fr = lane & 15, fc = (lane >> 4) * 8;

    for (int k0 = k0b; k0 < k0b + kpb; k0 += 32) {
        *(int4*)&As[lrow][lcol] = *(const int4*)(Ap + k0);
        int4 wz = {0, 0, 0, 0};
        *(int4*)&Ws[lrow][lcol] = wv ? *(const int4*)(Wp + k0) : wz;
        __syncthreads();
        v8bf a0 = *(const v8bf*)&As[wr + fr][fc];
        v8bf a1 = *(const v8bf*)&As[wr + 16 + fr][fc];
        v8bf b0 = *(const v8bf*)&Ws[wc + fr][fc];
        v8bf b1 = *(const v8bf*)&Ws[wc + 16 + fr][fc];
        acc[0][0] = __builtin_amdgcn_mfma_f32_16x16x32_bf16(a0, b0, acc[0][0], 0, 0, 0);
        acc[0][1] = __builtin_amdgcn_mfma_f32_16x16x32_bf16(a0, b1, acc[0][1], 0, 0, 0);
        acc[1][0] = __builtin_amdgcn_mfma_f32_16x16x32_bf16(a1, b0, acc[1][0], 0, 0, 0);
        acc[1][1] = __builtin_amdgcn_mfma_f32_16x16x32_bf16(a1, b1, acc[1][1], 0, 0, 0);
        __syncthreads();
    }
    int mrow = (lane >> 4) * 4;
    #pragma unroll
    for (int mi = 0; mi < 2; mi++) {
        #pragma unroll
        for (int ni = 0; ni < 2; ni++) {
            int d = bd + wc + ni * 16 + fr;
            if (d < D) {
                #pragma unroll
                for (int r = 0; r < 4; r++) {
                    int m = bi + wr + mi * 16 + mrow + r;
                    float v = acc[mi][ni][r];
                    if (SPLITK > 1) {
                        atomicAdd(&C[(size_t)m * ldc + d], v);
                    } else {
                        v += bias[d];
                        if (RELU) v = fmaxf(v, 0.f);
                        if (MODE != 2) C[(size_t)m * ldc + d] = v;
                        if (MODE >= 1) Cb[(size_t)m * ldc + d] = f2bf(v);
                    }
                }
            }
        }
    }
}

// ---------------------------------------------------------------------------
// prep2: rotate points (blocks < 672) + V transpose (blocks >= 672)
// ---------------------------------------------------------------------------
__global__ __launch_bounds__(256) void prep2_kernel(
    const float* __restrict__ qpraw, const float* __restrict__ kvpraw,
    const float* __restrict__ rot, const float* __restrict__ trans,
    const unsigned short* __restrict__ kv_bf,
    unsigned short* __restrict__ qph, unsigned short* __restrict__ qpl,
    unsigned short* __restrict__ kph, unsigned short* __restrict__ kpl,
    unsigned short* __restrict__ Vc)
{
    __shared__ unsigned short tile[32][136];
    int bx = blockIdx.x;
    int t = threadIdx.x;
    if (bx < 672) {
        int id = bx*256 + t;
        int i = id / (HH*28);
        int rem = id % (HH*28);
        int h = rem / 28;
        int idx = rem % 28;
        const float* R = rot + i*9;
        const float* T = trans + i*3;
        float s0, s1, s2;
        if (idx < 8) {
            s0 = qpraw[i*192 +   0 + h*8 + idx];
            s1 = qpraw[i*192 +  64 + h*8 + idx];
            s2 = qpraw[i*192 + 128 + h*8 + idx];
        } else {
            int pp = idx - 8;
            s0 = kvpraw[i*480 +   0 + h*20 + pp];
            s1 = kvpraw[i*480 + 160 + h*20 + pp];
            s2 = kvpraw[i*480 + 320 + h*20 + pp];
        }
        float ov[3];
        ov[0] = R[0]*s0 + R[1]*s1 + R[2]*s2 + T[0];
        ov[1] = R[3]*s0 + R[4]*s1 + R[5]*s2 + T[1];
        ov[2] = R[6]*s0 + R[7]*s1 + R[8]*s2 + T[2];
        if (idx < 8) {
            #pragma unroll
            for (int x = 0; x < 3; x++) {
                unsigned short hi = f2bf(ov[x]);
                qph[i*256 + h*32 + idx*3 + x] = hi;
                qpl[i*256 + h*32 + idx*3 + x] = f2bf(ov[x] - bf2f(hi));
            }
            if (idx == 0) {
                #pragma unroll
                for (int m = 24; m < 32; m++) { qph[i*256+h*32+m] = 0; qpl[i*256+h*32+m] = 0; }
            }
        } else if (idx < 16) {
            int pp = idx - 8;
            #pragma unroll
            for (int x = 0; x < 3; x++) {
                unsigned short hi = f2bf(ov[x]);
                kph[i*256 + h*32 + pp*3 + x] = hi;
                kpl[i*256 + h*32 + pp*3 + x] = f2bf(ov[x] - bf2f(hi));
            }
            if (idx == 8) {
                #pragma unroll
                for (int m = 24; m < 32; m++) { kph[i*256+h*32+m] = 0; kpl[i*256+h*32+m] = 0; }
            }
        } else {
            int ppv = idx - 16;
            #pragma unroll
            for (int x = 0; x < 3; x++)
                Vc[((size_t)h*192 + 128 + ppv*3 + x)*768 + i] = f2bf(ov[x]);
        }
    } else {
        int bx2 = bx - 672;
        int h = bx2 & 7, jt = bx2 >> 3;
        int r = t >> 3, c0 = (t & 7) * 16;
        const unsigned short* src = kv_bf + (size_t)(jt*32 + r)*2048 + h*256 + 128 + c0;
        *(int4*)&tile[r][c0]     = *(const int4*)src;
        *(int4*)&tile[r][c0 + 8] = *(const int4*)(src + 8);
        __syncthreads();
        int c = t >> 1, jh = (t & 1) * 16;
        unsigned short tmp[16];
        #pragma unroll
        for (int k = 0; k < 16; k++) tmp[k] = tile[jh + k][c];
        unsigned short* dst = Vc + ((size_t)h*192 + c)*768 + jt*32 + jh;
        *(int4*)dst       = *(int4*)&tmp[0];
        *(int4*)(dst + 8) = *(int4*)&tmp[8];
    }
}

// ---------------------------------------------------------------------------
// Logits via MFMA + per-row max folded in via order-encoded atomicMax.
// ---------------------------------------------------------------------------
__global__ __launch_bounds__(256) void logits_mfma(
    const unsigned short* __restrict__ q_bf, const unsigned short* __restrict__ kv_bf,
    const unsigned short* __restrict__ qph, const unsigned short* __restrict__ qpl,
    const unsigned short* __restrict__ kph, const unsigned short* __restrict__ kpl,
    const float* __restrict__ mask, const float* __restrict__ head_w,
    float* __restrict__ att, unsigned* __restrict__ m0enc)
{
    __shared__ unsigned short Qs[64][136];
    __shared__ unsigned short Ks[64][136];
    __shared__ unsigned short Aph[64][40], Apl[64][40], Bph[64][40], Bpl[64][40];
    __shared__ float Qss[64], Kss[64], Mi[64], Mj[64];
    int h = blockIdx.z;
    int i0 = blockIdx.y * 64, j0 = blockIdx.x * 64;
    int tid = threadIdx.x, lane = tid & 63, wid = tid >> 6;
    int wr = (wid >> 1) * 32, wc = (wid & 1) * 32;
    int r = tid >> 2, cq = (tid & 3) * 32;
    const unsigned short* qg = q_bf  + (size_t)(i0 + r)*1024 + h*128 + cq;
    const unsigned short* kg = kv_bf + (size_t)(j0 + r)*2048 + h*256 + cq;
    #pragma unroll
    for (int kk = 0; kk < 4; kk++) {
        *(int4*)&Qs[r][cq + kk*8] = *(const int4*)(qg + kk*8);
        *(int4*)&Ks[r][cq + kk*8] = *(const int4*)(kg + kk*8);
    }
    int cp = (tid & 3) * 8;
    *(int4*)&Aph[r][cp] = *(const int4*)(qph + (size_t)(i0 + r)*256 + h*32 + cp);
    *(int4*)&Apl[r][cp] = *(const int4*)(qpl + (size_t)(i0 + r)*256 + h*32 + cp);
    *(int4*)&Bph[r][cp] = *(const int4*)(kph + (size_t)(j0 + r)*256 + h*32 + cp);
    *(int4*)&Bpl[r][cp] = *(const int4*)(kpl + (size_t)(j0 + r)*256 + h*32 + cp);
    if (tid < 64) {
        Mi[tid] = mask[i0 + tid];
        Mj[tid] = mask[j0 + tid];
    }
    __syncthreads();
    if (tid < 64) {
        float qs2 = 0.f, ks2 = 0.f;
        #pragma unroll
        for (int m = 0; m < 24; m++) {
            float qv = bf2f(Aph[tid][m]) + bf2f(Apl[tid][m]);
            float kv = bf2f(Bph[tid][m]) + bf2f(Bpl[tid][m]);
            qs2 += qv*qv; ks2 += kv*kv;
        }
        Qss[tid] = qs2; Kss[tid] = ks2;
    }
    int fr = lane & 15, fc = (lane >> 4) * 8;
    v4f aqk[2][2] = {}, ap[2][2] = {};
    #pragma unroll
    for (int ks = 0; ks < 4; ks++) {
        v8bf a0 = *(const v8bf*)&Qs[wr + fr][ks*32 + fc];
        v8bf a1 = *(const v8bf*)&Qs[wr + 16 + fr][ks*32 + fc];
        v8bf b0 = *(const v8bf*)&Ks[wc + fr][ks*32 + fc];
        v8bf b1 = *(const v8bf*)&Ks[wc + 16 + fr][ks*32 + fc];
        aqk[0][0] = __builtin_amdgcn_mfma_f32_16x16x32_bf16(a0, b0, aqk[0][0], 0, 0, 0);
        aqk[0][1] = __builtin_amdgcn_mfma_f32_16x16x32_bf16(a0, b1, aqk[0][1], 0, 0, 0);
        aqk[1][0] = __builtin_amdgcn_mfma_f32_16x16x32_bf16(a1, b0, aqk[1][0], 0, 0, 0);
        aqk[1][1] = __builtin_amdgcn_mfma_f32_16x16x32_bf16(a1, b1, aqk[1][1], 0, 0, 0);
    }
    {
        v8bf ah0 = *(const v8bf*)&Aph[wr + fr][fc];
        v8bf ah1 = *(const v8bf*)&Aph[wr + 16 + fr][fc];
        v8bf al0 = *(const v8bf*)&Apl[wr + fr][fc];
        v8bf al1 = *(const v8bf*)&Apl[wr + 16 + fr][fc];
        v8bf bh0 = *(const v8bf*)&Bph[wc + fr][fc];
        v8bf bh1 = *(const v8bf*)&Bph[wc + 16 + fr][fc];
        v8bf bl0 = *(const v8bf*)&Bpl[wc + fr][fc];
        v8bf bl1 = *(const v8bf*)&Bpl[wc + 16 + fr][fc];
        ap[0][0] = __builtin_amdgcn_mfma_f32_16x16x32_bf16(ah0, bh0, ap[0][0], 0, 0, 0);
        ap[0][1] = __builtin_amdgcn_mfma_f32_16x16x32_bf16(ah0, bh1, ap[0][1], 0, 0, 0);
        ap[1][0] = __builtin_amdgcn_mfma_f32_16x16x32_bf16(ah1, bh0, ap[1][0], 0, 0, 0);
        ap[1][1] = __builtin_amdgcn_mfma_f32_16x16x32_bf16(ah1, bh1, ap[1][1], 0, 0, 0);
        ap[0][0] = __builtin_amdgcn_mfma_f32_16x16x32_bf16(ah0, bl0, ap[0][0], 0, 0, 0);
        ap[0][1] = __builtin_amdgcn_mfma_f32_16x16x32_bf16(ah0, bl1, ap[0][1], 0, 0, 0);
        ap[1][0] = __builtin_amdgcn_mfma_f32_16x16x32_bf16(ah1, bl0, ap[1][0], 0, 0, 0);
        ap[1][1] = __builtin_amdgcn_mfma_f32_16x16x32_bf16(ah1, bl1, ap[1][1], 0, 0, 0);
        ap[0][0] = __builtin_amdgcn_mfma_f32_16x16x32_bf16(al0, bh0, ap[0][0], 0, 0, 0);
        ap[0][1] = __builtin_amdgcn_mfma_f32_16x16x32_bf16(al0, bh1, ap[0][1], 0, 0, 0);
        ap[1][0] = __builtin_amdgcn_mfma_f32_16x16x32_bf16(al1, bh0, ap[1][0], 0, 0, 0);
        ap[1][1] = __builtin_amdgcn_mfma_f32_16x16x32_bf16(al1, bh1, ap[1][1], 0, 0, 0);
    }
    __syncthreads();
    float hx = head_w[h];
    float sp = (hx > 20.f) ? hx : log1pf(__expf(hx));
    float hw = sp * 0.09622504486493764f;
    const float scale_qk = 0.05103103630798288f;
    int mrow = (lane >> 4) * 4;
    float val[2][2][4];
    #pragma unroll
    for (int mi = 0; mi < 2; mi++) {
        #pragma unroll
        for (int ni = 0; ni < 2; ni++) {
            int jl = wc + ni*16 + fr;
            #pragma unroll
            for (int rr = 0; rr < 4; rr++) {
                int il = wr + mi*16 + mrow + rr;
                float v = aqk[mi][ni][rr]*scale_qk + hw*ap[mi][ni][rr]
                        - 0.5f*hw*(Qss[il] + Kss[jl])
                        + 100000.0f*(Mi[il]*Mj[jl] - 1.0f);
                val[mi][ni][rr] = v;
                att[(size_t)h*ATT_HSTRIDE + (size_t)(i0 + il)*768 + (j0 + jl)] = v;
            }
        }
    }
    // per-row max over this block's 64 j, then atomicMax into m0enc
    #pragma unroll
    for (int mi = 0; mi < 2; mi++) {
        #pragma unroll
        for (int rr = 0; rr < 4; rr++) {
            float m = fmaxf(val[mi][0][rr], val[mi][1][rr]);
            #pragma unroll
            for (int d2 = 1; d2 < 16; d2 <<= 1) m = fmaxf(m, __shfl_xor(m, d2));
            if (fr == 0) {
                int il = wr + mi*16 + mrow + rr;
                atomicMax(&m0enc[h*768 + i0 + il], encf(m));
            }
        }
    }
}

// ---------------------------------------------------------------------------
// fused_p3s: half of the j-range per block; single pass over p; MFMA bias +
// MFMA opair (B-fragments from ptile columns). Writes unnormalized att_bf +
// f32 partials (lpart, opart).
// ---------------------------------------------------------------------------
__global__ __launch_bounds__(256) void fused_p3s_kernel(
    const float* __restrict__ att0,
    const float* __restrict__ p,
    const float* __restrict__ Wpb, const float* __restrict__ bpb,
    const unsigned* __restrict__ m0enc,
    unsigned short* __restrict__ att_bf,
    float* __restrict__ lpart,
    float* __restrict__ opart)
{
    __shared__ unsigned short ptile[64][132];
    __shared__ unsigned short wt[16][72];
    __shared__ float bpb_s[8], m8[8], lsum_w[4][8];

    int i = blockIdx.x;
    int half = blockIdx.y;
    int jbase = half * 384;
    int tid = threadIdx.x, lane = tid & 63, wid = tid >> 6;
    int fr = lane & 15, fc = (lane >> 4) * 8;
    int mrow = (lane >> 4) * 4;

    for (int idx = tid; idx < 16*72; idx += 256) ((unsigned short*)wt)[idx] = 0;
    if (tid < 8) {
        bpb_s[tid] = bpb[tid];
        m8[tid] = decf(m0enc[tid*768 + i]);
    }

    v8bf aW[4];
    #pragma unroll
    for (int ks = 0; ks < 4; ks++) {
        v8bf v = {};
        if (fr < 8) {
            const float* wp = Wpb + fr*128 + ks*32 + fc;
            float4 w0 = *(const float4*)wp;
            float4 w1 = *(const float4*)(wp + 4);
            v[0] = (__bf16)w0.x; v[1] = (__bf16)w0.y; v[2] = (__bf16)w0.z; v[3] = (__bf16)w0.w;
            v[4] = (__bf16)w1.x; v[5] = (__bf16)w1.y; v[6] = (__bf16)w1.z; v[7] = (__bf16)w1.w;
        }
        aW[ks] = v;
    }
    __syncthreads();
    float m0l[4];
    #pragma unroll
    for (int r = 0; r < 4; r++) m0l[r] = (mrow == 0) ? m8[r] : m8[4 + r];

    const float* pbase = p + (size_t)i*98304 + (size_t)jbase*128;
    float4 pfA[4], pfB[4];
    #pragma unroll
    for (int r = 0; r < 4; r++) {
        int idx = r*256 + tid;
        const float* src = pbase + (idx >> 4)*128 + (idx & 15)*8;
        pfA[r] = *(const float4*)src;
        pfB[r] = *(const float4*)(src + 4);
    }

    v4f accD[2] = {};
    float lacc[4] = {0.f, 0.f, 0.f, 0.f};
    const float sqrt13 = 0.57735026918962576f;
    bool expo = (mrow < 8);

    for (int t64 = 0; t64 < 6; t64++) {
        int j0 = jbase + t64 * 64;
        #pragma unroll
        for (int r = 0; r < 4; r++) {
            int idx = r*256 + tid;
            int j = idx >> 4, zo = (idx & 15) * 8;
            v4bf lo, hi;
            lo[0] = (__bf16)pfA[r].x; lo[1] = (__bf16)pfA[r].y;
            lo[2] = (__bf16)pfA[r].z; lo[3] = (__bf16)pfA[r].w;
            hi[0] = (__bf16)pfB[r].x; hi[1] = (__bf16)pfB[r].y;
            hi[2] = (__bf16)pfB[r].z; hi[3] = (__bf16)pfB[r].w;
            *(v4bf*)&ptile[j][zo]     = lo;
            *(v4bf*)&ptile[j][zo + 4] = hi;
        }
        if (t64 < 5) {
            #pragma unroll
            for (int r = 0; r < 4; r++) {
                int idx = r*256 + tid;
                const float* src = pbase + (size_t)((t64+1)*64 + (idx >> 4))*128 + (idx & 15)*8;
                pfA[r] = *(const float4*)src;
                pfB[r] = *(const float4*)(src + 4);
            }
        }
        __syncthreads();   // B1: ptile staged

        float a0v[4];
        if (expo) {
            int j = 16*wid + fr;
            #pragma unroll
            for (int r = 0; r < 4; r++)
                a0v[r] = att0[((size_t)(mrow + r)*768 + i)*768 + j0 + j];
        }

        v4f bd = {};
        #pragma unroll
        for (int ks = 0; ks < 4; ks++) {
            int c = ks*32 + fc;
            v4bf blo = *(const v4bf*)&ptile[16*wid + fr][c];
            v4bf bhi = *(const v4bf*)&ptile[16*wid + fr][c + 4];
            v8bf b;
            b[0]=blo[0]; b[1]=blo[1]; b[2]=blo[2]; b[3]=blo[3];
            b[4]=bhi[0]; b[5]=bhi[1]; b[6]=bhi[2]; b[7]=bhi[3];
            bd = __builtin_amdgcn_mfma_f32_16x16x32_bf16(aW[ks], b, bd, 0, 0, 0);
        }

        if (expo) {
            int j = 16*wid + fr;
            float w8[4];
            #pragma unroll
            for (int r = 0; r < 4; r++) {
                int h = mrow + r;
                float L = a0v[r] + sqrt13*(bd[r] + bpb_s[h]);
                w8[r] = __expf(fminf(L - m0l[r], 60.f));
            }
            #pragma unroll
            for (int r = 0; r < 4; r++) {
                int h = mrow + r;
                unsigned short wb = f2bf(w8[r]);
                wt[h][j] = wb;
                att_bf[((size_t)h*768 + i)*768 + j0 + j] = wb;
            }
            #pragma unroll
            for (int m = 1; m < 16; m <<= 1) {
                #pragma unroll
                for (int r = 0; r < 4; r++) w8[r] += __shfl_xor(w8[r], m);
            }
            #pragma unroll
            for (int r = 0; r < 4; r++) lacc[r] += w8[r];
        }
        __syncthreads();   // B2: wt ready

        #pragma unroll
        for (int mm = 0; mm < 2; mm++) {
            int zcol = (2*wid + mm)*16 + fr;
            #pragma unroll
            for (int ks = 0; ks < 2; ks++) {
                v8bf b;
                #pragma unroll
                for (int kk = 0; kk < 8; kk++)
                    b[kk] = *(const __bf16*)&ptile[ks*32 + fc + kk][zcol];
                v8bf a = *(const v8bf*)&wt[fr][ks*32 + fc];
                accD[mm] = __builtin_amdgcn_mfma_f32_16x16x32_bf16(a, b, accD[mm], 0, 0, 0);
            }
        }
        __syncthreads();   // B3: protect ptile
    }

    if (fr == 0 && expo) {
        #pragma unroll
        for (int r = 0; r < 4; r++) lsum_w[wid][mrow + r] = lacc[r];
    }
    __syncthreads();
    if (tid < 8) {
        lpart[(size_t)(half*8 + tid)*768 + i] =
            lsum_w[0][tid] + lsum_w[1][tid] + lsum_w[2][tid] + lsum_w[3][tid];
    }
    if (expo) {
        float* ob = opart + (size_t)(half*768 + i)*1024;
        #pragma unroll
        for (int mm = 0; mm < 2; mm++) {
            int z = (2*wid + mm)*16 + fr;
            #pragma unroll
            for (int r = 0; r < 4; r++)
                ob[(mrow + r)*128 + z] = accD[mm][r];
        }
    }
}

// ---------------------------------------------------------------------------
// preduce: sum the two j-half partials -> linv + opair into concat
// ---------------------------------------------------------------------------
__global__ __launch_bounds__(256) void preduce_kernel(
    const float* __restrict__ lpart, const float* __restrict__ opart,
    float* __restrict__ linv, unsigned short* __restrict__ concat)
{
    __shared__ float inv_s[8];
    int i = blockIdx.x, t = threadIdx.x;
    if (t < 8) {
        float l = lpart[(size_t)t*768 + i] + lpart[(size_t)(8 + t)*768 + i];
        float iv = 1.0f / l;
        inv_s[t] = iv;
        linv[(size_t)t*768 + i] = iv;
    }
    __syncthreads();
    const float* o0 = opart + (size_t)i*1024;
    const float* o1 = opart + (size_t)(768 + i)*1024;
    #pragma unroll
    for (int k = 0; k < 4; k++) {
        int c = t + k*256;
        float s = o0[c] + o1[c];
        concat[(size_t)i*CONCAT + 1408 + c] = f2bf(s * inv_s[c >> 7]);
    }
}

// ---------------------------------------------------------------------------
// Fused (o | opt) = (att_unnorm @ Vc^T) * linv per h; opt blocks also do
// rot^T/trans/norm epilogue.
// ---------------------------------------------------------------------------
__global__ __launch_bounds__(256) void attvc_mfma(
    const unsigned short* __restrict__ att_bf, const unsigned short* __restrict__ Vc,
    const float* __restrict__ linv, const float* __restrict__ rot,
    const float* __restrict__ trans, unsigned short* __restrict__ concat)
{
    __shared__ unsigned short As[64][72];
    __shared__ unsigned short Bs[64][72];
    int h = blockIdx.z;
    int i0 = blockIdx.y * 64, nd0 = blockIdx.x * 64;
    int tid = threadIdx.x, lane = tid & 63, wid = tid >> 6;
    int wr = (wid >> 1) * 32, wc = (wid & 1) * 32;
    int r = tid >> 2, c8 = (tid & 3) * 16;
    int fr = lane & 15, fc = (lane >> 4) * 8;
    v4f acc[2][2] = {};
    for (int k0 = 0; k0 < 768; k0 += 64) {
        const unsigned short* ag = att_bf + ((size_t)h*768 + i0 + r)*768 + k0 + c8;
        const unsigned short* bg = Vc + ((size_t)h*192 + nd0 + r)*768 + k0 + c8;
        *(int4*)&As[r][c8]     = *(const int4*)ag;
        *(int4*)&As[r][c8 + 8] = *(const int4*)(ag + 8);
        *(int4*)&Bs[r][c8]     = *(const int4*)bg;
        *(int4*)&Bs[r][c8 + 8] = *(const int4*)(bg + 8);
        __syncthreads();
        #pragma unroll
        for (int ks = 0; ks < 2; ks++) {
            v8bf a0 = *(const v8bf*)&As[wr + fr][ks*32 + fc];
            v8bf a1 = *(const v8bf*)&As[wr + 16 + fr][ks*32 + fc];
            v8bf b0 = *(const v8bf*)&Bs[wc + fr][ks*32 + fc];
            v8bf b1 = *(const v8bf*)&Bs[wc + 16 + fr][ks*32 + fc];
            acc[0][0] = __builtin_amdgcn_mfma_f32_16x16x32_bf16(a0, b0, acc[0][0], 0, 0, 0);
            acc[0][1] = __builtin_amdgcn_mfma_f32_16x16x32_bf16(a0, b1, acc[0][1], 0, 0, 0);
            acc[1][0] = __builtin_amdgcn_mfma_f32_16x16x32_bf16(a1, b0, acc[1][0], 0, 0, 0);
            acc[1][1] = __builtin_amdgcn_mfma_f32_16x16x32_bf16(a1, b1, acc[1][1], 0, 0, 0);
        }
        __syncthreads();
    }
    int mrow = (lane >> 4) * 4;
    float lv[2][4];
    #pragma unroll
    for (int mi = 0; mi < 2; mi++) {
        int ibase = i0 + wr + mi*16 + mrow;
        float4 l4 = *(const float4*)&linv[(size_t)h*768 + ibase];
        lv[mi][0] = l4.x; lv[mi][1] = l4.y; lv[mi][2] = l4.z; lv[mi][3] = l4.w;
    }
    if (nd0 < 128) {
        #pragma unroll
        for (int mi = 0; mi < 2; mi++) {
            #pragma unroll
            for (int ni = 0; ni < 2; ni++) {
                int d = nd0 + wc + ni*16 + fr;
                #pragma unroll
                for (int rr = 0; rr < 4; rr++) {
                    int i = i0 + wr + mi*16 + mrow + rr;
                    concat[(size_t)i*CONCAT + h*128 + d] = f2bf(acc[mi][ni][rr] * lv[mi][rr]);
                }
            }
        }
    } else {
        float* opt_s = (float*)&As[0][0];
        #pragma unroll
        for (int mi = 0; mi < 2; mi++) {
            #pragma unroll
            for (int ni = 0; ni < 2; ni++) {
                int c = wc + ni*16 + fr;
                if (c < 36) {
                    #pragma unroll
                    for (int rr = 0; rr < 4; rr++) {
                        int rl = wr + mi*16 + mrow + rr;
                        opt_s[rl*36 + c] = acc[mi][ni][rr] * lv[mi][rr];
                    }
                }
            }
        }
        __syncthreads();
        for (int it = tid; it < 768; it += 256) {
            int rl = it / 12, pp = it % 12;
            int i = i0 + rl;
            const float* R = rot + i*9;
            const float* T = trans + i*3;
            float y0 = opt_s[rl*36 + pp*3 + 0] - T[0];
            float y1 = opt_s[rl*36 + pp*3 + 1] - T[1];
            float y2 = opt_s[rl*36 + pp*3 + 2] - T[2];
            float o0 = R[0]*y0 + R[3]*y1 + R[6]*y2;
            float o1 = R[1]*y0 + R[4]*y1 + R[7]*y2;
            float o2 = R[2]*y0 + R[5]*y1 + R[8]*y2;
            float nrm = sqrtf(o0*o0 + o1*o1 + o2*o2 + 1e-8f);
            int hp = h*12 + pp;
            unsigned short* cb = concat + (size_t)i*CONCAT;
            cb[1024 +   0 + hp] = f2bf(o0);
            cb[1024 +  96 + hp] = f2bf(o1);
            cb[1024 + 192 + hp] = f2bf(o2);
            cb[1312 + hp] = f2bf(nrm);
        }
    }
}

// ---------------------------------------------------------------------------
// tail: LN1 + transition MLP (3 MFMA stages) + LN2 + upd + frame, row-local.
// 32 rows per block, 24 blocks.
// ---------------------------------------------------------------------------
__global__ __launch_bounds__(256) void tail_kernel(
    const float* __restrict__ s, const float* __restrict__ ipa,
    const float* __restrict__ bo,
    const float* __restrict__ g1, const float* __restrict__ be1,
    const unsigned short* __restrict__ Wt1, const float* __restrict__ bt1,
    const unsigned short* __restrict__ Wt2, const float* __restrict__ bt2,
    const unsigned short* __restrict__ Wt3, const float* __restrict__ bt3,
    const float* __restrict__ g2, const float* __restrict__ be2,
    const float* __restrict__ Wbb, const float* __restrict__ bbb,
    const float* __restrict__ mask,
    const float* __restrict__ rot, const float* __restrict__ trans,
    float* __restrict__ out, float* __restrict__ rot_out, float* __restrict__ trans_out)
{
    __shared__ float s1f[32][257];
    __shared__ unsigned short Ab[32][264];
    __shared__ float upd_s[32][6];
    int i0 = blockIdx.x * 32;
    int tid = threadIdx.x, lane = tid & 63, wid = tid >> 6;
    int fr = lane & 15, fc = (lane >> 4) * 8, mrow = (lane >> 4) * 4;

    // ---- LN1: x = s + ipa + bo ----
    int r = tid >> 3, cg = (tid & 7) * 32;
    {
        float xv[32];
        float sum = 0.f, sq = 0.f;
        #pragma unroll
        for (int q = 0; q < 8; q++) {
            float4 a = *(const float4*)&s[(size_t)(i0 + r)*256 + cg + q*4];
            float4 b = *(const float4*)&ipa[(size_t)(i0 + r)*256 + cg + q*4];
            float4 c = *(const float4*)&bo[cg + q*4];
            float v0 = a.x + b.x + c.x, v1 = a.y + b.y + c.y;
            float v2 = a.z + b.z + c.z, v3 = a.w + b.w + c.w;
            xv[q*4+0] = v0; xv[q*4+1] = v1; xv[q*4+2] = v2; xv[q*4+3] = v3;
            sum += v0 + v1 + v2 + v3;
            sq  += v0*v0 + v1*v1 + v2*v2 + v3*v3;
        }
        #pragma unroll
        for (int d = 1; d < 8; d <<= 1) { sum += __shfl_xor(sum, d); sq += __shfl_xor(sq, d); }
        float mu = sum * (1.0f/256.0f);
        float var = sq * (1.0f/256.0f) - mu*mu;
        float rsig = 1.0f / sqrtf(var + 1e-5f);
        #pragma unroll
        for (int c = 0; c < 32; c++) {
            float o = (xv[c] - mu) * rsig * g1[cg + c] + be1[cg + c];
            s1f[r][cg + c] = o;
            Ab[r][cg + c] = f2bf(o);
        }
    }
    __syncthreads();

    // ---- 3 GEMM stages ----
    const unsigned short* Ws[3] = {Wt1, Wt2, Wt3};
    const float* Bs[3] = {bt1, bt2, bt3};
    #pragma unroll
    for (int stage = 0; stage < 3; stage++) {
        const unsigned short* W = Ws[stage];
        const float* bias = Bs[stage];
        v4f acc[2][4] = {};
        #pragma unroll
        for (int k0 = 0; k0 < 8; k0++) {
            v8bf a0 = *(const v8bf*)&Ab[fr][k0*32 + fc];
            v8bf a1 = *(const v8bf*)&Ab[16 + fr][k0*32 + fc];
            #pragma unroll
            for (int n = 0; n < 4; n++) {
                int d = wid*64 + n*16 + fr;
                v8bf b = *(const v8bf*)&W[(size_t)d*256 + k0*32 + fc];
                acc[0][n] = __builtin_amdgcn_mfma_f32_16x16x32_bf16(a0, b, acc[0][n], 0, 0, 0);
                acc[1][n] = __builtin_amdgcn_mfma_f32_16x16x32_bf16(a1, b, acc[1][n], 0, 0, 0);
            }
        }
        __syncthreads();
        if (stage < 2) {
            #pragma unroll
            for (int mi = 0; mi < 2; mi++) {
                #pragma unroll
                for (int n = 0; n < 4; n++) {
                    int d = wid*64 + n*16 + fr;
                    #pragma unroll
                    for (int rr = 0; rr < 4; rr++) {
                        int m = mi*16 + mrow + rr;
                        Ab[m][d] = f2bf(fmaxf(acc[mi][n][rr] + bias[d], 0.f));
                    }
                }
            }
        } else {
            #pragma unroll
            for (int mi = 0; mi < 2; mi++) {
                #pragma unroll
                for (int n = 0; n < 4; n++) {
                    int d = wid*64 + n*16 + fr;
                    #pragma unroll
                    for (int rr = 0; rr < 4; rr++) {
                        int m = mi*16 + mrow + rr;
                        s1f[m][d] += acc[mi][n][rr] + bias[d];
                    }
                }
            }
        }
        __syncthreads();
    }

    // ---- LN2 over s1f (now s1 + y3); write out + keep s2 in s1f ----
    {
        float xv[32];
        float sum = 0.f, sq = 0.f;
        #pragma unroll
        for (int c = 0; c < 32; c++) {
            float v = s1f[r][cg + c];
            xv[c] = v; sum += v; sq += v*v;
        }
        #pragma unroll
        for (int d = 1; d < 8; d <<= 1) { sum += __shfl_xor(sum, d); sq += __shfl_xor(sq, d); }
        float mu = sum * (1.0f/256.0f);
        float var = sq * (1.0f/256.0f) - mu*mu;
        float rsig = 1.0f / sqrtf(var + 1e-5f);
        float o4[32];
        #pragma unroll
        for (int c = 0; c < 32; c++)
            o4[c] = (xv[c] - mu) * rsig * g2[cg + c] + be2[cg + c];
        #pragma unroll
        for (int q = 0; q < 8; q++) {
            float4 w; w.x = o4[q*4]; w.y = o4[q*4+1]; w.z = o4[q*4+2]; w.w = o4[q*4+3];
            *(float4*)&out[(size_t)(i0 + r)*256 + cg + q*4] = w;
        }
        __syncthreads();
        #pragma unroll
        for (int c = 0; c < 32; c++) s1f[r][cg + c] = o4[c];
    }
    __syncthreads();

    // ---- upd = (s2 @ Wbb^T + bbb) * mask ----
    if (tid < 192) {
        int rr = tid / 6, d = tid % 6;
        float acc = bbb[d];
        const float* wb = Wbb + d*256;
        #pragma unroll 8
        for (int c = 0; c < 256; c++) acc += s1f[rr][c] * wb[c];
        upd_s[rr][d] = acc * mask[i0 + rr];
    }
    __syncthreads();

    // ---- frame composition ----
    if (tid < 32) {
        int i = i0 + tid;
        float u0 = upd_s[tid][0], u1 = upd_s[tid][1], u2 = upd_s[tid][2];
        float t0 = upd_s[tid][3], t1 = upd_s[tid][4], t2 = upd_s[tid][5];
        float n = sqrtf(1.f + u0*u0 + u1*u1 + u2*u2);
        float w = 1.f/n, x = u0/n, y = u1/n, z = u2/n;
        float R[3][3];
        R[0][0] = 1.f - 2.f*(y*y + z*z); R[0][1] = 2.f*(x*y - w*z);       R[0][2] = 2.f*(x*z + w*y);
        R[1][0] = 2.f*(x*y + w*z);       R[1][1] = 1.f - 2.f*(x*x + z*z); R[1][2] = 2.f*(y*z - w*x);
        R[2][0] = 2.f*(x*z - w*y);       R[2][1] = 2.f*(y*z + w*x);       R[2][2] = 1.f - 2.f*(x*x + y*y);
        const float* Ri = rot + i*9;
        #pragma unroll
        for (int a = 0; a < 3; a++) {
            #pragma unroll
            for (int b = 0; b < 3; b++) {
                float acc = 0.f;
                #pragma unroll
                for (int j = 0; j < 3; j++) acc += Ri[a*3+j]*R[j][b];
                rot_out[i*9 + a*3 + b] = acc;
            }
            trans_out[i*3 + a] = trans[i*3 + a] + Ri[a*3+0]*t0 + Ri[a*3+1]*t1 + Ri[a*3+2]*t2;
        }
    }
}

// ---------------------------------------------------------------------------
extern "C" void kernel_launch(void* const* d_in, const int* in_sizes, int n_in,
                              void* d_out, int out_size, void* d_ws, size_t ws_size,
                              hipStream_t stream)
{
    const float* s      = (const float*)d_in[0];
    const float* p      = (const float*)d_in[1];
    const float* rot    = (const float*)d_in[2];
    const float* trans  = (const float*)d_in[3];
    const float* mask   = (const float*)d_in[4];
    const float* Wq     = (const float*)d_in[5];
    const float* bq     = (const float*)d_in[6];
    const float* Wkv    = (const float*)d_in[7];
    const float* bkv    = (const float*)d_in[8];
    const float* Wqp    = (const float*)d_in[9];
    const float* bqp    = (const float*)d_in[10];
    const float* Wkvp   = (const float*)d_in[11];
    const float* bkvp   = (const float*)d_in[12];
    const float* Wpb    = (const float*)d_in[13];
    const float* bpb    = (const float*)d_in[14];
    const float* Wo     = (const float*)d_in[15];
    const float* bo     = (const float*)d_in[16];
    const float* Wt1    = (const float*)d_in[17];
    const float* bt1    = (const float*)d_in[18];
    const float* Wt2    = (const float*)d_in[19];
    const float* bt2    = (const float*)d_in[20];
    const float* Wt3    = (const float*)d_in[21];
    const float* bt3    = (const float*)d_in[22];
    const float* Wbb    = (const float*)d_in[23];
    const float* bbb    = (const float*)d_in[24];
    const float* head_w = (const float*)d_in[25];
    const float* g1     = (const float*)d_in[26];
    const float* be1    = (const float*)d_in[27];
    const float* g2     = (const float*)d_in[28];
    const float* be2    = (const float*)d_in[29];

    float* out = (float*)d_out;
    char*  wsb = (char*)d_ws;

    size_t off = 0;
    auto alloc = [&](size_t bytes) -> char* {
        char* ptr = wsb + off;
        off += (bytes + 255) & ~(size_t)255;
        return ptr;
    };
    float* qpraw   = (float*)alloc((size_t)NN*192*4);
    float* kvpraw  = (float*)alloc((size_t)NN*480*4);
    float* att     = (float*)alloc((size_t)8*768*768*4);
    float* ipa     = (float*)alloc((size_t)NN*256*4);
    float* linv    = (float*)alloc((size_t)8*768*4);
    float* lpart   = (float*)alloc((size_t)16*768*4);
    float* opart   = (float*)alloc((size_t)2*768*1024*4);
    unsigned* m0enc = (unsigned*)alloc((size_t)8*768*4);
    unsigned short* s_bf    = (unsigned short*)alloc((size_t)NN*256*2);
    unsigned short* Wq_bf   = (unsigned short*)alloc((size_t)1024*256*2);
    unsigned short* Wkv_bf  = (unsigned short*)alloc((size_t)2048*256*2);
    unsigned short* Wqp_bf  = (unsigned short*)alloc((size_t)192*256*2);
    unsigned short* Wkvp_bf = (unsigned short*)alloc((size_t)480*256*2);
    unsigned short* Wo_bf   = (unsigned short*)alloc((size_t)256*2432*2);
    unsigned short* Wt1_bf  = (unsigned short*)alloc((size_t)256*256*2);
    unsigned short* Wt2_bf  = (unsigned short*)alloc((size_t)256*256*2);
    unsigned short* Wt3_bf  = (unsigned short*)alloc((size_t)256*256*2);
    unsigned short* q_bf    = (unsigned short*)alloc((size_t)NN*1024*2);
    unsigned short* kv_bf   = (unsigned short*)alloc((size_t)NN*2048*2);
    unsigned short* qph     = (unsigned short*)alloc((size_t)NN*256*2);
    unsigned short* qpl     = (unsigned short*)alloc((size_t)NN*256*2);
    unsigned short* kph     = (unsigned short*)alloc((size_t)NN*256*2);
    unsigned short* kpl     = (unsigned short*)alloc((size_t)NN*256*2);
    unsigned short* Vc      = (unsigned short*)alloc((size_t)8*192*768*2);
    unsigned short* att_bf  = (unsigned short*)alloc((size_t)8*768*768*2);
    unsigned short* concat  = (unsigned short*)alloc((size_t)NN*CONCAT*2);

    // 0) zero-init atomic targets
    hipMemsetAsync(ipa, 0, (size_t)NN*256*4, stream);
    hipMemsetAsync(m0enc, 0, (size_t)8*768*4, stream);

    // 1) f32->bf16 conversions
    CvtDesc cd;
    const float* csrc[NCVT]    = {s, Wq, Wkv, Wqp, Wkvp, Wo, Wt1, Wt2, Wt3};
    unsigned short* cdst[NCVT] = {s_bf, Wq_bf, Wkv_bf, Wqp_bf, Wkvp_bf, Wo_bf, Wt1_bf, Wt2_bf, Wt3_bf};
    int csz[NCVT] = {NN*256, 1024*256, 2048*256, 192*256, 480*256, 256*2432, 256*256, 256*256, 256*256};
    int cum = 0;
    for (int i2 = 0; i2 < NCVT; i2++) {
        cd.src[i2] = csrc[i2]; cd.dst[i2] = cdst[i2]; cd.nelem[i2] = csz[i2];
        cd.blk_start[i2] = cum;
        cum += (csz[i2] + 2047) / 2048;
    }
    cd.blk_start[NCVT] = cum;
    cvt_many<<<cum, 256, 0, stream>>>(cd);

    // 2) All projections in one GEMM launch
    ProjDesc pd;
    pd.W[0] = Wq_bf;   pd.bias[0] = bq;   pd.dstb[0] = q_bf;   pd.dstf[0] = nullptr; pd.D[0] = 1024; pd.ldc[0] = 1024; pd.mode[0] = 2;
    pd.W[1] = Wkv_bf;  pd.bias[1] = bkv;  pd.dstb[1] = kv_bf;  pd.dstf[1] = nullptr; pd.D[1] = 2048; pd.ldc[1] = 2048; pd.mode[1] = 2;
    pd.W[2] = Wqp_bf;  pd.bias[2] = bqp;  pd.dstb[2] = nullptr; pd.dstf[2] = qpraw;  pd.D[2] = 192;  pd.ldc[2] = 192;  pd.mode[2] = 0;
    pd.W[3] = Wkvp_bf; pd.bias[3] = bkvp; pd.dstb[3] = nullptr; pd.dstf[3] = kvpraw; pd.D[3] = 480;  pd.ldc[3] = 480;  pd.mode[3] = 0;
    pd.blk_start[0] = 0; pd.blk_start[1] = 16; pd.blk_start[2] = 48; pd.blk_start[3] = 51; pd.blk_start[4] = 59;
    proj_all<<<dim3(59, 12), 256, 0, stream>>>(s_bf, pd);

    // 3) rotate + vtrans merged
    prep2_kernel<<<672 + 192, 256, 0, stream>>>(
        qpraw, kvpraw, rot, trans, kv_bf, qph, qpl, kph, kpl, Vc);

    // 4) logits (+row max via atomicMax)
    logits_mfma<<<dim3(12, 12, 8), 256, 0, stream>>>(
        q_bf, kv_bf, qph, qpl, kph, kpl, mask, head_w, att, m0enc);

    // 5) single-pass p kernel, split over 2 j-halves
    fused_p3s_kernel<<<dim3(768, 2), 256, 0, stream>>>(
        att, p, Wpb, bpb, m0enc, att_bf, lpart, opart);
    preduce_kernel<<<768, 256, 0, stream>>>(lpart, opart, linv, concat);

    // 6) o / opt (+final epilogue)
    attvc_mfma<<<dim3(3, 12, 8), 256, 0, stream>>>(att_bf, Vc, linv, rot, trans, concat);

    // 7) Output projection (split-K into zeroed ipa)
    mfma_gemm<4,0,0><<<dim3(4,12,4), 256, 0, stream>>>(concat, Wo_bf, nullptr, ipa, nullptr, 256, 2432, 256);

    // 8) fused tail: LN1 + MLP + LN2 + upd + frame
    tail_kernel<<<24, 256, 0, stream>>>(
        s, ipa, bo, g1, be1, Wt1_bf, bt1, Wt2_bf, bt2, Wt3_bf, bt3,
        g2, be2, Wbb, bbb, mask, rot, trans,
        out, out + (size_t)NN*256, out + (size_t)NN*256 + (size_t)NN*9);
}

// Round 8
// 187.542 us; speedup vs baseline: 3.9857x; 1.0277x over previous
//
#include <hip/hip_runtime.h>
#include <hip/hip_bf16.h>
#include <math.h>

// Problem constants
#define NN 768
#define CS 256
#define CZ 128
#define CH 128
#define HH 8
#define PQK 8
#define PV 12
#define CONCAT 2432   // 1024 + 288 + 96 + 1024
#define ATT_HSTRIDE (768*768)

typedef __bf16 v8bf __attribute__((ext_vector_type(8)));
typedef __bf16 v4bf __attribute__((ext_vector_type(4)));
typedef float  v4f  __attribute__((ext_vector_type(4)));

__device__ inline unsigned short f2bf(float f) {
    union { float f; unsigned u; } v; v.f = f;
    unsigned r = v.u + 0x7FFFu + ((v.u >> 16) & 1u);
    return (unsigned short)(r >> 16);
}
__device__ inline float bf2f(unsigned short u) {
    union { unsigned u; float f; } v; v.u = ((unsigned)u) << 16; return v.f;
}
// order-preserving float<->uint encoding (for atomicMax on floats)
__device__ inline unsigned encf(float f) {
    unsigned u = __float_as_uint(f);
    return (u >> 31) ? ~u : (u | 0x80000000u);
}
__device__ inline float decf(unsigned e) {
    unsigned u = (e >> 31) ? (e & 0x7FFFFFFFu) : ~e;
    return __uint_as_float(u);
}

// ---------------------------------------------------------------------------
// Batched f32 -> bf16 conversion
// ---------------------------------------------------------------------------
#define NCVT 9
struct CvtDesc {
    const float* src[NCVT];
    unsigned short* dst[NCVT];
    int nelem[NCVT];
    int blk_start[NCVT + 1];
};

__global__ __launch_bounds__(256) void cvt_many(CvtDesc d)
{
    int b = blockIdx.x;
    int seg = 0;
    #pragma unroll
    for (int i = 0; i < NCVT - 1; i++) if (b >= d.blk_start[i + 1]) seg = i + 1;
    int local = b - d.blk_start[seg];
    int base = local * 2048 + threadIdx.x;
    const float* s = d.src[seg];
    unsigned short* o = d.dst[seg];
    int n = d.nelem[seg];
    #pragma unroll
    for (int r = 0; r < 8; r++) {
        int idx = base + r * 256;
        if (idx < n) o[idx] = f2bf(s[idx]);
    }
}

// ---------------------------------------------------------------------------
// Combined projection GEMM: 4 weight segments, shared A = s_bf, K=256.
// ---------------------------------------------------------------------------
struct ProjDesc {
    const unsigned short* W[4];
    const float* bias[4];
    unsigned short* dstb[4];
    float* dstf[4];
    int D[4];
    int ldc[4];
    int mode[4];
    int blk_start[5];
};

__global__ __launch_bounds__(256) void proj_all(const unsigned short* __restrict__ A, ProjDesc d)
{
    __shared__ unsigned short As[64][40];
    __shared__ unsigned short Ws[64][40];
    int bx = blockIdx.x;
    int seg = 0;
    #pragma unroll
    for (int q = 0; q < 3; q++) if (bx >= d.blk_start[q + 1]) seg = q + 1;
    int bd = (bx - d.blk_start[seg]) * 64;
    int bi = blockIdx.y * 64;
    const unsigned short* W = d.W[seg];
    int D = d.D[seg], ldc = d.ldc[seg];

    int tid = threadIdx.x, lane = tid & 63, wid = tid >> 6;
    int wr = (wid >> 1) * 32, wc = (wid & 1) * 32;
    v4f acc[2][2] = {};
    int lrow = tid >> 2, lcol = (tid & 3) * 8;
    const unsigned short* Ap = A + (size_t)(bi + lrow) * 256 + lcol;
    const unsigned short* Wp = W + (size_t)(bd + lrow) * 256 + lcol;
    bool wv = (bd + lrow) < D;
    int fr = lane & 15, fc = (lane >> 4) * 8;

    for (int k0 = 0; k0 < 256; k0 += 32) {
        *(int4*)&As[lrow][lcol] = *(const int4*)(Ap + k0);
        int4 wz = {0, 0, 0, 0};
        *(int4*)&Ws[lrow][lcol] = wv ? *(const int4*)(Wp + k0) : wz;
        __syncthreads();
        v8bf a0 = *(const v8bf*)&As[wr + fr][fc];
        v8bf a1 = *(const v8bf*)&As[wr + 16 + fr][fc];
        v8bf b0 = *(const v8bf*)&Ws[wc + fr][fc];
        v8bf b1 = *(const v8bf*)&Ws[wc + 16 + fr][fc];
        acc[0][0] = __builtin_amdgcn_mfma_f32_16x16x32_bf16(a0, b0, acc[0][0], 0, 0, 0);
        acc[0][1] = __builtin_amdgcn_mfma_f32_16x16x32_bf16(a0, b1, acc[0][1], 0, 0, 0);
        acc[1][0] = __builtin_amdgcn_mfma_f32_16x16x32_bf16(a1, b0, acc[1][0], 0, 0, 0);
        acc[1][1] = __builtin_amdgcn_mfma_f32_16x16x32_bf16(a1, b1, acc[1][1], 0, 0, 0);
        __syncthreads();
    }
    const float* bias = d.bias[seg];
    int mode = d.mode[seg];
    unsigned short* Cb = d.dstb[seg];
    float* Cf = d.dstf[seg];
    int mrow = (lane >> 4) * 4;
    #pragma unroll
    for (int mi = 0; mi < 2; mi++) {
        #pragma unroll
        for (int ni = 0; ni < 2; ni++) {
            int dd = bd + wc + ni * 16 + fr;
            if (dd < D) {
                #pragma unroll
                for (int r = 0; r < 4; r++) {
                    int m = bi + wr + mi * 16 + mrow + r;
                    float v = acc[mi][ni][r] + bias[dd];
                    if (mode == 2) Cb[(size_t)m * ldc + dd] = f2bf(v);
                    else           Cf[(size_t)m * ldc + dd] = v;
                }
            }
        }
    }
}

// ---------------------------------------------------------------------------
// Generic MFMA bf16 GEMM (used for Wo split-K)
// ---------------------------------------------------------------------------
template<int SPLITK, int MODE, int RELU>
__global__ __launch_bounds__(256) void mfma_gemm(
    const unsigned short* __restrict__ A,
    const unsigned short* __restrict__ W,
    const float* __restrict__ bias,
    float* __restrict__ C,
    unsigned short* __restrict__ Cb,
    int D, int K, int ldc)
{
    __shared__ unsigned short As[64][40];
    __shared__ unsigned short Ws[64][40];
    int tid = threadIdx.x;
    int bi = blockIdx.y * 64;
    int bd = blockIdx.x * 64;
    int kpb = K / SPLITK;
    int k0b = blockIdx.z * kpb;
    int lane = tid & 63;
    int wid = tid >> 6;
    int wr = (wid >> 1) * 32, wc = (wid & 1) * 32;
    v4f acc[2][2] = {};
    int lrow = tid >> 2;
    int lcol = (tid & 3) * 8;
    const unsigned short* Ap = A + (size_t)(bi + lrow) * K + lcol;
    const unsigned short* Wp = W + (size_t)(bd + lrow) * K + lcol;
    bool wv = (bd + lrow) < D;
    int fr = lane & 15, fc = (lane >> 4) * 8;

    for (int k0 = k0b; k0 < k0b + kpb; k0 += 32) {
        *(int4*)&As[lrow][lcol] = *(const int4*)(Ap + k0);
        int4 wz = {0, 0, 0, 0};
        *(int4*)&Ws[lrow][lcol] = wv ? *(const int4*)(Wp + k0) : wz;
        __syncthreads();
        v8bf a0 = *(const v8bf*)&As[wr + fr][fc];
        v8bf a1 = *(const v8bf*)&As[wr + 16 + fr][fc];
        v8bf b0 = *(const v8bf*)&Ws[wc + fr][fc];
        v8bf b1 = *(const v8bf*)&Ws[wc + 16 + fr][fc];
        acc[0][0] = __builtin_amdgcn_mfma_f32_16x16x32_bf16(a0, b0, acc[0][0], 0, 0, 0);
        acc[0][1] = __builtin_amdgcn_mfma_f32_16x16x32_bf16(a0, b1, acc[0][1], 0, 0, 0);
        acc[1][0] = __builtin_amdgcn_mfma_f32_16x16x32_bf16(a1, b0, acc[1][0], 0, 0, 0);
        acc[1][1] = __builtin_amdgcn_mfma_f32_16x16x32_bf16(a1, b1, acc[1][1], 0, 0, 0);
        __syncthreads();
    }
    int mrow = (lane >> 4) * 4;
    #pragma unroll
    for (int mi = 0; mi < 2; mi++) {
        #pragma unroll
        for (int ni = 0; ni < 2; ni++) {
            int d = bd + wc + ni * 16 + fr;
            if (d < D) {
                #pragma unroll
                for (int r = 0; r < 4; r++) {
                    int m = bi + wr + mi * 16 + mrow + r;
                    float v = acc[mi][ni][r];
                    if (SPLITK > 1) {
                        atomicAdd(&C[(size_t)m * ldc + d], v);
                    } else {
                        v += bias[d];
                        if (RELU) v = fmaxf(v, 0.f);
                        if (MODE != 2) C[(size_t)m * ldc + d] = v;
                        if (MODE >= 1) Cb[(size_t)m * ldc + d] = f2bf(v);
                    }
                }
            }
        }
    }
}

// ---------------------------------------------------------------------------
// prep2: rotate points (blocks < 672) + V transpose (blocks >= 672)
// ---------------------------------------------------------------------------
__global__ __launch_bounds__(256) void prep2_kernel(
    const float* __restrict__ qpraw, const float* __restrict__ kvpraw,
    const float* __restrict__ rot, const float* __restrict__ trans,
    const unsigned short* __restrict__ kv_bf,
    unsigned short* __restrict__ qph, unsigned short* __restrict__ qpl,
    unsigned short* __restrict__ kph, unsigned short* __restrict__ kpl,
    unsigned short* __restrict__ Vc)
{
    __shared__ unsigned short tile[32][136];
    int bx = blockIdx.x;
    int t = threadIdx.x;
    if (bx < 672) {
        int id = bx*256 + t;
        int i = id / (HH*28);
        int rem = id % (HH*28);
        int h = rem / 28;
        int idx = rem % 28;
        const float* R = rot + i*9;
        const float* T = trans + i*3;
        float s0, s1, s2;
        if (idx < 8) {
            s0 = qpraw[i*192 +   0 + h*8 + idx];
            s1 = qpraw[i*192 +  64 + h*8 + idx];
            s2 = qpraw[i*192 + 128 + h*8 + idx];
        } else {
            int pp = idx - 8;
            s0 = kvpraw[i*480 +   0 + h*20 + pp];
            s1 = kvpraw[i*480 + 160 + h*20 + pp];
            s2 = kvpraw[i*480 + 320 + h*20 + pp];
        }
        float ov[3];
        ov[0] = R[0]*s0 + R[1]*s1 + R[2]*s2 + T[0];
        ov[1] = R[3]*s0 + R[4]*s1 + R[5]*s2 + T[1];
        ov[2] = R[6]*s0 + R[7]*s1 + R[8]*s2 + T[2];
        if (idx < 8) {
            #pragma unroll
            for (int x = 0; x < 3; x++) {
                unsigned short hi = f2bf(ov[x]);
                qph[i*256 + h*32 + idx*3 + x] = hi;
                qpl[i*256 + h*32 + idx*3 + x] = f2bf(ov[x] - bf2f(hi));
            }
            if (idx == 0) {
                #pragma unroll
                for (int m = 24; m < 32; m++) { qph[i*256+h*32+m] = 0; qpl[i*256+h*32+m] = 0; }
            }
        } else if (idx < 16) {
            int pp = idx - 8;
            #pragma unroll
            for (int x = 0; x < 3; x++) {
                unsigned short hi = f2bf(ov[x]);
                kph[i*256 + h*32 + pp*3 + x] = hi;
                kpl[i*256 + h*32 + pp*3 + x] = f2bf(ov[x] - bf2f(hi));
            }
            if (idx == 8) {
                #pragma unroll
                for (int m = 24; m < 32; m++) { kph[i*256+h*32+m] = 0; kpl[i*256+h*32+m] = 0; }
            }
        } else {
            int ppv = idx - 16;
            #pragma unroll
            for (int x = 0; x < 3; x++)
                Vc[((size_t)h*192 + 128 + ppv*3 + x)*768 + i] = f2bf(ov[x]);
        }
    } else {
        int bx2 = bx - 672;
        int h = bx2 & 7, jt = bx2 >> 3;
        int r = t >> 3, c0 = (t & 7) * 16;
        const unsigned short* src = kv_bf + (size_t)(jt*32 + r)*2048 + h*256 + 128 + c0;
        *(int4*)&tile[r][c0]     = *(const int4*)src;
        *(int4*)&tile[r][c0 + 8] = *(const int4*)(src + 8);
        __syncthreads();
        int c = t >> 1, jh = (t & 1) * 16;
        unsigned short tmp[16];
        #pragma unroll
        for (int k = 0; k < 16; k++) tmp[k] = tile[jh + k][c];
        unsigned short* dst = Vc + ((size_t)h*192 + c)*768 + jt*32 + jh;
        *(int4*)dst       = *(int4*)&tmp[0];
        *(int4*)(dst + 8) = *(int4*)&tmp[8];
    }
}

// ---------------------------------------------------------------------------
// Logits via MFMA. Point fragments loaded DIRECT from global (L2-resident),
// Qss/Kss computed in-register (shfl reduce). LDS = Qs+Ks+mask only
// (~36 KB -> 4 blocks/CU). Row max folded in via order-encoded atomicMax.
// ---------------------------------------------------------------------------
__global__ __launch_bounds__(256) void logits_mfma(
    const unsigned short* __restrict__ q_bf, const unsigned short* __restrict__ kv_bf,
    const unsigned short* __restrict__ qph, const unsigned short* __restrict__ qpl,
    const unsigned short* __restrict__ kph, const unsigned short* __restrict__ kpl,
    const float* __restrict__ mask, const float* __restrict__ head_w,
    float* __restrict__ att, unsigned* __restrict__ m0enc)
{
    __shared__ unsigned short Qs[64][136];
    __shared__ unsigned short Ks[64][136];
    __shared__ float Mi[64], Mj[64];
    int h = blockIdx.z;
    int i0 = blockIdx.y * 64, j0 = blockIdx.x * 64;
    int tid = threadIdx.x, lane = tid & 63, wid = tid >> 6;
    int wr = (wid >> 1) * 32, wc = (wid & 1) * 32;
    int r = tid >> 2, cq = (tid & 3) * 32;
    const unsigned short* qg = q_bf  + (size_t)(i0 + r)*1024 + h*128 + cq;
    const unsigned short* kg = kv_bf + (size_t)(j0 + r)*2048 + h*256 + cq;
    #pragma unroll
    for (int kk = 0; kk < 4; kk++) {
        *(int4*)&Qs[r][cq + kk*8] = *(const int4*)(qg + kk*8);
        *(int4*)&Ks[r][cq + kk*8] = *(const int4*)(kg + kk*8);
    }
    if (tid < 64) {
        Mi[tid] = mask[i0 + tid];
        Mj[tid] = mask[j0 + tid];
    }
    int fr = lane & 15, fc = (lane >> 4) * 8;
    // direct point-fragment loads (rows 64B-aligned; m=24..31 zeroed in prep2)
    v8bf ah0 = *(const v8bf*)&qph[(size_t)(i0 + wr + fr)*256 + h*32 + fc];
    v8bf ah1 = *(const v8bf*)&qph[(size_t)(i0 + wr + 16 + fr)*256 + h*32 + fc];
    v8bf al0 = *(const v8bf*)&qpl[(size_t)(i0 + wr + fr)*256 + h*32 + fc];
    v8bf al1 = *(const v8bf*)&qpl[(size_t)(i0 + wr + 16 + fr)*256 + h*32 + fc];
    v8bf bh0 = *(const v8bf*)&kph[(size_t)(j0 + wc + fr)*256 + h*32 + fc];
    v8bf bh1 = *(const v8bf*)&kph[(size_t)(j0 + wc + 16 + fr)*256 + h*32 + fc];
    v8bf bl0 = *(const v8bf*)&kpl[(size_t)(j0 + wc + fr)*256 + h*32 + fc];
    v8bf bl1 = *(const v8bf*)&kpl[(size_t)(j0 + wc + 16 + fr)*256 + h*32 + fc];
    // in-register point norms: row wr+fr (q2a), wr+16+fr (q2b); cols likewise
    float q2a = 0.f, q2b = 0.f, k2a = 0.f, k2b = 0.f;
    #pragma unroll
    for (int m = 0; m < 8; m++) {
        float va = (float)ah0[m] + (float)al0[m];
        float vb = (float)ah1[m] + (float)al1[m];
        float wa = (float)bh0[m] + (float)bl0[m];
        float wb = (float)bh1[m] + (float)bl1[m];
        q2a += va*va; q2b += vb*vb; k2a += wa*wa; k2b += wb*wb;
    }
    q2a += __shfl_xor(q2a, 16); q2a += __shfl_xor(q2a, 32);
    q2b += __shfl_xor(q2b, 16); q2b += __shfl_xor(q2b, 32);
    k2a += __shfl_xor(k2a, 16); k2a += __shfl_xor(k2a, 32);
    k2b += __shfl_xor(k2b, 16); k2b += __shfl_xor(k2b, 32);

    v4f ap[2][2] = {};
    ap[0][0] = __builtin_amdgcn_mfma_f32_16x16x32_bf16(ah0, bh0, ap[0][0], 0, 0, 0);
    ap[0][1] = __builtin_amdgcn_mfma_f32_16x16x32_bf16(ah0, bh1, ap[0][1], 0, 0, 0);
    ap[1][0] = __builtin_amdgcn_mfma_f32_16x16x32_bf16(ah1, bh0, ap[1][0], 0, 0, 0);
    ap[1][1] = __builtin_amdgcn_mfma_f32_16x16x32_bf16(ah1, bh1, ap[1][1], 0, 0, 0);
    ap[0][0] = __builtin_amdgcn_mfma_f32_16x16x32_bf16(ah0, bl0, ap[0][0], 0, 0, 0);
    ap[0][1] = __builtin_amdgcn_mfma_f32_16x16x32_bf16(ah0, bl1, ap[0][1], 0, 0, 0);
    ap[1][0] = __builtin_amdgcn_mfma_f32_16x16x32_bf16(ah1, bl0, ap[1][0], 0, 0, 0);
    ap[1][1] = __builtin_amdgcn_mfma_f32_16x16x32_bf16(ah1, bl1, ap[1][1], 0, 0, 0);
    ap[0][0] = __builtin_amdgcn_mfma_f32_16x16x32_bf16(al0, bh0, ap[0][0], 0, 0, 0);
    ap[0][1] = __builtin_amdgcn_mfma_f32_16x16x32_bf16(al0, bh1, ap[0][1], 0, 0, 0);
    ap[1][0] = __builtin_amdgcn_mfma_f32_16x16x32_bf16(al1, bh0, ap[1][0], 0, 0, 0);
    ap[1][1] = __builtin_amdgcn_mfma_f32_16x16x32_bf16(al1, bh1, ap[1][1], 0, 0, 0);

    __syncthreads();   // Qs/Ks staged
    v4f aqk[2][2] = {};
    #pragma unroll
    for (int ks = 0; ks < 4; ks++) {
        v8bf a0 = *(const v8bf*)&Qs[wr + fr][ks*32 + fc];
        v8bf a1 = *(const v8bf*)&Qs[wr + 16 + fr][ks*32 + fc];
        v8bf b0 = *(const v8bf*)&Ks[wc + fr][ks*32 + fc];
        v8bf b1 = *(const v8bf*)&Ks[wc + 16 + fr][ks*32 + fc];
        aqk[0][0] = __builtin_amdgcn_mfma_f32_16x16x32_bf16(a0, b0, aqk[0][0], 0, 0, 0);
        aqk[0][1] = __builtin_amdgcn_mfma_f32_16x16x32_bf16(a0, b1, aqk[0][1], 0, 0, 0);
        aqk[1][0] = __builtin_amdgcn_mfma_f32_16x16x32_bf16(a1, b0, aqk[1][0], 0, 0, 0);
        aqk[1][1] = __builtin_amdgcn_mfma_f32_16x16x32_bf16(a1, b1, aqk[1][1], 0, 0, 0);
    }
    float hx = head_w[h];
    float sp = (hx > 20.f) ? hx : log1pf(__expf(hx));
    float hw = sp * 0.09622504486493764f;
    const float scale_qk = 0.05103103630798288f;
    int mrow = (lane >> 4) * 4;
    float val[2][2][4];
    #pragma unroll
    for (int mi = 0; mi < 2; mi++) {
        #pragma unroll
        for (int rr = 0; rr < 4; rr++) {
            float qss = __shfl((mi == 0) ? q2a : q2b, mrow + rr);
            #pragma unroll
            for (int ni = 0; ni < 2; ni++) {
                int jl = wc + ni*16 + fr;
                int il = wr + mi*16 + mrow + rr;
                float kss = (ni == 0) ? k2a : k2b;
                float v = aqk[mi][ni][rr]*scale_qk + hw*ap[mi][ni][rr]
                        - 0.5f*hw*(qss + kss)
                        + 100000.0f*(Mi[il]*Mj[jl] - 1.0f);
                val[mi][ni][rr] = v;
                att[(size_t)h*ATT_HSTRIDE + (size_t)(i0 + il)*768 + (j0 + jl)] = v;
            }
        }
    }
    // per-row max over this block's 64 j, then atomicMax into m0enc
    #pragma unroll
    for (int mi = 0; mi < 2; mi++) {
        #pragma unroll
        for (int rr = 0; rr < 4; rr++) {
            float m = fmaxf(val[mi][0][rr], val[mi][1][rr]);
            #pragma unroll
            for (int d2 = 1; d2 < 16; d2 <<= 1) m = fmaxf(m, __shfl_xor(m, d2));
            if (fr == 0) {
                int il = wr + mi*16 + mrow + rr;
                atomicMax(&m0enc[h*768 + i0 + il], encf(m));
            }
        }
    }
}

// ---------------------------------------------------------------------------
// fused_p3s: half of the j-range per block; single pass over p; MFMA bias +
// MFMA opair (B-fragments from ptile columns). Double-buffered ptile ->
// 2 barriers/tile with stage/compute overlap.
// ---------------------------------------------------------------------------
__global__ __launch_bounds__(256) void fused_p3s_kernel(
    const float* __restrict__ att0,
    const float* __restrict__ p,
    const float* __restrict__ Wpb, const float* __restrict__ bpb,
    const unsigned* __restrict__ m0enc,
    unsigned short* __restrict__ att_bf,
    float* __restrict__ lpart,
    float* __restrict__ opart)
{
    __shared__ unsigned short ptile[2][64][132];
    __shared__ unsigned short wt[16][72];
    __shared__ float bpb_s[8], m8[8], lsum_w[4][8];

    int i = blockIdx.x;
    int half = blockIdx.y;
    int jbase = half * 384;
    int tid = threadIdx.x, lane = tid & 63, wid = tid >> 6;
    int fr = lane & 15, fc = (lane >> 4) * 8;
    int mrow = (lane >> 4) * 4;

    for (int idx = tid; idx < 16*72; idx += 256) ((unsigned short*)wt)[idx] = 0;
    if (tid < 8) {
        bpb_s[tid] = bpb[tid];
        m8[tid] = decf(m0enc[tid*768 + i]);
    }

    v8bf aW[4];
    #pragma unroll
    for (int ks = 0; ks < 4; ks++) {
        v8bf v = {};
        if (fr < 8) {
            const float* wp = Wpb + fr*128 + ks*32 + fc;
            float4 w0 = *(const float4*)wp;
            float4 w1 = *(const float4*)(wp + 4);
            v[0] = (__bf16)w0.x; v[1] = (__bf16)w0.y; v[2] = (__bf16)w0.z; v[3] = (__bf16)w0.w;
            v[4] = (__bf16)w1.x; v[5] = (__bf16)w1.y; v[6] = (__bf16)w1.z; v[7] = (__bf16)w1.w;
        }
        aW[ks] = v;
    }

    const float* pbase = p + (size_t)i*98304 + (size_t)jbase*128;
    int ldrow = tid >> 4, ldz = (tid & 15) * 8;   // each thread: rows ldrow+16k
    float4 pfA[4], pfB[4];
    // load tile 0 -> regs, stage -> buf0, load tile 1 -> regs
    #pragma unroll
    for (int r2 = 0; r2 < 4; r2++) {
        const float* src = pbase + (size_t)(r2*16 + ldrow)*128 + ldz;
        pfA[r2] = *(const float4*)src;
        pfB[r2] = *(const float4*)(src + 4);
    }
    #pragma unroll
    for (int r2 = 0; r2 < 4; r2++) {
        v4bf lo, hi;
        lo[0] = (__bf16)pfA[r2].x; lo[1] = (__bf16)pfA[r2].y;
        lo[2] = (__bf16)pfA[r2].z; lo[3] = (__bf16)pfA[r2].w;
        hi[0] = (__bf16)pfB[r2].x; hi[1] = (__bf16)pfB[r2].y;
        hi[2] = (__bf16)pfB[r2].z; hi[3] = (__bf16)pfB[r2].w;
        *(v4bf*)&ptile[0][r2*16 + ldrow][ldz]     = lo;
        *(v4bf*)&ptile[0][r2*16 + ldrow][ldz + 4] = hi;
    }
    #pragma unroll
    for (int r2 = 0; r2 < 4; r2++) {
        const float* src = pbase + (size_t)(64 + r2*16 + ldrow)*128 + ldz;
        pfA[r2] = *(const float4*)src;
        pfB[r2] = *(const float4*)(src + 4);
    }
    __syncthreads();
    float m0l[4];
    #pragma unroll
    for (int r2 = 0; r2 < 4; r2++) m0l[r2] = (mrow == 0) ? m8[r2] : m8[4 + r2];

    v4f accD[2] = {};
    float lacc[4] = {0.f, 0.f, 0.f, 0.f};
    const float sqrt13 = 0.57735026918962576f;
    bool expo = (mrow < 8);

    for (int t64 = 0; t64 < 6; t64++) {
        int cur = t64 & 1;
        int j0 = jbase + t64 * 64;

        // bias mfma on ptile[cur]
        v4f bd = {};
        #pragma unroll
        for (int ks = 0; ks < 4; ks++) {
            int c = ks*32 + fc;
            v4bf blo = *(const v4bf*)&ptile[cur][16*wid + fr][c];
            v4bf bhi = *(const v4bf*)&ptile[cur][16*wid + fr][c + 4];
            v8bf b;
            b[0]=blo[0]; b[1]=blo[1]; b[2]=blo[2]; b[3]=blo[3];
            b[4]=bhi[0]; b[5]=bhi[1]; b[6]=bhi[2]; b[7]=bhi[3];
            bd = __builtin_amdgcn_mfma_f32_16x16x32_bf16(aW[ks], b, bd, 0, 0, 0);
        }
        // exp + wt + att_bf + row-sum
        if (expo) {
            int j = 16*wid + fr;
            float a0v[4], w8[4];
            #pragma unroll
            for (int r2 = 0; r2 < 4; r2++)
                a0v[r2] = att0[((size_t)(mrow + r2)*768 + i)*768 + j0 + j];
            #pragma unroll
            for (int r2 = 0; r2 < 4; r2++) {
                int h = mrow + r2;
                float L = a0v[r2] + sqrt13*(bd[r2] + bpb_s[h]);
                w8[r2] = __expf(fminf(L - m0l[r2], 60.f));
            }
            #pragma unroll
            for (int r2 = 0; r2 < 4; r2++) {
                int h = mrow + r2;
                unsigned short wb = f2bf(w8[r2]);
                wt[h][j] = wb;
                att_bf[((size_t)h*768 + i)*768 + j0 + j] = wb;
            }
            #pragma unroll
            for (int m = 1; m < 16; m <<= 1) {
                #pragma unroll
                for (int r2 = 0; r2 < 4; r2++) w8[r2] += __shfl_xor(w8[r2], m);
            }
            #pragma unroll
            for (int r2 = 0; r2 < 4; r2++) lacc[r2] += w8[r2];
        }
        // stage regs (tile t64+1) -> other buffer; issue loads for t64+2
        if (t64 < 5) {
            #pragma unroll
            for (int r2 = 0; r2 < 4; r2++) {
                v4bf lo, hi;
                lo[0] = (__bf16)pfA[r2].x; lo[1] = (__bf16)pfA[r2].y;
                lo[2] = (__bf16)pfA[r2].z; lo[3] = (__bf16)pfA[r2].w;
                hi[0] = (__bf16)pfB[r2].x; hi[1] = (__bf16)pfB[r2].y;
                hi[2] = (__bf16)pfB[r2].z; hi[3] = (__bf16)pfB[r2].w;
                *(v4bf*)&ptile[cur ^ 1][r2*16 + ldrow][ldz]     = lo;
                *(v4bf*)&ptile[cur ^ 1][r2*16 + ldrow][ldz + 4] = hi;
            }
            if (t64 < 4) {
                #pragma unroll
                for (int r2 = 0; r2 < 4; r2++) {
                    const float* src = pbase + (size_t)((t64+2)*64 + r2*16 + ldrow)*128 + ldz;
                    pfA[r2] = *(const float4*)src;
                    pfB[r2] = *(const float4*)(src + 4);
                }
            }
        }
        __syncthreads();   // wt visible; next buffer staged

        // opair mfma: D[h][z], A = wt rows, B = ptile[cur] columns
        #pragma unroll
        for (int mm = 0; mm < 2; mm++) {
            int zcol = (2*wid + mm)*16 + fr;
            #pragma unroll
            for (int ks = 0; ks < 2; ks++) {
                v8bf b;
                #pragma unroll
                for (int kk = 0; kk < 8; kk++)
                    b[kk] = *(const __bf16*)&ptile[cur][ks*32 + fc + kk][zcol];
                v8bf a = *(const v8bf*)&wt[fr][ks*32 + fc];
                accD[mm] = __builtin_amdgcn_mfma_f32_16x16x32_bf16(a, b, accD[mm], 0, 0, 0);
            }
        }
        __syncthreads();   // protect wt + ptile[cur] for next iteration
    }

    if (fr == 0 && expo) {
        #pragma unroll
        for (int r2 = 0; r2 < 4; r2++) lsum_w[wid][mrow + r2] = lacc[r2];
    }
    __syncthreads();
    if (tid < 8) {
        lpart[(size_t)(half*8 + tid)*768 + i] =
            lsum_w[0][tid] + lsum_w[1][tid] + lsum_w[2][tid] + lsum_w[3][tid];
    }
    if (expo) {
        float* ob = opart + (size_t)(half*768 + i)*1024;
        #pragma unroll
        for (int mm = 0; mm < 2; mm++) {
            int z = (2*wid + mm)*16 + fr;
            #pragma unroll
            for (int r2 = 0; r2 < 4; r2++)
                ob[(mrow + r2)*128 + z] = accD[mm][r2];
        }
    }
}

// ---------------------------------------------------------------------------
// preduce: sum the two j-half partials -> linv + opair into concat
// ---------------------------------------------------------------------------
__global__ __launch_bounds__(256) void preduce_kernel(
    const float* __restrict__ lpart, const float* __restrict__ opart,
    float* __restrict__ linv, unsigned short* __restrict__ concat)
{
    __shared__ float inv_s[8];
    int i = blockIdx.x, t = threadIdx.x;
    if (t < 8) {
        float l = lpart[(size_t)t*768 + i] + lpart[(size_t)(8 + t)*768 + i];
        float iv = 1.0f / l;
        inv_s[t] = iv;
        linv[(size_t)t*768 + i] = iv;
    }
    __syncthreads();
    const float* o0 = opart + (size_t)i*1024;
    const float* o1 = opart + (size_t)(768 + i)*1024;
    #pragma unroll
    for (int k = 0; k < 4; k++) {
        int c = t + k*256;
        float s = o0[c] + o1[c];
        concat[(size_t)i*CONCAT + 1408 + c] = f2bf(s * inv_s[c >> 7]);
    }
}

// ---------------------------------------------------------------------------
// Fused (o | opt) = (att_unnorm @ Vc^T) * linv per h; opt blocks also do
// rot^T/trans/norm epilogue.
// ---------------------------------------------------------------------------
__global__ __launch_bounds__(256) void attvc_mfma(
    const unsigned short* __restrict__ att_bf, const unsigned short* __restrict__ Vc,
    const float* __restrict__ linv, const float* __restrict__ rot,
    const float* __restrict__ trans, unsigned short* __restrict__ concat)
{
    __shared__ unsigned short As[64][72];
    __shared__ unsigned short Bs[64][72];
    int h = blockIdx.z;
    int i0 = blockIdx.y * 64, nd0 = blockIdx.x * 64;
    int tid = threadIdx.x, lane = tid & 63, wid = tid >> 6;
    int wr = (wid >> 1) * 32, wc = (wid & 1) * 32;
    int r = tid >> 2, c8 = (tid & 3) * 16;
    int fr = lane & 15, fc = (lane >> 4) * 8;
    v4f acc[2][2] = {};
    for (int k0 = 0; k0 < 768; k0 += 64) {
        const unsigned short* ag = att_bf + ((size_t)h*768 + i0 + r)*768 + k0 + c8;
        const unsigned short* bg = Vc + ((size_t)h*192 + nd0 + r)*768 + k0 + c8;
        *(int4*)&As[r][c8]     = *(const int4*)ag;
        *(int4*)&As[r][c8 + 8] = *(const int4*)(ag + 8);
        *(int4*)&Bs[r][c8]     = *(const int4*)bg;
        *(int4*)&Bs[r][c8 + 8] = *(const int4*)(bg + 8);
        __syncthreads();
        #pragma unroll
        for (int ks = 0; ks < 2; ks++) {
            v8bf a0 = *(const v8bf*)&As[wr + fr][ks*32 + fc];
            v8bf a1 = *(const v8bf*)&As[wr + 16 + fr][ks*32 + fc];
            v8bf b0 = *(const v8bf*)&Bs[wc + fr][ks*32 + fc];
            v8bf b1 = *(const v8bf*)&Bs[wc + 16 + fr][ks*32 + fc];
            acc[0][0] = __builtin_amdgcn_mfma_f32_16x16x32_bf16(a0, b0, acc[0][0], 0, 0, 0);
            acc[0][1] = __builtin_amdgcn_mfma_f32_16x16x32_bf16(a0, b1, acc[0][1], 0, 0, 0);
            acc[1][0] = __builtin_amdgcn_mfma_f32_16x16x32_bf16(a1, b0, acc[1][0], 0, 0, 0);
            acc[1][1] = __builtin_amdgcn_mfma_f32_16x16x32_bf16(a1, b1, acc[1][1], 0, 0, 0);
        }
        __syncthreads();
    }
    int mrow = (lane >> 4) * 4;
    float lv[2][4];
    #pragma unroll
    for (int mi = 0; mi < 2; mi++) {
        int ibase = i0 + wr + mi*16 + mrow;
        float4 l4 = *(const float4*)&linv[(size_t)h*768 + ibase];
        lv[mi][0] = l4.x; lv[mi][1] = l4.y; lv[mi][2] = l4.z; lv[mi][3] = l4.w;
    }
    if (nd0 < 128) {
        #pragma unroll
        for (int mi = 0; mi < 2; mi++) {
            #pragma unroll
            for (int ni = 0; ni < 2; ni++) {
                int d = nd0 + wc + ni*16 + fr;
                #pragma unroll
                for (int rr = 0; rr < 4; rr++) {
                    int i = i0 + wr + mi*16 + mrow + rr;
                    concat[(size_t)i*CONCAT + h*128 + d] = f2bf(acc[mi][ni][rr] * lv[mi][rr]);
                }
            }
        }
    } else {
        float* opt_s = (float*)&As[0][0];
        #pragma unroll
        for (int mi = 0; mi < 2; mi++) {
            #pragma unroll
            for (int ni = 0; ni < 2; ni++) {
                int c = wc + ni*16 + fr;
                if (c < 36) {
                    #pragma unroll
                    for (int rr = 0; rr < 4; rr++) {
                        int rl = wr + mi*16 + mrow + rr;
                        opt_s[rl*36 + c] = acc[mi][ni][rr] * lv[mi][rr];
                    }
                }
            }
        }
        __syncthreads();
        for (int it = tid; it < 768; it += 256) {
            int rl = it / 12, pp = it % 12;
            int i = i0 + rl;
            const float* R = rot + i*9;
            const float* T = trans + i*3;
            float y0 = opt_s[rl*36 + pp*3 + 0] - T[0];
            float y1 = opt_s[rl*36 + pp*3 + 1] - T[1];
            float y2 = opt_s[rl*36 + pp*3 + 2] - T[2];
            float o0 = R[0]*y0 + R[3]*y1 + R[6]*y2;
            float o1 = R[1]*y0 + R[4]*y1 + R[7]*y2;
            float o2 = R[2]*y0 + R[5]*y1 + R[8]*y2;
            float nrm = sqrtf(o0*o0 + o1*o1 + o2*o2 + 1e-8f);
            int hp = h*12 + pp;
            unsigned short* cb = concat + (size_t)i*CONCAT;
            cb[1024 +   0 + hp] = f2bf(o0);
            cb[1024 +  96 + hp] = f2bf(o1);
            cb[1024 + 192 + hp] = f2bf(o2);
            cb[1312 + hp] = f2bf(nrm);
        }
    }
}

// ---------------------------------------------------------------------------
// tail: LN1 + transition MLP (3 MFMA stages) + LN2 + upd + frame, row-local.
// ---------------------------------------------------------------------------
__global__ __launch_bounds__(256) void tail_kernel(
    const float* __restrict__ s, const float* __restrict__ ipa,
    const float* __restrict__ bo,
    const float* __restrict__ g1, const float* __restrict__ be1,
    const unsigned short* __restrict__ Wt1, const float* __restrict__ bt1,
    const unsigned short* __restrict__ Wt2, const float* __restrict__ bt2,
    const unsigned short* __restrict__ Wt3, const float* __restrict__ bt3,
    const float* __restrict__ g2, const float* __restrict__ be2,
    const float* __restrict__ Wbb, const float* __restrict__ bbb,
    const float* __restrict__ mask,
    const float* __restrict__ rot, const float* __restrict__ trans,
    float* __restrict__ out, float* __restrict__ rot_out, float* __restrict__ trans_out)
{
    __shared__ float s1f[32][257];
    __shared__ unsigned short Ab[32][264];
    __shared__ float upd_s[32][6];
    int i0 = blockIdx.x * 32;
    int tid = threadIdx.x, lane = tid & 63, wid = tid >> 6;
    int fr = lane & 15, fc = (lane >> 4) * 8, mrow = (lane >> 4) * 4;

    // ---- LN1: x = s + ipa + bo ----
    int r = tid >> 3, cg = (tid & 7) * 32;
    {
        float xv[32];
        float sum = 0.f, sq = 0.f;
        #pragma unroll
        for (int q = 0; q < 8; q++) {
            float4 a = *(const float4*)&s[(size_t)(i0 + r)*256 + cg + q*4];
            float4 b = *(const float4*)&ipa[(size_t)(i0 + r)*256 + cg + q*4];
            float4 c = *(const float4*)&bo[cg + q*4];
            float v0 = a.x + b.x + c.x, v1 = a.y + b.y + c.y;
            float v2 = a.z + b.z + c.z, v3 = a.w + b.w + c.w;
            xv[q*4+0] = v0; xv[q*4+1] = v1; xv[q*4+2] = v2; xv[q*4+3] = v3;
            sum += v0 + v1 + v2 + v3;
            sq  += v0*v0 + v1*v1 + v2*v2 + v3*v3;
        }
        #pragma unroll
        for (int d = 1; d < 8; d <<= 1) { sum += __shfl_xor(sum, d); sq += __shfl_xor(sq, d); }
        float mu = sum * (1.0f/256.0f);
        float var = sq * (1.0f/256.0f) - mu*mu;
        float rsig = 1.0f / sqrtf(var + 1e-5f);
        #pragma unroll
        for (int c = 0; c < 32; c++) {
            float o = (xv[c] - mu) * rsig * g1[cg + c] + be1[cg + c];
            s1f[r][cg + c] = o;
            Ab[r][cg + c] = f2bf(o);
        }
    }
    __syncthreads();

    // ---- 3 GEMM stages ----
    const unsigned short* Ws[3] = {Wt1, Wt2, Wt3};
    const float* Bs[3] = {bt1, bt2, bt3};
    #pragma unroll
    for (int stage = 0; stage < 3; stage++) {
        const unsigned short* W = Ws[stage];
        const float* bias = Bs[stage];
        v4f acc[2][4] = {};
        #pragma unroll
        for (int k0 = 0; k0 < 8; k0++) {
            v8bf a0 = *(const v8bf*)&Ab[fr][k0*32 + fc];
            v8bf a1 = *(const v8bf*)&Ab[16 + fr][k0*32 + fc];
            #pragma unroll
            for (int n = 0; n < 4; n++) {
                int d = wid*64 + n*16 + fr;
                v8bf b = *(const v8bf*)&W[(size_t)d*256 + k0*32 + fc];
                acc[0][n] = __builtin_amdgcn_mfma_f32_16x16x32_bf16(a0, b, acc[0][n], 0, 0, 0);
                acc[1][n] = __builtin_amdgcn_mfma_f32_16x16x32_bf16(a1, b, acc[1][n], 0, 0, 0);
            }
        }
        __syncthreads();
        if (stage < 2) {
            #pragma unroll
            for (int mi = 0; mi < 2; mi++) {
                #pragma unroll
                for (int n = 0; n < 4; n++) {
                    int d = wid*64 + n*16 + fr;
                    #pragma unroll
                    for (int rr = 0; rr < 4; rr++) {
                        int m = mi*16 + mrow + rr;
                        Ab[m][d] = f2bf(fmaxf(acc[mi][n][rr] + bias[d], 0.f));
                    }
                }
            }
        } else {
            #pragma unroll
            for (int mi = 0; mi < 2; mi++) {
                #pragma unroll
                for (int n = 0; n < 4; n++) {
                    int d = wid*64 + n*16 + fr;
                    #pragma unroll
                    for (int rr = 0; rr < 4; rr++) {
                        int m = mi*16 + mrow + rr;
                        s1f[m][d] += acc[mi][n][rr] + bias[d];
                    }
                }
            }
        }
        __syncthreads();
    }

    // ---- LN2 over s1f (now s1 + y3); write out + keep s2 in s1f ----
    {
        float xv[32];
        float sum = 0.f, sq = 0.f;
        #pragma unroll
        for (int c = 0; c < 32; c++) {
            float v = s1f[r][cg + c];
            xv[c] = v; sum += v; sq += v*v;
        }
        #pragma unroll
        for (int d = 1; d < 8; d <<= 1) { sum += __shfl_xor(sum, d); sq += __shfl_xor(sq, d); }
        float mu = sum * (1.0f/256.0f);
        float var = sq * (1.0f/256.0f) - mu*mu;
        float rsig = 1.0f / sqrtf(var + 1e-5f);
        float o4[32];
        #pragma unroll
        for (int c = 0; c < 32; c++)
            o4[c] = (xv[c] - mu) * rsig * g2[cg + c] + be2[cg + c];
        #pragma unroll
        for (int q = 0; q < 8; q++) {
            float4 w; w.x = o4[q*4]; w.y = o4[q*4+1]; w.z = o4[q*4+2]; w.w = o4[q*4+3];
            *(float4*)&out[(size_t)(i0 + r)*256 + cg + q*4] = w;
        }
        __syncthreads();
        #pragma unroll
        for (int c = 0; c < 32; c++) s1f[r][cg + c] = o4[c];
    }
    __syncthreads();

    // ---- upd = (s2 @ Wbb^T + bbb) * mask ----
    if (tid < 192) {
        int rr = tid / 6, d = tid % 6;
        float acc = bbb[d];
        const float* wb = Wbb + d*256;
        #pragma unroll 8
        for (int c = 0; c < 256; c++) acc += s1f[rr][c] * wb[c];
        upd_s[rr][d] = acc * mask[i0 + rr];
    }
    __syncthreads();

    // ---- frame composition ----
    if (tid < 32) {
        int i = i0 + tid;
        float u0 = upd_s[tid][0], u1 = upd_s[tid][1], u2 = upd_s[tid][2];
        float t0 = upd_s[tid][3], t1 = upd_s[tid][4], t2 = upd_s[tid][5];
        float n = sqrtf(1.f + u0*u0 + u1*u1 + u2*u2);
        float w = 1.f/n, x = u0/n, y = u1/n, z = u2/n;
        float R[3][3];
        R[0][0] = 1.f - 2.f*(y*y + z*z); R[0][1] = 2.f*(x*y - w*z);       R[0][2] = 2.f*(x*z + w*y);
        R[1][0] = 2.f*(x*y + w*z);       R[1][1] = 1.f - 2.f*(x*x + z*z); R[1][2] = 2.f*(y*z - w*x);
        R[2][0] = 2.f*(x*z - w*y);       R[2][1] = 2.f*(y*z + w*x);       R[2][2] = 1.f - 2.f*(x*x + y*y);
        const float* Ri = rot + i*9;
        #pragma unroll
        for (int a = 0; a < 3; a++) {
            #pragma unroll
            for (int b = 0; b < 3; b++) {
                float acc = 0.f;
                #pragma unroll
                for (int j = 0; j < 3; j++) acc += Ri[a*3+j]*R[j][b];
                rot_out[i*9 + a*3 + b] = acc;
            }
            trans_out[i*3 + a] = trans[i*3 + a] + Ri[a*3+0]*t0 + Ri[a*3+1]*t1 + Ri[a*3+2]*t2;
        }
    }
}

// ---------------------------------------------------------------------------
extern "C" void kernel_launch(void* const* d_in, const int* in_sizes, int n_in,
                              void* d_out, int out_size, void* d_ws, size_t ws_size,
                              hipStream_t stream)
{
    const float* s      = (const float*)d_in[0];
    const float* p      = (const float*)d_in[1];
    const float* rot    = (const float*)d_in[2];
    const float* trans  = (const float*)d_in[3];
    const float* mask   = (const float*)d_in[4];
    const float* Wq     = (const float*)d_in[5];
    const float* bq     = (const float*)d_in[6];
    const float* Wkv    = (const float*)d_in[7];
    const float* bkv    = (const float*)d_in[8];
    const float* Wqp    = (const float*)d_in[9];
    const float* bqp    = (const float*)d_in[10];
    const float* Wkvp   = (const float*)d_in[11];
    const float* bkvp   = (const float*)d_in[12];
    const float* Wpb    = (const float*)d_in[13];
    const float* bpb    = (const float*)d_in[14];
    const float* Wo     = (const float*)d_in[15];
    const float* bo     = (const float*)d_in[16];
    const float* Wt1    = (const float*)d_in[17];
    const float* bt1    = (const float*)d_in[18];
    const float* Wt2    = (const float*)d_in[19];
    const float* bt2    = (const float*)d_in[20];
    const float* Wt3    = (const float*)d_in[21];
    const float* bt3    = (const float*)d_in[22];
    const float* Wbb    = (const float*)d_in[23];
    const float* bbb    = (const float*)d_in[24];
    const float* head_w = (const float*)d_in[25];
    const float* g1     = (const float*)d_in[26];
    const float* be1    = (const float*)d_in[27];
    const float* g2     = (const float*)d_in[28];
    const float* be2    = (const float*)d_in[29];

    float* out = (float*)d_out;
    char*  wsb = (char*)d_ws;

    size_t off = 0;
    auto alloc = [&](size_t bytes) -> char* {
        char* ptr = wsb + off;
        off += (bytes + 255) & ~(size_t)255;
        return ptr;
    };
    float* qpraw   = (float*)alloc((size_t)NN*192*4);
    float* kvpraw  = (float*)alloc((size_t)NN*480*4);
    float* att     = (float*)alloc((size_t)8*768*768*4);
    float* ipa     = (float*)alloc((size_t)NN*256*4);
    float* linv    = (float*)alloc((size_t)8*768*4);
    float* lpart   = (float*)alloc((size_t)16*768*4);
    float* opart   = (float*)alloc((size_t)2*768*1024*4);
    unsigned* m0enc = (unsigned*)alloc((size_t)8*768*4);
    unsigned short* s_bf    = (unsigned short*)alloc((size_t)NN*256*2);
    unsigned short* Wq_bf   = (unsigned short*)alloc((size_t)1024*256*2);
    unsigned short* Wkv_bf  = (unsigned short*)alloc((size_t)2048*256*2);
    unsigned short* Wqp_bf  = (unsigned short*)alloc((size_t)192*256*2);
    unsigned short* Wkvp_bf = (unsigned short*)alloc((size_t)480*256*2);
    unsigned short* Wo_bf   = (unsigned short*)alloc((size_t)256*2432*2);
    unsigned short* Wt1_bf  = (unsigned short*)alloc((size_t)256*256*2);
    unsigned short* Wt2_bf  = (unsigned short*)alloc((size_t)256*256*2);
    unsigned short* Wt3_bf  = (unsigned short*)alloc((size_t)256*256*2);
    unsigned short* q_bf    = (unsigned short*)alloc((size_t)NN*1024*2);
    unsigned short* kv_bf   = (unsigned short*)alloc((size_t)NN*2048*2);
    unsigned short* qph     = (unsigned short*)alloc((size_t)NN*256*2);
    unsigned short* qpl     = (unsigned short*)alloc((size_t)NN*256*2);
    unsigned short* kph     = (unsigned short*)alloc((size_t)NN*256*2);
    unsigned short* kpl     = (unsigned short*)alloc((size_t)NN*256*2);
    unsigned short* Vc      = (unsigned short*)alloc((size_t)8*192*768*2);
    unsigned short* att_bf  = (unsigned short*)alloc((size_t)8*768*768*2);
    unsigned short* concat  = (unsigned short*)alloc((size_t)NN*CONCAT*2);

    // 0) zero-init atomic targets
    hipMemsetAsync(ipa, 0, (size_t)NN*256*4, stream);
    hipMemsetAsync(m0enc, 0, (size_t)8*768*4, stream);

    // 1) f32->bf16 conversions
    CvtDesc cd;
    const float* csrc[NCVT]    = {s, Wq, Wkv, Wqp, Wkvp, Wo, Wt1, Wt2, Wt3};
    unsigned short* cdst[NCVT] = {s_bf, Wq_bf, Wkv_bf, Wqp_bf, Wkvp_bf, Wo_bf, Wt1_bf, Wt2_bf, Wt3_bf};
    int csz[NCVT] = {NN*256, 1024*256, 2048*256, 192*256, 480*256, 256*2432, 256*256, 256*256, 256*256};
    int cum = 0;
    for (int i2 = 0; i2 < NCVT; i2++) {
        cd.src[i2] = csrc[i2]; cd.dst[i2] = cdst[i2]; cd.nelem[i2] = csz[i2];
        cd.blk_start[i2] = cum;
        cum += (csz[i2] + 2047) / 2048;
    }
    cd.blk_start[NCVT] = cum;
    cvt_many<<<cum, 256, 0, stream>>>(cd);

    // 2) All projections in one GEMM launch
    ProjDesc pd;
    pd.W[0] = Wq_bf;   pd.bias[0] = bq;   pd.dstb[0] = q_bf;   pd.dstf[0] = nullptr; pd.D[0] = 1024; pd.ldc[0] = 1024; pd.mode[0] = 2;
    pd.W[1] = Wkv_bf;  pd.bias[1] = bkv;  pd.dstb[1] = kv_bf;  pd.dstf[1] = nullptr; pd.D[1] = 2048; pd.ldc[1] = 2048; pd.mode[1] = 2;
    pd.W[2] = Wqp_bf;  pd.bias[2] = bqp;  pd.dstb[2] = nullptr; pd.dstf[2] = qpraw;  pd.D[2] = 192;  pd.ldc[2] = 192;  pd.mode[2] = 0;
    pd.W[3] = Wkvp_bf; pd.bias[3] = bkvp; pd.dstb[3] = nullptr; pd.dstf[3] = kvpraw; pd.D[3] = 480;  pd.ldc[3] = 480;  pd.mode[3] = 0;
    pd.blk_start[0] = 0; pd.blk_start[1] = 16; pd.blk_start[2] = 48; pd.blk_start[3] = 51; pd.blk_start[4] = 59;
    proj_all<<<dim3(59, 12), 256, 0, stream>>>(s_bf, pd);

    // 3) rotate + vtrans merged
    prep2_kernel<<<672 + 192, 256, 0, stream>>>(
        qpraw, kvpraw, rot, trans, kv_bf, qph, qpl, kph, kpl, Vc);

    // 4) logits (+row max via atomicMax)
    logits_mfma<<<dim3(12, 12, 8), 256, 0, stream>>>(
        q_bf, kv_bf, qph, qpl, kph, kpl, mask, head_w, att, m0enc);

    // 5) single-pass p kernel, split over 2 j-halves
    fused_p3s_kernel<<<dim3(768, 2), 256, 0, stream>>>(
        att, p, Wpb, bpb, m0enc, att_bf, lpart, opart);
    preduce_kernel<<<768, 256, 0, stream>>>(lpart, opart, linv, concat);

    // 6) o / opt (+final epilogue)
    attvc_mfma<<<dim3(3, 12, 8), 256, 0, stream>>>(att_bf, Vc, linv, rot, trans, concat);

    // 7) Output projection (split-K into zeroed ipa)
    mfma_gemm<4,0,0><<<dim3(4,12,4), 256, 0, stream>>>(concat, Wo_bf, nullptr, ipa, nullptr, 256, 2432, 256);

    // 8) fused tail: LN1 + MLP + LN2 + upd + frame
    tail_kernel<<<24, 256, 0, stream>>>(
        s, ipa, bo, g1, be1, Wt1_bf, bt1, Wt2_bf, bt2, Wt3_bf, bt3,
        g2, be2, Wbb, bbb, mask, rot, trans,
        out, out + (size_t)NN*256, out + (size_t)NN*256 + (size_t)NN*9);
}